// Round 7
// baseline (202.157 us; speedup 1.0000x reference)
//
#include <hip/hip_runtime.h>
#include <stdint.h>

#define B_ 16
#define N_ 1025
#define D_ 512
#define H_ 8
#define HD 64
#define NP 1152           // padded N: 9*128 (q side)
#define WM 36             // bitmask u32 words per row
#define M_ (B_*N_)        // 16400 (real rows)
#define MP (B_*NP)        // 18432 = 144*128 padded rows
#define NTKV 17           // KV tiles of 64 actually processed (17*64=1088 >= 1025)
#define NQG 72            // q-groups of 16 (NP/16)

typedef unsigned short u16;
typedef __attribute__((ext_vector_type(8))) short bf16x8;
typedef __attribute__((ext_vector_type(4))) u16 u16x4;
typedef __attribute__((ext_vector_type(8))) u16 u16x8;
typedef __attribute__((ext_vector_type(4))) float f32x4;

typedef __attribute__((address_space(1))) const uint32_t gld_t;
typedef __attribute__((address_space(3))) uint32_t lds_t;

__device__ __forceinline__ u16 f2bf(float f) {
  uint32_t u = __float_as_uint(f);
  u += 0x7FFFu + ((u >> 16) & 1u);   // RNE
  return (u16)(u >> 16);
}

__device__ __forceinline__ uint32_t cvtpk(float a, float b) {
  uint32_t r;
  asm("v_cvt_pk_bf16_f32 %0, %1, %2" : "=v"(r) : "v"(a), "v"(b));
  return r;
}

__device__ __forceinline__ float exp2a(float x) {   // bare v_exp_f32 (no OCML fixup)
  float r;
  asm("v_exp_f32 %0, %1\n\ts_nop 0" : "=v"(r) : "v"(x));
  return r;
}

__device__ __forceinline__ void gload16(const void* g, void* l) {
  __builtin_amdgcn_global_load_lds((gld_t*)g, (lds_t*)l, 16, 0, 0);
}

// ---------------- K0: pack attn_mask into bitmask [NP][WM] u32 ----------------
__global__ void k_bitmask(const float* __restrict__ mask, uint32_t* __restrict__ bm) {
  int r = blockIdx.x;
  int wave = threadIdx.x >> 6, lane = threadIdx.x & 63;
  for (int chunk = wave; chunk < 18; chunk += 4) {
    int kv = chunk * 64 + lane;
    bool pred = (r < N_) && (kv < N_) && (mask[(size_t)r * N_ + kv] != 0.0f);
    unsigned long long bal = __ballot(pred);
    if (lane == 0) {
      bm[r * WM + chunk * 2]     = (uint32_t)bal;
      bm[r * WM + chunk * 2 + 1] = (uint32_t)(bal >> 32);
    }
  }
}

// ---------------- K0b: additive mask in MFMA C-fragment layout ----------------
__global__ __launch_bounds__(64) void k_amask(const uint32_t* __restrict__ bm, float* __restrict__ am) {
  int qg = blockIdx.x, ti = blockIdx.y;
  int lane = threadIdx.x;
  int lq = lane & 15, lg = lane >> 4;
  int q = qg * 16 + lq;
  size_t base = ((size_t)(qg * NTKV + ti) * 64 + lane) * 16;
#pragma unroll
  for (int f = 0; f < 4; ++f) {
    f32x4 o;
#pragma unroll
    for (int r = 0; r < 4; ++r) {
      int kv = ti * 64 + f * 16 + 4 * lg + r;
      uint32_t bit = (bm[q * WM + (kv >> 5)] >> (kv & 31)) & 1u;
      o[r] = bit ? 0.f : -30000.f;
    }
    *reinterpret_cast<f32x4*>(am + base + f * 4) = o;
  }
}

// ---------------- K1: convert+transpose weights to bf16 ----------------
__global__ void k_wconv(const float* __restrict__ wqkv, const float* __restrict__ wproj,
                        u16* __restrict__ wtq, u16* __restrict__ wtp) {
  int idx = blockIdx.x * 256 + threadIdx.x;
  if (idx < 3 * D_ * D_) {
    int k = idx / (3 * D_), c = idx % (3 * D_);
    wtq[c * D_ + k] = f2bf(wqkv[idx]);
  }
  if (idx < D_ * D_) {
    int k = idx >> 9, c = idx & 511;
    wtp[c * D_ + k] = f2bf(wproj[idx]);
  }
}

// ---------------- K2: x -> bf16, padded [B][NP][D], padded rows zeroed ----------------
__global__ void k_xconv(const float* __restrict__ x, u16* __restrict__ xb) {
  int i = blockIdx.x * 256 + threadIdx.x;
  int idx = i * 8;
  int pr = idx >> 9;
  int col = idx & 511;
  int b = pr / NP, n = pr - b * NP;
  u16x8 o;
  if (n < N_) {
    const float* src = x + ((size_t)b * N_ + n) * D_ + col;
    float4 v0 = *reinterpret_cast<const float4*>(src);
    float4 v1 = *reinterpret_cast<const float4*>(src + 4);
    o[0] = f2bf(v0.x); o[1] = f2bf(v0.y); o[2] = f2bf(v0.z); o[3] = f2bf(v0.w);
    o[4] = f2bf(v1.x); o[5] = f2bf(v1.y); o[6] = f2bf(v1.z); o[7] = f2bf(v1.w);
  } else {
    o = (u16x8){0,0,0,0,0,0,0,0};
  }
  *reinterpret_cast<u16x8*>(xb + idx) = o;
}

// ---------------- K3: QKV GEMM -> Q (scaled by 0.125*log2e), K, Vt (fused transpose) ----------------
__global__ __launch_bounds__(256) void k_qkv(const u16* __restrict__ xb, const u16* __restrict__ wtq,
                                             u16* __restrict__ Q, u16* __restrict__ K,
                                             u16* __restrict__ Vt) {
  __shared__ u16 sA[2][128 * 64];
  __shared__ u16 sB[2][128 * 64];
  const int m0 = blockIdx.y * 128;
  const int n0 = blockIdx.x * 128;
  const int t = threadIdx.x;
  const int wave = t >> 6, lane = t & 63;
  const int wm = wave >> 1, wn = wave & 1;
  const int lq = lane & 15, lg = lane >> 4;

  const int srow = lane >> 3;
  const int schunk = (lane & 7) ^ srow;

  f32x4 acc[4][4] = {};

#define QSTAGE(buf, k0_)                                                          \
  {                                                                               \
    _Pragma("unroll")                                                             \
    for (int p = 0; p < 4; ++p) {                                                 \
      int row = p * 32 + wave * 8 + srow;                                         \
      gload16(xb + (size_t)(m0 + row) * 512 + (k0_) + schunk * 8,                 \
              &sA[buf][p * 2048 + wave * 512 + lane * 8]);                        \
      gload16(wtq + (size_t)(n0 + row) * 512 + (k0_) + schunk * 8,                \
              &sB[buf][p * 2048 + wave * 512 + lane * 8]);                        \
    }                                                                             \
  }

  QSTAGE(0, 0);
  __syncthreads();
  int cur = 0;
  for (int k0 = 0; k0 < 512; k0 += 64) {
    if (k0 < 448) QSTAGE(cur ^ 1, k0 + 64);
#pragma unroll
    for (int kk = 0; kk < 2; ++kk) {
      bf16x8 af[4], bff[4];
      const int pc = (kk * 4 + lg) ^ (lq & 7);
#pragma unroll
      for (int f = 0; f < 4; ++f) {
        af[f]  = *reinterpret_cast<const bf16x8*>(&sA[cur][(wm * 64 + f * 16 + lq) * 64 + pc * 8]);
        bff[f] = *reinterpret_cast<const bf16x8*>(&sB[cur][(wn * 64 + f * 16 + lq) * 64 + pc * 8]);
      }
#pragma unroll
      for (int i = 0; i < 4; ++i)
#pragma unroll
        for (int j = 0; j < 4; ++j)
          acc[i][j] = __builtin_amdgcn_mfma_f32_16x16x32_bf16(af[i], bff[j], acc[i][j], 0, 0, 0);
    }
    __syncthreads();
    cur ^= 1;
  }
#undef QSTAGE

  if (n0 >= 1024) {
    // ---- V block: transpose 128(m) x 128(c) through XOR-swizzled LDS, write Vt coalesced ----
    u16* T = (u16*)&sA[0][0];
#pragma unroll
    for (int j = 0; j < 4; ++j) {
      int c = wn * 64 + j * 16 + lq;
#pragma unroll
      for (int i = 0; i < 4; ++i) {
        int mb = wm * 64 + i * 16 + lg * 4;
        u16x4 pw;
#pragma unroll
        for (int r = 0; r < 4; ++r) pw[r] = f2bf(acc[i][j][r]);
        *reinterpret_cast<u16x4*>(&T[c * 128 + ((((mb >> 3) ^ lq) << 3) | (mb & 7))]) = pw;
      }
    }
    __syncthreads();
    int c = t & 127;
    int ch0 = (t >> 7) << 3;
    int cg = n0 + c - 1024;
    int h = cg >> 6, d = cg & 63;
    int bb = m0 / NP;
    int nb = m0 - bb * NP;
    u16* dst = Vt + (((size_t)(bb * H_ + h) * HD + d) * NP + nb);
#pragma unroll
    for (int rep = 0; rep < 8; ++rep) {
      int chunk = ch0 + rep;
      u16x8 vv = *reinterpret_cast<const u16x8*>(&T[c * 128 + ((chunk ^ (c & 15)) << 3)]);
      *reinterpret_cast<u16x8*>(&dst[chunk * 8]) = vv;
    }
  } else {
#pragma unroll
    for (int j = 0; j < 4; ++j) {
      int c = n0 + wn * 64 + j * 16 + lq;
      int which = c >> 9, h = (c >> 6) & 7, d = c & 63;
#pragma unroll
      for (int i = 0; i < 4; ++i) {
        int mbase = m0 + wm * 64 + i * 16 + lg * 4;
#pragma unroll
        for (int r = 0; r < 4; ++r) {
          int m = mbase + r;
          int b = m / NP, n = m - b * NP;
          int bh = b * H_ + h;
          float v = acc[i][j][r];
          if (which == 0) Q[((size_t)bh * NP + n) * HD + d] = f2bf(v * 0.18033688f); // 0.125*log2(e)
          else            K[((size_t)bh * NP + n) * HD + d] = f2bf(v);
        }
      }
    }
  }
}

// ---------------- K4: flash attention, 4 waves x 32 q-rows (2 q-frags/wave) ----------------
// Each LDS K/V fragment read feeds TWO MFMAs -> LDS-read per MFMA halved vs r6.
__global__ __launch_bounds__(256) void k_attn(const u16* __restrict__ Q, const u16* __restrict__ K,
                                              const u16* __restrict__ Vt, const float* __restrict__ am,
                                              u16* __restrict__ O) {
  __shared__ u16 sK[2][64 * 64];
  __shared__ u16 sV[2][64 * 64];
  __shared__ u16 sP[4][32 * 64];

  int bid = blockIdx.x;
  int wg = (bid & 7) * (9 * 128 / 8) + (bid >> 3);   // XCD swizzle (1152 % 8 == 0)
  int bh = wg / 9, qt = wg - bh * 9;
  int b = bh >> 3, h = bh & 7;
  int t = threadIdx.x;
  int w = t >> 6, lane = t & 63;
  int lq = lane & 15, lg = lane >> 4;
  int qbase = qt * 128 + w * 32;
  int qg0 = qt * 8 + w * 2;
  const u16* Qp = Q + ((size_t)bh * NP + qbase) * HD;
  const u16* Kp = K + (size_t)bh * NP * HD;
  const u16* Vp = Vt + (size_t)bh * HD * NP;
  const float* amp0 = am + ((size_t)qg0 * NTKV * 64 + lane) * 16;
  const float* amp1 = am + ((size_t)(qg0 + 1) * NTKV * 64 + lane) * 16;

  // Q fragments: group A = rows 0..15, group B = rows 16..31 of this wave's 32
  bf16x8 qfA0 = *reinterpret_cast<const bf16x8*>(Qp + lq * HD + lg * 8);
  bf16x8 qfA1 = *reinterpret_cast<const bf16x8*>(Qp + lq * HD + 32 + lg * 8);
  bf16x8 qfB0 = *reinterpret_cast<const bf16x8*>(Qp + (16 + lq) * HD + lg * 8);
  bf16x8 qfB1 = *reinterpret_cast<const bf16x8*>(Qp + (16 + lq) * HD + 32 + lg * 8);

  // staging: K/V tiles 64x64 = 512 chunks each; thread t stages chunks t and t+256
  const int c0 = t, c1 = t + 256;
  const int r0 = c0 >> 3, ch0 = (c0 & 7) ^ (r0 & 7);
  const int r1 = c1 >> 3, ch1 = (c1 & 7) ^ (r1 & 7);

  f32x4 oaccA[4] = {}, oaccB[4] = {};
  float lpA = 0.f, lpB = 0.f;

#define STAGE(buf, kv0_)                                                        \
  {                                                                             \
    gload16(Kp + (size_t)((kv0_) + r0) * HD + ch0 * 8, &sK[buf][c0 * 8]);       \
    gload16(Kp + (size_t)((kv0_) + r1) * HD + ch1 * 8, &sK[buf][c1 * 8]);       \
    gload16(Vp + (size_t)r0 * NP + (kv0_) + ch0 * 8,   &sV[buf][c0 * 8]);       \
    gload16(Vp + (size_t)r1 * NP + (kv0_) + ch1 * 8,   &sV[buf][c1 * 8]);       \
  }

#define AML(an, ti_)                                                            \
  {                                                                             \
    const f32x4* apA = reinterpret_cast<const f32x4*>(amp0 + (size_t)(ti_) * 64 * 16); \
    const f32x4* apB = reinterpret_cast<const f32x4*>(amp1 + (size_t)(ti_) * 64 * 16); \
    an[0] = apA[0]; an[1] = apA[1]; an[2] = apA[2]; an[3] = apA[3];             \
    an[4] = apB[0]; an[5] = apB[1]; an[6] = apB[2]; an[7] = apB[3];             \
  }

#define COMPUTE(buf, ac)                                                         \
  {                                                                              \
    f32x4 s0[4] = {ac[0], ac[1], ac[2], ac[3]};                                  \
    f32x4 s1[4] = {ac[4], ac[5], ac[6], ac[7]};                                  \
    __builtin_amdgcn_s_setprio(1);                                               \
    _Pragma("unroll")                                                            \
    for (int kk = 0; kk < 2; ++kk) {                                             \
      bf16x8 qa = kk ? qfA1 : qfA0;                                              \
      bf16x8 qb = kk ? qfB1 : qfB0;                                              \
      int pc = (kk * 4 + lg) ^ (lq & 7);                                         \
      _Pragma("unroll")                                                          \
      for (int f = 0; f < 4; ++f) {                                              \
        bf16x8 kf = *reinterpret_cast<const bf16x8*>(&sK[buf][(f * 16 + lq) * 64 + pc * 8]); \
        s0[f] = __builtin_amdgcn_mfma_f32_16x16x32_bf16(kf, qa, s0[f], 0, 0, 0); \
        s1[f] = __builtin_amdgcn_mfma_f32_16x16x32_bf16(kf, qb, s1[f], 0, 0, 0); \
      }                                                                          \
    }                                                                            \
    __builtin_amdgcn_s_setprio(0);                                               \
    _Pragma("unroll")                                                            \
    for (int f = 0; f < 4; ++f) {                                                \
      _Pragma("unroll")                                                          \
      for (int r = 0; r < 4; ++r) {                                              \
        float pa = exp2a(s0[f][r]); s0[f][r] = pa; lpA += pa;                    \
        float pb = exp2a(s1[f][r]); s1[f][r] = pb; lpB += pb;                    \
      }                                                                          \
    }                                                                            \
    _Pragma("unroll")                                                            \
    for (int f = 0; f < 4; ++f) {                                                \
      int pch = (2 * f + (lg >> 1)) ^ (lq & 7);                                  \
      uint2 pw;                                                                  \
      pw.x = cvtpk(s0[f][0], s0[f][1]);                                          \
      pw.y = cvtpk(s0[f][2], s0[f][3]);                                          \
      *reinterpret_cast<uint2*>(&sP[w][lq * 64 + pch * 8 + (lg & 1) * 4]) = pw;  \
      pw.x = cvtpk(s1[f][0], s1[f][1]);                                          \
      pw.y = cvtpk(s1[f][2], s1[f][3]);                                          \
      *reinterpret_cast<uint2*>(&sP[w][1024 + lq * 64 + pch * 8 + (lg & 1) * 4]) = pw; \
    }                                                                            \
    __builtin_amdgcn_s_setprio(1);                                               \
    _Pragma("unroll")                                                            \
    for (int kk = 0; kk < 2; ++kk) {                                             \
      int pc = (kk * 4 + lg) ^ (lq & 7);                                         \
      bf16x8 pfA = *reinterpret_cast<const bf16x8*>(&sP[w][lq * 64 + pc * 8]);   \
      bf16x8 pfB = *reinterpret_cast<const bf16x8*>(&sP[w][1024 + lq * 64 + pc * 8]); \
      _Pragma("unroll")                                                          \
      for (int j = 0; j < 4; ++j) {                                              \
        bf16x8 vf = *reinterpret_cast<const bf16x8*>(&sV[buf][(j * 16 + lq) * 64 + pc * 8]); \
        oaccA[j] = __builtin_amdgcn_mfma_f32_16x16x32_bf16(pfA, vf, oaccA[j], 0, 0, 0); \
        oaccB[j] = __builtin_amdgcn_mfma_f32_16x16x32_bf16(pfB, vf, oaccB[j], 0, 0, 0); \
      }                                                                          \
    }                                                                            \
    __builtin_amdgcn_s_setprio(0);                                               \
  }

// pipelined step: stage tile ti+1 (4 loads) + amask ti+1 (8 loads); wait tile-ti's set
#define STEP(bufb, ac, an, ti_)                                                  \
  {                                                                              \
    STAGE((bufb) ^ 1, ((ti_) + 1) * 64);                                         \
    AML(an, (ti_) + 1);                                                          \
    asm volatile("s_waitcnt vmcnt(12)" ::: "memory");                            \
    __builtin_amdgcn_s_barrier();                                                \
    COMPUTE(bufb, ac);                                                           \
    __builtin_amdgcn_s_barrier();                                                \
  }

  f32x4 a0[8], a1[8];
  STAGE(0, 0);
  AML(a0, 0);
  for (int tp = 0; tp < 8; ++tp) {       // tiles 0..15
    STEP(0, a0, a1, 2 * tp);
    STEP(1, a1, a0, 2 * tp + 1);
  }
  asm volatile("s_waitcnt vmcnt(0)" ::: "memory");
  __builtin_amdgcn_s_barrier();
  COMPUTE(0, a0);                        // tile 16
#undef STAGE
#undef AML
#undef COMPUTE
#undef STEP

  // deferred l reduction per group
  lpA += __shfl_xor(lpA, 16);
  lpA += __shfl_xor(lpA, 32);
  lpB += __shfl_xor(lpB, 16);
  lpB += __shfl_xor(lpB, 32);

#pragma unroll
  for (int r = 0; r < 4; ++r) {
    float lrA = __shfl(lpA, 4 * lg + r);
    float lrB = __shfl(lpB, 4 * lg + r);
    float liA = (lrA > 0.f) ? 1.f / lrA : 0.f;
    float liB = (lrB > 0.f) ? 1.f / lrB : 0.f;
    size_t rowA = (size_t)b * NP + qbase + 4 * lg + r;
    size_t rowB = rowA + 16;
#pragma unroll
    for (int j = 0; j < 4; ++j) {
      O[rowA * D_ + h * HD + j * 16 + lq] = f2bf(oaccA[j][r] * liA);
      O[rowB * D_ + h * HD + j * 16 + lq] = f2bf(oaccB[j][r] * liB);
    }
  }
}

// ---------------- K5: proj GEMM + bias -> fp32 (padded M), 2-phase dbuf ----------------
__global__ __launch_bounds__(256) void k_proj(const u16* __restrict__ ob, const u16* __restrict__ wtp,
                                              const float* __restrict__ bias, float* __restrict__ oproj) {
  __shared__ u16 sA[2][128 * 64];
  __shared__ u16 sB[2][128 * 64];
  const int m0 = blockIdx.y * 128;
  const int n0 = blockIdx.x * 128;
  const int t = threadIdx.x;
  const int wave = t >> 6, lane = t & 63;
  const int wm = wave >> 1, wn = wave & 1;
  const int lq = lane & 15, lg = lane >> 4;

  const int srow = lane >> 3;
  const int schunk = (lane & 7) ^ srow;

  f32x4 acc[4][4] = {};

#define PSTAGE(buf, k0_)                                                          \
  {                                                                               \
    _Pragma("unroll")                                                             \
    for (int p = 0; p < 4; ++p) {                                                 \
      int row = p * 32 + wave * 8 + srow;                                         \
      gload16(ob + (size_t)(m0 + row) * 512 + (k0_) + schunk * 8,                 \
              &sA[buf][p * 2048 + wave * 512 + lane * 8]);                        \
      gload16(wtp + (size_t)(n0 + row) * 512 + (k0_) + schunk * 8,                \
              &sB[buf][p * 2048 + wave * 512 + lane * 8]);                        \
    }                                                                             \
  }

  PSTAGE(0, 0);
  __syncthreads();
  int cur = 0;
  for (int k0 = 0; k0 < 512; k0 += 64) {
    if (k0 < 448) PSTAGE(cur ^ 1, k0 + 64);
#pragma unroll
    for (int kk = 0; kk < 2; ++kk) {
      bf16x8 af[4], bff[4];
      const int pc = (kk * 4 + lg) ^ (lq & 7);
#pragma unroll
      for (int f = 0; f < 4; ++f) {
        af[f]  = *reinterpret_cast<const bf16x8*>(&sA[cur][(wm * 64 + f * 16 + lq) * 64 + pc * 8]);
        bff[f] = *reinterpret_cast<const bf16x8*>(&sB[cur][(wn * 64 + f * 16 + lq) * 64 + pc * 8]);
      }
#pragma unroll
      for (int i = 0; i < 4; ++i)
#pragma unroll
        for (int j = 0; j < 4; ++j)
          acc[i][j] = __builtin_amdgcn_mfma_f32_16x16x32_bf16(af[i], bff[j], acc[i][j], 0, 0, 0);
    }
    __syncthreads();
    cur ^= 1;
  }
#undef PSTAGE

#pragma unroll
  for (int j = 0; j < 4; ++j) {
    int c = n0 + wn * 64 + j * 16 + lq;
    float bv = bias[c];
#pragma unroll
    for (int i = 0; i < 4; ++i) {
      int mbase = m0 + wm * 64 + i * 16 + lg * 4;
#pragma unroll
      for (int r = 0; r < 4; ++r) {
        int m = mbase + r;
        oproj[(size_t)m * D_ + c] = acc[i][j][r] + bv;
      }
    }
  }
}

// ---------------- K6: LN + residual (reads padded, writes real) ----------------
__global__ __launch_bounds__(256) void k_ln(const float* __restrict__ op, const float* __restrict__ gamma,
                                            const float* __restrict__ beta, float* __restrict__ out) {
  int row = blockIdx.x;
  int b = row / N_, n = row - b * N_;
  int t = threadIdx.x;
  const float* r = op + ((size_t)b * NP + n) * D_;
  float v0 = r[t], v1 = r[t + 256];
  float s = v0 + v1, sq = v0 * v0 + v1 * v1;
#pragma unroll
  for (int off = 1; off < 64; off <<= 1) { s += __shfl_xor(s, off); sq += __shfl_xor(sq, off); }
  __shared__ float ls[4], lsq[4];
  int wave = t >> 6, lane = t & 63;
  if (lane == 0) { ls[wave] = s; lsq[wave] = sq; }
  __syncthreads();
  float S = ls[0] + ls[1] + ls[2] + ls[3];
  float SQ = lsq[0] + lsq[1] + lsq[2] + lsq[3];
  float mu = S * (1.f / 512.f);
  float var = SQ * (1.f / 512.f) - mu * mu;
  float rinv = rsqrtf(var + 1e-5f);
  float g0 = gamma[t], g1 = gamma[t + 256], b0 = beta[t], b1 = beta[t + 256];
  out[(size_t)row * D_ + t]       = v0 + (v0 - mu) * rinv * g0 + b0;
  out[(size_t)row * D_ + t + 256] = v1 + (v1 - mu) * rinv * g1 + b1;
}

extern "C" void kernel_launch(void* const* d_in, const int* in_sizes, int n_in,
                              void* d_out, int out_size, void* d_ws, size_t ws_size,
                              hipStream_t stream) {
  const float* x     = (const float*)d_in[0];
  const float* wqkv  = (const float*)d_in[1];
  const float* wproj = (const float*)d_in[2];
  const float* bproj = (const float*)d_in[3];
  const float* gamma = (const float*)d_in[4];
  const float* beta  = (const float*)d_in[5];
  const float* mask  = (const float*)d_in[6];
  float* out = (float*)d_out;

  char* ws = (char*)d_ws;
  size_t off = 0;
  auto alloc = [&](size_t bytes) {
    void* p = ws + off;
    off = (off + bytes + 255) & ~(size_t)255;
    return p;
  };
  uint32_t* bmask = (uint32_t*)alloc((size_t)NP * WM * 4);
  float* am  = (float*)alloc((size_t)NQG * NTKV * 64 * 16 * 4);
  u16* wtq  = (u16*)alloc((size_t)3 * D_ * D_ * 2);
  u16* wtp  = (u16*)alloc((size_t)D_ * D_ * 2);
  u16* xb   = (u16*)alloc((size_t)MP * D_ * 2);
  u16* Qb   = (u16*)alloc((size_t)128 * NP * HD * 2);
  u16* Kb   = (u16*)alloc((size_t)128 * NP * HD * 2);
  u16* Vtb  = (u16*)alloc((size_t)128 * HD * NP * 2);
  u16* Ob   = (u16*)alloc((size_t)MP * D_ * 2);
  float* oproj = (float*)alloc((size_t)MP * D_ * 4);

  k_bitmask<<<dim3(NP), dim3(256), 0, stream>>>(mask, bmask);
  k_amask<<<dim3(NQG, NTKV), dim3(64), 0, stream>>>(bmask, am);
  k_wconv<<<dim3(3072), dim3(256), 0, stream>>>(wqkv, wproj, wtq, wtp);
  k_xconv<<<dim3(MP * D_ / (256 * 8)), dim3(256), 0, stream>>>(x, xb);
  k_qkv<<<dim3(12, MP / 128), dim3(256), 0, stream>>>(xb, wtq, Qb, Kb, Vtb);
  k_attn<<<dim3(9 * 128), dim3(256), 0, stream>>>(Qb, Kb, Vtb, am, Ob);
  k_proj<<<dim3(4, MP / 128), dim3(256), 0, stream>>>(Ob, wtp, bproj, oproj);
  k_ln<<<dim3(M_), dim3(256), 0, stream>>>(oproj, gamma, beta, out);
}

// Round 8
// 192.412 us; speedup vs baseline: 1.0506x; 1.0506x over previous
//
#include <hip/hip_runtime.h>
#include <stdint.h>

#define B_ 16
#define N_ 1025
#define D_ 512
#define H_ 8
#define HD 64
#define NP 1152           // padded N: 9*128 (q side)
#define WM 36             // bitmask u32 words per row
#define M_ (B_*N_)        // 16400 (real rows)
#define MP (B_*NP)        // 18432 = 144*128 padded rows
#define NT32 34           // KV tiles of 32 (34*32=1088 >= 1025)
#define NQG 72            // q-groups of 16 (NP/16)

typedef unsigned short u16;
typedef __attribute__((ext_vector_type(8))) short bf16x8;
typedef __attribute__((ext_vector_type(4))) u16 u16x4;
typedef __attribute__((ext_vector_type(8))) u16 u16x8;
typedef __attribute__((ext_vector_type(4))) float f32x4;

typedef __attribute__((address_space(1))) const uint32_t gld_t;
typedef __attribute__((address_space(3))) uint32_t lds_t;

__device__ __forceinline__ u16 f2bf(float f) {
  uint32_t u = __float_as_uint(f);
  u += 0x7FFFu + ((u >> 16) & 1u);   // RNE
  return (u16)(u >> 16);
}

__device__ __forceinline__ uint32_t cvtpk(float a, float b) {
  uint32_t r;
  asm("v_cvt_pk_bf16_f32 %0, %1, %2" : "=v"(r) : "v"(a), "v"(b));
  return r;
}

__device__ __forceinline__ float exp2a(float x) {   // bare v_exp_f32 (no OCML fixup)
  float r;
  asm("v_exp_f32 %0, %1\n\ts_nop 0" : "=v"(r) : "v"(x));
  return r;
}

__device__ __forceinline__ void gload16(const void* g, void* l) {
  __builtin_amdgcn_global_load_lds((gld_t*)g, (lds_t*)l, 16, 0, 0);
}

// ---------------- K0: pack attn_mask into bitmask [NP][WM] u32 ----------------
__global__ void k_bitmask(const float* __restrict__ mask, uint32_t* __restrict__ bm) {
  int r = blockIdx.x;
  int wave = threadIdx.x >> 6, lane = threadIdx.x & 63;
  for (int chunk = wave; chunk < 18; chunk += 4) {
    int kv = chunk * 64 + lane;
    bool pred = (r < N_) && (kv < N_) && (mask[(size_t)r * N_ + kv] != 0.0f);
    unsigned long long bal = __ballot(pred);
    if (lane == 0) {
      bm[r * WM + chunk * 2]     = (uint32_t)bal;
      bm[r * WM + chunk * 2 + 1] = (uint32_t)(bal >> 32);
    }
  }
}

// ---------------- K0b: additive mask (bf16) in MFMA C-fragment layout, KVBLK=32 ----------------
// am[qg][ti][lane][f*4+r] : bf16(0) if mask bit set else bf16(-29952)
__global__ __launch_bounds__(64) void k_amask(const uint32_t* __restrict__ bm, u16* __restrict__ am) {
  int qg = blockIdx.x, ti = blockIdx.y;
  int lane = threadIdx.x;
  int lq = lane & 15, lg = lane >> 4;
  int q = qg * 16 + lq;
  const u16 neg = f2bf(-30000.f);
  u16x8 o;
#pragma unroll
  for (int f = 0; f < 2; ++f) {
#pragma unroll
    for (int r = 0; r < 4; ++r) {
      int kv = ti * 32 + f * 16 + 4 * lg + r;
      uint32_t bit = (bm[q * WM + (kv >> 5)] >> (kv & 31)) & 1u;
      o[f * 4 + r] = bit ? (u16)0 : neg;
    }
  }
  *reinterpret_cast<u16x8*>(am + ((size_t)(qg * NT32 + ti) * 64 + lane) * 8) = o;
}

// ---------------- K1: convert+transpose weights to bf16 ----------------
__global__ void k_wconv(const float* __restrict__ wqkv, const float* __restrict__ wproj,
                        u16* __restrict__ wtq, u16* __restrict__ wtp) {
  int idx = blockIdx.x * 256 + threadIdx.x;
  if (idx < 3 * D_ * D_) {
    int k = idx / (3 * D_), c = idx % (3 * D_);
    wtq[c * D_ + k] = f2bf(wqkv[idx]);
  }
  if (idx < D_ * D_) {
    int k = idx >> 9, c = idx & 511;
    wtp[c * D_ + k] = f2bf(wproj[idx]);
  }
}

// ---------------- K2: x -> bf16, padded [B][NP][D], padded rows zeroed ----------------
__global__ void k_xconv(const float* __restrict__ x, u16* __restrict__ xb) {
  int i = blockIdx.x * 256 + threadIdx.x;
  int idx = i * 8;
  int pr = idx >> 9;
  int col = idx & 511;
  int b = pr / NP, n = pr - b * NP;
  u16x8 o;
  if (n < N_) {
    const float* src = x + ((size_t)b * N_ + n) * D_ + col;
    float4 v0 = *reinterpret_cast<const float4*>(src);
    float4 v1 = *reinterpret_cast<const float4*>(src + 4);
    o[0] = f2bf(v0.x); o[1] = f2bf(v0.y); o[2] = f2bf(v0.z); o[3] = f2bf(v0.w);
    o[4] = f2bf(v1.x); o[5] = f2bf(v1.y); o[6] = f2bf(v1.z); o[7] = f2bf(v1.w);
  } else {
    o = (u16x8){0,0,0,0,0,0,0,0};
  }
  *reinterpret_cast<u16x8*>(xb + idx) = o;
}

// ---------------- K3: QKV GEMM -> Q (scaled by 0.125*log2e), K, Vt (fused transpose) ----------------
__global__ __launch_bounds__(256) void k_qkv(const u16* __restrict__ xb, const u16* __restrict__ wtq,
                                             u16* __restrict__ Q, u16* __restrict__ K,
                                             u16* __restrict__ Vt) {
  __shared__ u16 sA[2][128 * 64];
  __shared__ u16 sB[2][128 * 64];
  const int m0 = blockIdx.y * 128;
  const int n0 = blockIdx.x * 128;
  const int t = threadIdx.x;
  const int wave = t >> 6, lane = t & 63;
  const int wm = wave >> 1, wn = wave & 1;
  const int lq = lane & 15, lg = lane >> 4;

  const int srow = lane >> 3;
  const int schunk = (lane & 7) ^ srow;

  f32x4 acc[4][4] = {};

#define QSTAGE(buf, k0_)                                                          \
  {                                                                               \
    _Pragma("unroll")                                                             \
    for (int p = 0; p < 4; ++p) {                                                 \
      int row = p * 32 + wave * 8 + srow;                                         \
      gload16(xb + (size_t)(m0 + row) * 512 + (k0_) + schunk * 8,                 \
              &sA[buf][p * 2048 + wave * 512 + lane * 8]);                        \
      gload16(wtq + (size_t)(n0 + row) * 512 + (k0_) + schunk * 8,                \
              &sB[buf][p * 2048 + wave * 512 + lane * 8]);                        \
    }                                                                             \
  }

  QSTAGE(0, 0);
  __syncthreads();
  int cur = 0;
  for (int k0 = 0; k0 < 512; k0 += 64) {
    if (k0 < 448) QSTAGE(cur ^ 1, k0 + 64);
#pragma unroll
    for (int kk = 0; kk < 2; ++kk) {
      bf16x8 af[4], bff[4];
      const int pc = (kk * 4 + lg) ^ (lq & 7);
#pragma unroll
      for (int f = 0; f < 4; ++f) {
        af[f]  = *reinterpret_cast<const bf16x8*>(&sA[cur][(wm * 64 + f * 16 + lq) * 64 + pc * 8]);
        bff[f] = *reinterpret_cast<const bf16x8*>(&sB[cur][(wn * 64 + f * 16 + lq) * 64 + pc * 8]);
      }
#pragma unroll
      for (int i = 0; i < 4; ++i)
#pragma unroll
        for (int j = 0; j < 4; ++j)
          acc[i][j] = __builtin_amdgcn_mfma_f32_16x16x32_bf16(af[i], bff[j], acc[i][j], 0, 0, 0);
    }
    __syncthreads();
    cur ^= 1;
  }
#undef QSTAGE

  if (n0 >= 1024) {
    // ---- V block: transpose 128(m) x 128(c) through XOR-swizzled LDS, write Vt coalesced ----
    u16* T = (u16*)&sA[0][0];
#pragma unroll
    for (int j = 0; j < 4; ++j) {
      int c = wn * 64 + j * 16 + lq;
#pragma unroll
      for (int i = 0; i < 4; ++i) {
        int mb = wm * 64 + i * 16 + lg * 4;
        u16x4 pw;
#pragma unroll
        for (int r = 0; r < 4; ++r) pw[r] = f2bf(acc[i][j][r]);
        *reinterpret_cast<u16x4*>(&T[c * 128 + ((((mb >> 3) ^ lq) << 3) | (mb & 7))]) = pw;
      }
    }
    __syncthreads();
    int c = t & 127;
    int ch0 = (t >> 7) << 3;
    int cg = n0 + c - 1024;
    int h = cg >> 6, d = cg & 63;
    int bb = m0 / NP;
    int nb = m0 - bb * NP;
    u16* dst = Vt + (((size_t)(bb * H_ + h) * HD + d) * NP + nb);
#pragma unroll
    for (int rep = 0; rep < 8; ++rep) {
      int chunk = ch0 + rep;
      u16x8 vv = *reinterpret_cast<const u16x8*>(&T[c * 128 + ((chunk ^ (c & 15)) << 3)]);
      *reinterpret_cast<u16x8*>(&dst[chunk * 8]) = vv;
    }
  } else {
#pragma unroll
    for (int j = 0; j < 4; ++j) {
      int c = n0 + wn * 64 + j * 16 + lq;
      int which = c >> 9, h = (c >> 6) & 7, d = c & 63;
#pragma unroll
      for (int i = 0; i < 4; ++i) {
        int mbase = m0 + wm * 64 + i * 16 + lg * 4;
#pragma unroll
        for (int r = 0; r < 4; ++r) {
          int m = mbase + r;
          int b = m / NP, n = m - b * NP;
          int bh = b * H_ + h;
          float v = acc[i][j][r];
          if (which == 0) Q[((size_t)bh * NP + n) * HD + d] = f2bf(v * 0.18033688f); // 0.125*log2(e)
          else            K[((size_t)bh * NP + n) * HD + d] = f2bf(v);
        }
      }
    }
  }
}

// ---------------- K4: flash attention, 4 waves x 32 q-rows, KVBLK=32, 24KB LDS ----------------
__global__ __launch_bounds__(256) void k_attn(const u16* __restrict__ Q, const u16* __restrict__ K,
                                              const u16* __restrict__ Vt, const u16* __restrict__ am,
                                              u16* __restrict__ O) {
  __shared__ u16 sK[2][32 * 64];   // [kv][d]
  __shared__ u16 sV[2][64 * 32];   // [d][kv]
  __shared__ u16 sP[4][32 * 32];   // per-wave P: rows 0..15 = group A, 16..31 = group B

  int bid = blockIdx.x;
  int wg = (bid & 7) * (9 * 128 / 8) + (bid >> 3);   // XCD swizzle (1152 % 8 == 0)
  int bh = wg / 9, qt = wg - bh * 9;
  int b = bh >> 3, h = bh & 7;
  int t = threadIdx.x;
  int w = t >> 6, lane = t & 63;
  int lq = lane & 15, lg = lane >> 4;
  int qbase = qt * 128 + w * 32;
  int qg0 = qt * 8 + w * 2;
  const u16* Qp = Q + ((size_t)bh * NP + qbase) * HD;
  const u16* Kp = K + (size_t)bh * NP * HD;
  const u16* Vp = Vt + (size_t)bh * HD * NP;
  const u16* ampA = am + ((size_t)qg0 * NT32 * 64 + lane) * 8;
  const u16* ampB = am + ((size_t)(qg0 + 1) * NT32 * 64 + lane) * 8;

  bf16x8 qfA0 = *reinterpret_cast<const bf16x8*>(Qp + lq * HD + lg * 8);
  bf16x8 qfA1 = *reinterpret_cast<const bf16x8*>(Qp + lq * HD + 32 + lg * 8);
  bf16x8 qfB0 = *reinterpret_cast<const bf16x8*>(Qp + (16 + lq) * HD + lg * 8);
  bf16x8 qfB1 = *reinterpret_cast<const bf16x8*>(Qp + (16 + lq) * HD + 32 + lg * 8);

  // staging: K tile 32x64 = 256 chunks; V tile 64x32 = 256 chunks; thread t does one of each
  const int rK = t >> 3, cK = (t & 7) ^ (rK & 7);
  const int rV = t >> 2, cV = (t & 3) ^ (rV & 3);

  f32x4 oaccA[4] = {}, oaccB[4] = {};
  float lpA = 0.f, lpB = 0.f;

#define STAGE(buf, kv0_)                                                        \
  {                                                                             \
    gload16(Kp + (size_t)((kv0_) + rK) * HD + cK * 8, &sK[buf][t * 8]);         \
    gload16(Vp + (size_t)rV * NP + (kv0_) + cV * 8,   &sV[buf][t * 8]);         \
  }

#define AML(an, ti_)                                                            \
  {                                                                             \
    an[0] = *reinterpret_cast<const u16x8*>(ampA + (size_t)(ti_) * 64 * 8);     \
    an[1] = *reinterpret_cast<const u16x8*>(ampB + (size_t)(ti_) * 64 * 8);     \
  }

#define COMPUTE(buf, an)                                                         \
  {                                                                              \
    f32x4 s0[2], s1[2];                                                          \
    _Pragma("unroll")                                                            \
    for (int f = 0; f < 2; ++f) {                                                \
      _Pragma("unroll")                                                          \
      for (int r = 0; r < 4; ++r) {                                              \
        s0[f][r] = __uint_as_float(((uint32_t)(u16)an[0][f * 4 + r]) << 16);     \
        s1[f][r] = __uint_as_float(((uint32_t)(u16)an[1][f * 4 + r]) << 16);     \
      }                                                                          \
    }                                                                            \
    __builtin_amdgcn_s_setprio(1);                                               \
    _Pragma("unroll")                                                            \
    for (int kk = 0; kk < 2; ++kk) {                                             \
      bf16x8 qa = kk ? qfA1 : qfA0;                                              \
      bf16x8 qb = kk ? qfB1 : qfB0;                                              \
      int pc = (kk * 4 + lg) ^ (lq & 7);                                         \
      _Pragma("unroll")                                                          \
      for (int f = 0; f < 2; ++f) {                                              \
        bf16x8 kf = *reinterpret_cast<const bf16x8*>(&sK[buf][(f * 16 + lq) * 64 + pc * 8]); \
        s0[f] = __builtin_amdgcn_mfma_f32_16x16x32_bf16(kf, qa, s0[f], 0, 0, 0); \
        s1[f] = __builtin_amdgcn_mfma_f32_16x16x32_bf16(kf, qb, s1[f], 0, 0, 0); \
      }                                                                          \
    }                                                                            \
    __builtin_amdgcn_s_setprio(0);                                               \
    _Pragma("unroll")                                                            \
    for (int f = 0; f < 2; ++f) {                                                \
      _Pragma("unroll")                                                          \
      for (int r = 0; r < 4; ++r) {                                              \
        float pa = exp2a(s0[f][r]); s0[f][r] = pa; lpA += pa;                    \
        float pb = exp2a(s1[f][r]); s1[f][r] = pb; lpB += pb;                    \
      }                                                                          \
    }                                                                            \
    _Pragma("unroll")                                                            \
    for (int f = 0; f < 2; ++f) {                                                \
      int pcw = (2 * f + (lg >> 1)) ^ (lq & 3);                                  \
      uint2 pw;                                                                  \
      pw.x = cvtpk(s0[f][0], s0[f][1]);                                          \
      pw.y = cvtpk(s0[f][2], s0[f][3]);                                          \
      *reinterpret_cast<uint2*>(&sP[w][lq * 32 + pcw * 8 + (lg & 1) * 4]) = pw;  \
      pw.x = cvtpk(s1[f][0], s1[f][1]);                                          \
      pw.y = cvtpk(s1[f][2], s1[f][3]);                                          \
      *reinterpret_cast<uint2*>(&sP[w][512 + lq * 32 + pcw * 8 + (lg & 1) * 4]) = pw; \
    }                                                                            \
    __builtin_amdgcn_s_setprio(1);                                               \
    {                                                                            \
      int pcp = lg ^ (lq & 3);                                                   \
      bf16x8 pfA = *reinterpret_cast<const bf16x8*>(&sP[w][lq * 32 + pcp * 8]);  \
      bf16x8 pfB = *reinterpret_cast<const bf16x8*>(&sP[w][512 + lq * 32 + pcp * 8]); \
      _Pragma("unroll")                                                          \
      for (int j = 0; j < 4; ++j) {                                              \
        bf16x8 vf = *reinterpret_cast<const bf16x8*>(&sV[buf][(j * 16 + lq) * 32 + pcp * 8]); \
        oaccA[j] = __builtin_amdgcn_mfma_f32_16x16x32_bf16(pfA, vf, oaccA[j], 0, 0, 0); \
        oaccB[j] = __builtin_amdgcn_mfma_f32_16x16x32_bf16(pfB, vf, oaccB[j], 0, 0, 0); \
      }                                                                          \
    }                                                                            \
    __builtin_amdgcn_s_setprio(0);                                               \
  }

// pipelined step: stage tile ti+1 (2 loads) + amask ti+1 (2 loads); keep 4 in flight
#define STEP(bufb, ac, an, ti_)                                                  \
  {                                                                              \
    STAGE((bufb) ^ 1, ((ti_) + 1) * 32);                                         \
    AML(an, (ti_) + 1);                                                          \
    asm volatile("s_waitcnt vmcnt(4)" ::: "memory");                             \
    __builtin_amdgcn_s_barrier();                                                \
    COMPUTE(bufb, ac);                                                           \
    __builtin_amdgcn_s_barrier();                                                \
  }

  u16x8 a0[2], a1[2];
  STAGE(0, 0);
  AML(a0, 0);
  for (int tp = 0; tp < 16; ++tp) {      // tiles 0..31
    STEP(0, a0, a1, 2 * tp);
    STEP(1, a1, a0, 2 * tp + 1);
  }
  STEP(0, a0, a1, 32);                   // tile 32, stages tile 33
  asm volatile("s_waitcnt vmcnt(0)" ::: "memory");
  __builtin_amdgcn_s_barrier();
  COMPUTE(1, a1);                        // tile 33
#undef STAGE
#undef AML
#undef COMPUTE
#undef STEP

  // deferred l reduction per group
  lpA += __shfl_xor(lpA, 16);
  lpA += __shfl_xor(lpA, 32);
  lpB += __shfl_xor(lpB, 16);
  lpB += __shfl_xor(lpB, 32);

#pragma unroll
  for (int r = 0; r < 4; ++r) {
    float lrA = __shfl(lpA, 4 * lg + r);
    float lrB = __shfl(lpB, 4 * lg + r);
    float liA = (lrA > 0.f) ? 1.f / lrA : 0.f;
    float liB = (lrB > 0.f) ? 1.f / lrB : 0.f;
    size_t rowA = (size_t)b * NP + qbase + 4 * lg + r;
    size_t rowB = rowA + 16;
#pragma unroll
    for (int j = 0; j < 4; ++j) {
      O[rowA * D_ + h * HD + j * 16 + lq] = f2bf(oaccA[j][r] * liA);
      O[rowB * D_ + h * HD + j * 16 + lq] = f2bf(oaccB[j][r] * liB);
    }
  }
}

// ---------------- K5: proj GEMM + bias -> fp32 (padded M), 2-phase dbuf ----------------
__global__ __launch_bounds__(256) void k_proj(const u16* __restrict__ ob, const u16* __restrict__ wtp,
                                              const float* __restrict__ bias, float* __restrict__ oproj) {
  __shared__ u16 sA[2][128 * 64];
  __shared__ u16 sB[2][128 * 64];
  const int m0 = blockIdx.y * 128;
  const int n0 = blockIdx.x * 128;
  const int t = threadIdx.x;
  const int wave = t >> 6, lane = t & 63;
  const int wm = wave >> 1, wn = wave & 1;
  const int lq = lane & 15, lg = lane >> 4;

  const int srow = lane >> 3;
  const int schunk = (lane & 7) ^ srow;

  f32x4 acc[4][4] = {};

#define PSTAGE(buf, k0_)                                                          \
  {                                                                               \
    _Pragma("unroll")                                                             \
    for (int p = 0; p < 4; ++p) {                                                 \
      int row = p * 32 + wave * 8 + srow;                                         \
      gload16(ob + (size_t)(m0 + row) * 512 + (k0_) + schunk * 8,                 \
              &sA[buf][p * 2048 + wave * 512 + lane * 8]);                        \
      gload16(wtp + (size_t)(n0 + row) * 512 + (k0_) + schunk * 8,                \
              &sB[buf][p * 2048 + wave * 512 + lane * 8]);                        \
    }                                                                             \
  }

  PSTAGE(0, 0);
  __syncthreads();
  int cur = 0;
  for (int k0 = 0; k0 < 512; k0 += 64) {
    if (k0 < 448) PSTAGE(cur ^ 1, k0 + 64);
#pragma unroll
    for (int kk = 0; kk < 2; ++kk) {
      bf16x8 af[4], bff[4];
      const int pc = (kk * 4 + lg) ^ (lq & 7);
#pragma unroll
      for (int f = 0; f < 4; ++f) {
        af[f]  = *reinterpret_cast<const bf16x8*>(&sA[cur][(wm * 64 + f * 16 + lq) * 64 + pc * 8]);
        bff[f] = *reinterpret_cast<const bf16x8*>(&sB[cur][(wn * 64 + f * 16 + lq) * 64 + pc * 8]);
      }
#pragma unroll
      for (int i = 0; i < 4; ++i)
#pragma unroll
        for (int j = 0; j < 4; ++j)
          acc[i][j] = __builtin_amdgcn_mfma_f32_16x16x32_bf16(af[i], bff[j], acc[i][j], 0, 0, 0);
    }
    __syncthreads();
    cur ^= 1;
  }
#undef PSTAGE

#pragma unroll
  for (int j = 0; j < 4; ++j) {
    int c = n0 + wn * 64 + j * 16 + lq;
    float bv = bias[c];
#pragma unroll
    for (int i = 0; i < 4; ++i) {
      int mbase = m0 + wm * 64 + i * 16 + lg * 4;
#pragma unroll
      for (int r = 0; r < 4; ++r) {
        int m = mbase + r;
        oproj[(size_t)m * D_ + c] = acc[i][j][r] + bv;
      }
    }
  }
}

// ---------------- K6: LN + residual (reads padded, writes real) ----------------
__global__ __launch_bounds__(256) void k_ln(const float* __restrict__ op, const float* __restrict__ gamma,
                                            const float* __restrict__ beta, float* __restrict__ out) {
  int row = blockIdx.x;
  int b = row / N_, n = row - b * N_;
  int t = threadIdx.x;
  const float* r = op + ((size_t)b * NP + n) * D_;
  float v0 = r[t], v1 = r[t + 256];
  float s = v0 + v1, sq = v0 * v0 + v1 * v1;
#pragma unroll
  for (int off = 1; off < 64; off <<= 1) { s += __shfl_xor(s, off); sq += __shfl_xor(sq, off); }
  __shared__ float ls[4], lsq[4];
  int wave = t >> 6, lane = t & 63;
  if (lane == 0) { ls[wave] = s; lsq[wave] = sq; }
  __syncthreads();
  float S = ls[0] + ls[1] + ls[2] + ls[3];
  float SQ = lsq[0] + lsq[1] + lsq[2] + lsq[3];
  float mu = S * (1.f / 512.f);
  float var = SQ * (1.f / 512.f) - mu * mu;
  float rinv = rsqrtf(var + 1e-5f);
  float g0 = gamma[t], g1 = gamma[t + 256], b0 = beta[t], b1 = beta[t + 256];
  out[(size_t)row * D_ + t]       = v0 + (v0 - mu) * rinv * g0 + b0;
  out[(size_t)row * D_ + t + 256] = v1 + (v1 - mu) * rinv * g1 + b1;
}

extern "C" void kernel_launch(void* const* d_in, const int* in_sizes, int n_in,
                              void* d_out, int out_size, void* d_ws, size_t ws_size,
                              hipStream_t stream) {
  const float* x     = (const float*)d_in[0];
  const float* wqkv  = (const float*)d_in[1];
  const float* wproj = (const float*)d_in[2];
  const float* bproj = (const float*)d_in[3];
  const float* gamma = (const float*)d_in[4];
  const float* beta  = (const float*)d_in[5];
  const float* mask  = (const float*)d_in[6];
  float* out = (float*)d_out;

  char* ws = (char*)d_ws;
  size_t off = 0;
  auto alloc = [&](size_t bytes) {
    void* p = ws + off;
    off = (off + bytes + 255) & ~(size_t)255;
    return p;
  };
  uint32_t* bmask = (uint32_t*)alloc((size_t)NP * WM * 4);
  u16* am   = (u16*)alloc((size_t)NQG * NT32 * 64 * 8 * 2);
  u16* wtq  = (u16*)alloc((size_t)3 * D_ * D_ * 2);
  u16* wtp  = (u16*)alloc((size_t)D_ * D_ * 2);
  u16* xb   = (u16*)alloc((size_t)MP * D_ * 2);
  u16* Qb   = (u16*)alloc((size_t)128 * NP * HD * 2);
  u16* Kb   = (u16*)alloc((size_t)128 * NP * HD * 2);
  u16* Vtb  = (u16*)alloc((size_t)128 * HD * NP * 2);
  u16* Ob   = (u16*)alloc((size_t)MP * D_ * 2);
  float* oproj = (float*)alloc((size_t)MP * D_ * 4);

  k_bitmask<<<dim3(NP), dim3(256), 0, stream>>>(mask, bmask);
  k_amask<<<dim3(NQG, NT32), dim3(64), 0, stream>>>(bmask, am);
  k_wconv<<<dim3(3072), dim3(256), 0, stream>>>(wqkv, wproj, wtq, wtp);
  k_xconv<<<dim3(MP * D_ / (256 * 8)), dim3(256), 0, stream>>>(x, xb);
  k_qkv<<<dim3(12, MP / 128), dim3(256), 0, stream>>>(xb, wtq, Qb, Kb, Vtb);
  k_attn<<<dim3(9 * 128), dim3(256), 0, stream>>>(Qb, Kb, Vtb, am, Ob);
  k_proj<<<dim3(4, MP / 128), dim3(256), 0, stream>>>(Ob, wtp, bproj, oproj);
  k_ln<<<dim3(M_), dim3(256), 0, stream>>>(oproj, gamma, beta, out);
}

// Round 9
// 187.013 us; speedup vs baseline: 1.0810x; 1.0289x over previous
//
#include <hip/hip_runtime.h>
#include <stdint.h>

#define B_ 16
#define N_ 1025
#define D_ 512
#define H_ 8
#define HD 64
#define NP 1152           // padded N: 9*128 (q side)
#define WM 36             // bitmask u32 words per row
#define M_ (B_*N_)        // 16400 (real rows)
#define MP (B_*NP)        // 18432 = 144*128 padded rows
#define NTKV 17           // KV tiles of 64 (17*64=1088 >= 1025)
#define NQG 72            // q-groups of 16 (NP/16)

typedef unsigned short u16;
typedef __attribute__((ext_vector_type(8))) short bf16x8;
typedef __attribute__((ext_vector_type(4))) u16 u16x4;
typedef __attribute__((ext_vector_type(8))) u16 u16x8;
typedef __attribute__((ext_vector_type(4))) float f32x4;

typedef __attribute__((address_space(1))) const uint32_t gld_t;
typedef __attribute__((address_space(3))) uint32_t lds_t;

__device__ __forceinline__ u16 f2bf(float f) {
  uint32_t u = __float_as_uint(f);
  u += 0x7FFFu + ((u >> 16) & 1u);   // RNE
  return (u16)(u >> 16);
}

__device__ __forceinline__ uint32_t cvtpk(float a, float b) {
  uint32_t r;
  asm("v_cvt_pk_bf16_f32 %0, %1, %2" : "=v"(r) : "v"(a), "v"(b));
  return r;
}

__device__ __forceinline__ float exp2a(float x) {   // bare v_exp_f32 (no OCML fixup)
  float r;
  asm("v_exp_f32 %0, %1\n\ts_nop 0" : "=v"(r) : "v"(x));
  return r;
}

__device__ __forceinline__ void gload16(const void* g, void* l) {
  __builtin_amdgcn_global_load_lds((gld_t*)g, (lds_t*)l, 16, 0, 0);
}

// ---------------- K0: pack attn_mask into bitmask [NP][WM] u32 ----------------
__global__ void k_bitmask(const float* __restrict__ mask, uint32_t* __restrict__ bm) {
  int r = blockIdx.x;
  int wave = threadIdx.x >> 6, lane = threadIdx.x & 63;
  for (int chunk = wave; chunk < 18; chunk += 4) {
    int kv = chunk * 64 + lane;
    bool pred = (r < N_) && (kv < N_) && (mask[(size_t)r * N_ + kv] != 0.0f);
    unsigned long long bal = __ballot(pred);
    if (lane == 0) {
      bm[r * WM + chunk * 2]     = (uint32_t)bal;
      bm[r * WM + chunk * 2 + 1] = (uint32_t)(bal >> 32);
    }
  }
}

// ---------------- K0b: additive mask in MFMA C-fragment layout (f32, KVBLK=64) ----------------
__global__ __launch_bounds__(64) void k_amask(const uint32_t* __restrict__ bm, float* __restrict__ am) {
  int qg = blockIdx.x, ti = blockIdx.y;
  int lane = threadIdx.x;
  int lq = lane & 15, lg = lane >> 4;
  int q = qg * 16 + lq;
  size_t base = ((size_t)(qg * NTKV + ti) * 64 + lane) * 16;
#pragma unroll
  for (int f = 0; f < 4; ++f) {
    f32x4 o;
#pragma unroll
    for (int r = 0; r < 4; ++r) {
      int kv = ti * 64 + f * 16 + 4 * lg + r;
      uint32_t bit = (bm[q * WM + (kv >> 5)] >> (kv & 31)) & 1u;
      o[r] = bit ? 0.f : -30000.f;
    }
    *reinterpret_cast<f32x4*>(am + base + f * 4) = o;
  }
}

// ---------------- K1: convert+transpose weights to bf16 ----------------
__global__ void k_wconv(const float* __restrict__ wqkv, const float* __restrict__ wproj,
                        u16* __restrict__ wtq, u16* __restrict__ wtp) {
  int idx = blockIdx.x * 256 + threadIdx.x;
  if (idx < 3 * D_ * D_) {
    int k = idx / (3 * D_), c = idx % (3 * D_);
    wtq[c * D_ + k] = f2bf(wqkv[idx]);
  }
  if (idx < D_ * D_) {
    int k = idx >> 9, c = idx & 511;
    wtp[c * D_ + k] = f2bf(wproj[idx]);
  }
}

// ---------------- K2: x -> bf16, padded [B][NP][D], padded rows zeroed ----------------
__global__ void k_xconv(const float* __restrict__ x, u16* __restrict__ xb) {
  int i = blockIdx.x * 256 + threadIdx.x;
  int idx = i * 8;
  int pr = idx >> 9;
  int col = idx & 511;
  int b = pr / NP, n = pr - b * NP;
  u16x8 o;
  if (n < N_) {
    const float* src = x + ((size_t)b * N_ + n) * D_ + col;
    float4 v0 = *reinterpret_cast<const float4*>(src);
    float4 v1 = *reinterpret_cast<const float4*>(src + 4);
    o[0] = f2bf(v0.x); o[1] = f2bf(v0.y); o[2] = f2bf(v0.z); o[3] = f2bf(v0.w);
    o[4] = f2bf(v1.x); o[5] = f2bf(v1.y); o[6] = f2bf(v1.z); o[7] = f2bf(v1.w);
  } else {
    o = (u16x8){0,0,0,0,0,0,0,0};
  }
  *reinterpret_cast<u16x8*>(xb + idx) = o;
}

// ---------------- K3: QKV GEMM, counted-vmcnt pipeline -> Q (scaled), K, Vt ----------------
__global__ __launch_bounds__(256) void k_qkv(const u16* __restrict__ xb, const u16* __restrict__ wtq,
                                             u16* __restrict__ Q, u16* __restrict__ K,
                                             u16* __restrict__ Vt) {
  __shared__ u16 sA[2][128 * 64];
  __shared__ u16 sB[2][128 * 64];
  const int m0 = blockIdx.y * 128;
  const int n0 = blockIdx.x * 128;
  const int t = threadIdx.x;
  const int wave = t >> 6, lane = t & 63;
  const int wm = wave >> 1, wn = wave & 1;
  const int lq = lane & 15, lg = lane >> 4;

  const int srow = lane >> 3;
  const int schunk = (lane & 7) ^ srow;

  f32x4 acc[4][4] = {};

#define QSTAGE(buf, k0_)                                                          \
  {                                                                               \
    _Pragma("unroll")                                                             \
    for (int p = 0; p < 4; ++p) {                                                 \
      int row = p * 32 + wave * 8 + srow;                                         \
      gload16(xb + (size_t)(m0 + row) * 512 + (k0_) + schunk * 8,                 \
              &sA[buf][p * 2048 + wave * 512 + lane * 8]);                        \
      gload16(wtq + (size_t)(n0 + row) * 512 + (k0_) + schunk * 8,                \
              &sB[buf][p * 2048 + wave * 512 + lane * 8]);                        \
    }                                                                             \
  }

#define QCOMPUTE(buf)                                                             \
  {                                                                               \
    _Pragma("unroll")                                                             \
    for (int kk = 0; kk < 2; ++kk) {                                              \
      bf16x8 af[4], bff[4];                                                       \
      const int pc = (kk * 4 + lg) ^ (lq & 7);                                    \
      _Pragma("unroll")                                                           \
      for (int f = 0; f < 4; ++f) {                                               \
        af[f]  = *reinterpret_cast<const bf16x8*>(&sA[buf][(wm * 64 + f * 16 + lq) * 64 + pc * 8]); \
        bff[f] = *reinterpret_cast<const bf16x8*>(&sB[buf][(wn * 64 + f * 16 + lq) * 64 + pc * 8]); \
      }                                                                           \
      _Pragma("unroll")                                                           \
      for (int i = 0; i < 4; ++i)                                                 \
        _Pragma("unroll")                                                         \
        for (int j = 0; j < 4; ++j)                                               \
          acc[i][j] = __builtin_amdgcn_mfma_f32_16x16x32_bf16(af[i], bff[j], acc[i][j], 0, 0, 0); \
    }                                                                             \
  }

  QSTAGE(0, 0);
  int cur = 0;
  for (int k0 = 0; k0 < 448; k0 += 64) {
    QSTAGE(cur ^ 1, k0 + 64);
    asm volatile("s_waitcnt vmcnt(8)" ::: "memory");   // tile-k0's 8 loads done; next 8 in flight
    __builtin_amdgcn_s_barrier();
    QCOMPUTE(cur);
    __builtin_amdgcn_s_barrier();
    cur ^= 1;
  }
  asm volatile("s_waitcnt vmcnt(0)" ::: "memory");
  __builtin_amdgcn_s_barrier();
  QCOMPUTE(cur);
#undef QSTAGE
#undef QCOMPUTE

  if (n0 >= 1024) {
    // ---- V block: transpose 128(m) x 128(c) through XOR-swizzled LDS, write Vt coalesced ----
    __syncthreads();                    // all waves done reading sA before scratch reuse
    u16* T = (u16*)&sA[0][0];
#pragma unroll
    for (int j = 0; j < 4; ++j) {
      int c = wn * 64 + j * 16 + lq;
#pragma unroll
      for (int i = 0; i < 4; ++i) {
        int mb = wm * 64 + i * 16 + lg * 4;
        u16x4 pw;
#pragma unroll
        for (int r = 0; r < 4; ++r) pw[r] = f2bf(acc[i][j][r]);
        *reinterpret_cast<u16x4*>(&T[c * 128 + ((((mb >> 3) ^ lq) << 3) | (mb & 7))]) = pw;
      }
    }
    __syncthreads();
    int c = t & 127;
    int ch0 = (t >> 7) << 3;
    int cg = n0 + c - 1024;
    int h = cg >> 6, d = cg & 63;
    int bb = m0 / NP;
    int nb = m0 - bb * NP;
    u16* dst = Vt + (((size_t)(bb * H_ + h) * HD + d) * NP + nb);
#pragma unroll
    for (int rep = 0; rep < 8; ++rep) {
      int chunk = ch0 + rep;
      u16x8 vv = *reinterpret_cast<const u16x8*>(&T[c * 128 + ((chunk ^ (c & 15)) << 3)]);
      *reinterpret_cast<u16x8*>(&dst[chunk * 8]) = vv;
    }
  } else {
#pragma unroll
    for (int j = 0; j < 4; ++j) {
      int c = n0 + wn * 64 + j * 16 + lq;
      int which = c >> 9, h = (c >> 6) & 7, d = c & 63;
#pragma unroll
      for (int i = 0; i < 4; ++i) {
        int mbase = m0 + wm * 64 + i * 16 + lg * 4;
#pragma unroll
        for (int r = 0; r < 4; ++r) {
          int m = mbase + r;
          int b = m / NP, n = m - b * NP;
          int bh = b * H_ + h;
          float v = acc[i][j][r];
          if (which == 0) Q[((size_t)bh * NP + n) * HD + d] = f2bf(v * 0.18033688f); // 0.125*log2(e)
          else            K[((size_t)bh * NP + n) * HD + d] = f2bf(v);
        }
      }
    }
  }
}

// ---------------- K4: flash attention (round-6 verified config) ----------------
// 8 waves, QBLK=128, KVBLK=64, counted-vmcnt, f32 amask C-init
__global__ __launch_bounds__(512) void k_attn(const u16* __restrict__ Q, const u16* __restrict__ K,
                                              const u16* __restrict__ Vt, const float* __restrict__ am,
                                              u16* __restrict__ O) {
  __shared__ u16 sK[2][64 * 64];
  __shared__ u16 sV[2][64 * 64];
  __shared__ u16 sP[8][16 * 64];

  int bid = blockIdx.x;
  int wg = (bid & 7) * (9 * 128 / 8) + (bid >> 3);   // XCD swizzle (1152 % 8 == 0)
  int bh = wg / 9, qt = wg - bh * 9;
  int b = bh >> 3, h = bh & 7;
  int t = threadIdx.x;
  int w = t >> 6, lane = t & 63;
  int lq = lane & 15, lg = lane >> 4;
  int qbase = qt * 128 + w * 16;
  int qg = qt * 8 + w;
  const u16* Qp = Q + ((size_t)bh * NP + qbase) * HD;
  const u16* Kp = K + (size_t)bh * NP * HD;
  const u16* Vp = Vt + (size_t)bh * HD * NP;
  const float* amp = am + ((size_t)qg * NTKV * 64 + lane) * 16;

  bf16x8 qf0 = *reinterpret_cast<const bf16x8*>(Qp + lq * HD + lg * 8);
  bf16x8 qf1 = *reinterpret_cast<const bf16x8*>(Qp + lq * HD + 32 + lg * 8);

  const int srow = t >> 3, sch = (t & 7) ^ (srow & 7);

  f32x4 oacc[4] = {};
  float lpart = 0.f;

#define STAGE(buf, kv0_)                                                        \
  {                                                                             \
    gload16(Kp + (size_t)((kv0_) + srow) * HD + sch * 8, &sK[buf][t * 8]);      \
    gload16(Vp + (size_t)srow * NP + (kv0_) + sch * 8,   &sV[buf][t * 8]);      \
  }

#define AML(an, ti_)                                                            \
  {                                                                             \
    const f32x4* ap = reinterpret_cast<const f32x4*>(amp + (size_t)(ti_) * 64 * 16); \
    an[0] = ap[0]; an[1] = ap[1]; an[2] = ap[2]; an[3] = ap[3];                 \
  }

#define COMPUTE(buf, ac)                                                         \
  {                                                                              \
    f32x4 s[4] = {ac[0], ac[1], ac[2], ac[3]};   /* C-init = additive mask */    \
    __builtin_amdgcn_s_setprio(1);                                               \
    _Pragma("unroll")                                                            \
    for (int kk = 0; kk < 2; ++kk) {                                             \
      bf16x8 qf = kk ? qf1 : qf0;                                                \
      int pc = (kk * 4 + lg) ^ (lq & 7);                                         \
      _Pragma("unroll")                                                          \
      for (int f = 0; f < 4; ++f) {                                              \
        bf16x8 kf = *reinterpret_cast<const bf16x8*>(&sK[buf][(f * 16 + lq) * 64 + pc * 8]); \
        s[f] = __builtin_amdgcn_mfma_f32_16x16x32_bf16(kf, qf, s[f], 0, 0, 0);   \
      }                                                                          \
    }                                                                            \
    __builtin_amdgcn_s_setprio(0);                                               \
    _Pragma("unroll")                                                            \
    for (int f = 0; f < 4; ++f) {                                                \
      _Pragma("unroll")                                                          \
      for (int r = 0; r < 4; ++r) {                                              \
        float pv = exp2a(s[f][r]);                                               \
        s[f][r] = pv;                                                            \
        lpart += pv;                                                             \
      }                                                                          \
    }                                                                            \
    _Pragma("unroll")                                                            \
    for (int f = 0; f < 4; ++f) {                                                \
      uint2 pw;                                                                  \
      pw.x = cvtpk(s[f][0], s[f][1]);                                            \
      pw.y = cvtpk(s[f][2], s[f][3]);                                            \
      int pch = (2 * f + (lg >> 1)) ^ (lq & 7);                                  \
      *reinterpret_cast<uint2*>(&sP[w][lq * 64 + pch * 8 + (lg & 1) * 4]) = pw;  \
    }                                                                            \
    __builtin_amdgcn_s_setprio(1);                                               \
    _Pragma("unroll")                                                            \
    for (int kk = 0; kk < 2; ++kk) {                                             \
      int pc = (kk * 4 + lg) ^ (lq & 7);                                         \
      bf16x8 pf = *reinterpret_cast<const bf16x8*>(&sP[w][lq * 64 + pc * 8]);    \
      _Pragma("unroll")                                                          \
      for (int j = 0; j < 4; ++j) {                                              \
        bf16x8 vf = *reinterpret_cast<const bf16x8*>(&sV[buf][(j * 16 + lq) * 64 + pc * 8]); \
        oacc[j] = __builtin_amdgcn_mfma_f32_16x16x32_bf16(pf, vf, oacc[j], 0, 0, 0); \
      }                                                                          \
    }                                                                            \
    __builtin_amdgcn_s_setprio(0);                                               \
  }

// pipelined step: stage tile ti+1 (2 loads) + amask ti+1 (4 loads); wait for tile-ti's 6
#define STEP(bufb, ac, an, ti_)                                                  \
  {                                                                              \
    STAGE((bufb) ^ 1, ((ti_) + 1) * 64);                                         \
    AML(an, (ti_) + 1);                                                          \
    asm volatile("s_waitcnt vmcnt(6)" ::: "memory");                             \
    __builtin_amdgcn_s_barrier();                                                \
    COMPUTE(bufb, ac);                                                           \
    __builtin_amdgcn_s_barrier();                                                \
  }

  f32x4 a0[4], a1[4];
  STAGE(0, 0);
  AML(a0, 0);
  for (int tp = 0; tp < 8; ++tp) {       // tiles 0..15
    STEP(0, a0, a1, 2 * tp);
    STEP(1, a1, a0, 2 * tp + 1);
  }
  // tile 16 (last): everything already staged into buf0, amask in a0
  asm volatile("s_waitcnt vmcnt(0)" ::: "memory");
  __builtin_amdgcn_s_barrier();
  COMPUTE(0, a0);
#undef STAGE
#undef AML
#undef COMPUTE
#undef STEP

  // deferred l reduction: combine the 4 lanes holding row lq
  lpart += __shfl_xor(lpart, 16);
  lpart += __shfl_xor(lpart, 32);

#pragma unroll
  for (int r = 0; r < 4; ++r) {
    int n = qbase + 4 * lg + r;
    float lr = __shfl(lpart, 4 * lg + r);
    float linv = (lr > 0.f) ? 1.f / lr : 0.f;
    size_t mrow = (size_t)b * NP + n;
#pragma unroll
    for (int j = 0; j < 4; ++j)
      O[mrow * D_ + h * HD + j * 16 + lq] = f2bf(oacc[j][r] * linv);
  }
}

// ---------------- K5: proj GEMM + bias -> fp32 (padded M), counted-vmcnt ----------------
__global__ __launch_bounds__(256) void k_proj(const u16* __restrict__ ob, const u16* __restrict__ wtp,
                                              const float* __restrict__ bias, float* __restrict__ oproj) {
  __shared__ u16 sA[2][128 * 64];
  __shared__ u16 sB[2][128 * 64];
  const int m0 = blockIdx.y * 128;
  const int n0 = blockIdx.x * 128;
  const int t = threadIdx.x;
  const int wave = t >> 6, lane = t & 63;
  const int wm = wave >> 1, wn = wave & 1;
  const int lq = lane & 15, lg = lane >> 4;

  const int srow = lane >> 3;
  const int schunk = (lane & 7) ^ srow;

  f32x4 acc[4][4] = {};

#define PSTAGE(buf, k0_)                                                          \
  {                                                                               \
    _Pragma("unroll")                                                             \
    for (int p = 0; p < 4; ++p) {                                                 \
      int row = p * 32 + wave * 8 + srow;                                         \
      gload16(ob + (size_t)(m0 + row) * 512 + (k0_) + schunk * 8,                 \
              &sA[buf][p * 2048 + wave * 512 + lane * 8]);                        \
      gload16(wtp + (size_t)(n0 + row) * 512 + (k0_) + schunk * 8,                \
              &sB[buf][p * 2048 + wave * 512 + lane * 8]);                        \
    }                                                                             \
  }

#define PCOMPUTE(buf)                                                             \
  {                                                                               \
    _Pragma("unroll")                                                             \
    for (int kk = 0; kk < 2; ++kk) {                                              \
      bf16x8 af[4], bff[4];                                                       \
      const int pc = (kk * 4 + lg) ^ (lq & 7);                                    \
      _Pragma("unroll")                                                           \
      for (int f = 0; f < 4; ++f) {                                               \
        af[f]  = *reinterpret_cast<const bf16x8*>(&sA[buf][(wm * 64 + f * 16 + lq) * 64 + pc * 8]); \
        bff[f] = *reinterpret_cast<const bf16x8*>(&sB[buf][(wn * 64 + f * 16 + lq) * 64 + pc * 8]); \
      }                                                                           \
      _Pragma("unroll")                                                           \
      for (int i = 0; i < 4; ++i)                                                 \
        _Pragma("unroll")                                                         \
        for (int j = 0; j < 4; ++j)                                               \
          acc[i][j] = __builtin_amdgcn_mfma_f32_16x16x32_bf16(af[i], bff[j], acc[i][j], 0, 0, 0); \
    }                                                                             \
  }

  PSTAGE(0, 0);
  int cur = 0;
  for (int k0 = 0; k0 < 448; k0 += 64) {
    PSTAGE(cur ^ 1, k0 + 64);
    asm volatile("s_waitcnt vmcnt(8)" ::: "memory");
    __builtin_amdgcn_s_barrier();
    PCOMPUTE(cur);
    __builtin_amdgcn_s_barrier();
    cur ^= 1;
  }
  asm volatile("s_waitcnt vmcnt(0)" ::: "memory");
  __builtin_amdgcn_s_barrier();
  PCOMPUTE(cur);
#undef PSTAGE
#undef PCOMPUTE

#pragma unroll
  for (int j = 0; j < 4; ++j) {
    int c = n0 + wn * 64 + j * 16 + lq;
    float bv = bias[c];
#pragma unroll
    for (int i = 0; i < 4; ++i) {
      int mbase = m0 + wm * 64 + i * 16 + lg * 4;
#pragma unroll
      for (int r = 0; r < 4; ++r) {
        int m = mbase + r;
        oproj[(size_t)m * D_ + c] = acc[i][j][r] + bv;
      }
    }
  }
}

// ---------------- K6: LN + residual (reads padded, writes real) ----------------
__global__ __launch_bounds__(256) void k_ln(const float* __restrict__ op, const float* __restrict__ gamma,
                                            const float* __restrict__ beta, float* __restrict__ out) {
  int row = blockIdx.x;
  int b = row / N_, n = row - b * N_;
  int t = threadIdx.x;
  const float* r = op + ((size_t)b * NP + n) * D_;
  float v0 = r[t], v1 = r[t + 256];
  float s = v0 + v1, sq = v0 * v0 + v1 * v1;
#pragma unroll
  for (int off = 1; off < 64; off <<= 1) { s += __shfl_xor(s, off); sq += __shfl_xor(sq, off); }
  __shared__ float ls[4], lsq[4];
  int wave = t >> 6, lane = t & 63;
  if (lane == 0) { ls[wave] = s; lsq[wave] = sq; }
  __syncthreads();
  float S = ls[0] + ls[1] + ls[2] + ls[3];
  float SQ = lsq[0] + lsq[1] + lsq[2] + lsq[3];
  float mu = S * (1.f / 512.f);
  float var = SQ * (1.f / 512.f) - mu * mu;
  float rinv = rsqrtf(var + 1e-5f);
  float g0 = gamma[t], g1 = gamma[t + 256], b0 = beta[t], b1 = beta[t + 256];
  out[(size_t)row * D_ + t]       = v0 + (v0 - mu) * rinv * g0 + b0;
  out[(size_t)row * D_ + t + 256] = v1 + (v1 - mu) * rinv * g1 + b1;
}

extern "C" void kernel_launch(void* const* d_in, const int* in_sizes, int n_in,
                              void* d_out, int out_size, void* d_ws, size_t ws_size,
                              hipStream_t stream) {
  const float* x     = (const float*)d_in[0];
  const float* wqkv  = (const float*)d_in[1];
  const float* wproj = (const float*)d_in[2];
  const float* bproj = (const float*)d_in[3];
  const float* gamma = (const float*)d_in[4];
  const float* beta  = (const float*)d_in[5];
  const float* mask  = (const float*)d_in[6];
  float* out = (float*)d_out;

  char* ws = (char*)d_ws;
  size_t off = 0;
  auto alloc = [&](size_t bytes) {
    void* p = ws + off;
    off = (off + bytes + 255) & ~(size_t)255;
    return p;
  };
  uint32_t* bmask = (uint32_t*)alloc((size_t)NP * WM * 4);
  float* am  = (float*)alloc((size_t)NQG * NTKV * 64 * 16 * 4);
  u16* wtq  = (u16*)alloc((size_t)3 * D_ * D_ * 2);
  u16* wtp  = (u16*)alloc((size_t)D_ * D_ * 2);
  u16* xb   = (u16*)alloc((size_t)MP * D_ * 2);
  u16* Qb   = (u16*)alloc((size_t)128 * NP * HD * 2);
  u16* Kb   = (u16*)alloc((size_t)128 * NP * HD * 2);
  u16* Vtb  = (u16*)alloc((size_t)128 * HD * NP * 2);
  u16* Ob   = (u16*)alloc((size_t)MP * D_ * 2);
  float* oproj = (float*)alloc((size_t)MP * D_ * 4);

  k_bitmask<<<dim3(NP), dim3(256), 0, stream>>>(mask, bmask);
  k_amask<<<dim3(NQG, NTKV), dim3(64), 0, stream>>>(bmask, am);
  k_wconv<<<dim3(3072), dim3(256), 0, stream>>>(wqkv, wproj, wtq, wtp);
  k_xconv<<<dim3(MP * D_ / (256 * 8)), dim3(256), 0, stream>>>(x, xb);
  k_qkv<<<dim3(12, MP / 128), dim3(256), 0, stream>>>(xb, wtq, Qb, Kb, Vtb);
  k_attn<<<dim3(9 * 128), dim3(512), 0, stream>>>(Qb, Kb, Vtb, am, Ob);
  k_proj<<<dim3(4, MP / 128), dim3(256), 0, stream>>>(Ob, wtp, bproj, oproj);
  k_ln<<<dim3(M_), dim3(256), 0, stream>>>(oproj, gamma, beta, out);
}

// Round 10
// 179.805 us; speedup vs baseline: 1.1243x; 1.0401x over previous
//
#include <hip/hip_runtime.h>
#include <stdint.h>

#define B_ 16
#define N_ 1025
#define D_ 512
#define H_ 8
#define HD 64
#define NP 1152           // padded N: 9*128 (q side)
#define WM 36             // bitmask u32 words per row
#define M_ (B_*N_)        // 16400 (real rows)
#define MP (B_*NP)        // 18432 = 144*128 padded rows
#define NTKV 17           // KV tiles of 64 (17*64=1088 >= 1025)
#define NQG 72            // q-groups of 16 (NP/16)

typedef unsigned short u16;
typedef __attribute__((ext_vector_type(8))) short bf16x8;
typedef __attribute__((ext_vector_type(4))) u16 u16x4;
typedef __attribute__((ext_vector_type(8))) u16 u16x8;
typedef __attribute__((ext_vector_type(4))) float f32x4;

typedef __attribute__((address_space(1))) const uint32_t gld_t;
typedef __attribute__((address_space(3))) uint32_t lds_t;

__device__ __forceinline__ u16 f2bf(float f) {
  uint32_t u = __float_as_uint(f);
  u += 0x7FFFu + ((u >> 16) & 1u);   // RNE
  return (u16)(u >> 16);
}

__device__ __forceinline__ uint32_t cvtpk(float a, float b) {
  uint32_t r;
  asm("v_cvt_pk_bf16_f32 %0, %1, %2" : "=v"(r) : "v"(a), "v"(b));
  return r;
}

__device__ __forceinline__ float exp2a(float x) {   // bare v_exp_f32 (no OCML fixup)
  float r;
  asm("v_exp_f32 %0, %1\n\ts_nop 0" : "=v"(r) : "v"(x));
  return r;
}

__device__ __forceinline__ void gload16(const void* g, void* l) {
  __builtin_amdgcn_global_load_lds((gld_t*)g, (lds_t*)l, 16, 0, 0);
}

// ---------------- K0: pack attn_mask into bitmask [NP][WM] u32 ----------------
__global__ void k_bitmask(const float* __restrict__ mask, uint32_t* __restrict__ bm) {
  int r = blockIdx.x;
  int wave = threadIdx.x >> 6, lane = threadIdx.x & 63;
  for (int chunk = wave; chunk < 18; chunk += 4) {
    int kv = chunk * 64 + lane;
    bool pred = (r < N_) && (kv < N_) && (mask[(size_t)r * N_ + kv] != 0.0f);
    unsigned long long bal = __ballot(pred);
    if (lane == 0) {
      bm[r * WM + chunk * 2]     = (uint32_t)bal;
      bm[r * WM + chunk * 2 + 1] = (uint32_t)(bal >> 32);
    }
  }
}

// ---------------- K0b: additive mask in MFMA C-fragment layout (f32, KVBLK=64) ----------------
__global__ __launch_bounds__(64) void k_amask(const uint32_t* __restrict__ bm, float* __restrict__ am) {
  int qg = blockIdx.x, ti = blockIdx.y;
  int lane = threadIdx.x;
  int lq = lane & 15, lg = lane >> 4;
  int q = qg * 16 + lq;
  size_t base = ((size_t)(qg * NTKV + ti) * 64 + lane) * 16;
#pragma unroll
  for (int f = 0; f < 4; ++f) {
    f32x4 o;
#pragma unroll
    for (int r = 0; r < 4; ++r) {
      int kv = ti * 64 + f * 16 + 4 * lg + r;
      uint32_t bit = (bm[q * WM + (kv >> 5)] >> (kv & 31)) & 1u;
      o[r] = bit ? 0.f : -30000.f;
    }
    *reinterpret_cast<f32x4*>(am + base + f * 4) = o;
  }
}

// ---------------- K1: convert+transpose weights to bf16 ----------------
__global__ void k_wconv(const float* __restrict__ wqkv, const float* __restrict__ wproj,
                        u16* __restrict__ wtq, u16* __restrict__ wtp) {
  int idx = blockIdx.x * 256 + threadIdx.x;
  if (idx < 3 * D_ * D_) {
    int k = idx / (3 * D_), c = idx % (3 * D_);
    wtq[c * D_ + k] = f2bf(wqkv[idx]);
  }
  if (idx < D_ * D_) {
    int k = idx >> 9, c = idx & 511;
    wtp[c * D_ + k] = f2bf(wproj[idx]);
  }
}

// ---------------- K2: x -> bf16, padded [B][NP][D], padded rows zeroed ----------------
__global__ void k_xconv(const float* __restrict__ x, u16* __restrict__ xb) {
  int i = blockIdx.x * 256 + threadIdx.x;
  int idx = i * 8;
  int pr = idx >> 9;
  int col = idx & 511;
  int b = pr / NP, n = pr - b * NP;
  u16x8 o;
  if (n < N_) {
    const float* src = x + ((size_t)b * N_ + n) * D_ + col;
    float4 v0 = *reinterpret_cast<const float4*>(src);
    float4 v1 = *reinterpret_cast<const float4*>(src + 4);
    o[0] = f2bf(v0.x); o[1] = f2bf(v0.y); o[2] = f2bf(v0.z); o[3] = f2bf(v0.w);
    o[4] = f2bf(v1.x); o[5] = f2bf(v1.y); o[6] = f2bf(v1.z); o[7] = f2bf(v1.w);
  } else {
    o = (u16x8){0,0,0,0,0,0,0,0};
  }
  *reinterpret_cast<u16x8*>(xb + idx) = o;
}

// ---------------- K3: QKV GEMM, counted-vmcnt pipeline, XCD-swizzled grid ----------------
// flat grid 12*144 = 1728 blocks; each XCD gets 18 contiguous m-tiles (n fastest)
__global__ __launch_bounds__(256) void k_qkv(const u16* __restrict__ xb, const u16* __restrict__ wtq,
                                             u16* __restrict__ Q, u16* __restrict__ K,
                                             u16* __restrict__ Vt) {
  __shared__ u16 sA[2][128 * 64];
  __shared__ u16 sB[2][128 * 64];
  const int bid = blockIdx.x;
  const int wg = (bid & 7) * 216 + (bid >> 3);   // 1728/8 = 216, bijective
  const int m0 = (wg / 12) * 128;
  const int n0 = (wg % 12) * 128;
  const int t = threadIdx.x;
  const int wave = t >> 6, lane = t & 63;
  const int wm = wave >> 1, wn = wave & 1;
  const int lq = lane & 15, lg = lane >> 4;

  const int srow = lane >> 3;
  const int schunk = (lane & 7) ^ srow;

  f32x4 acc[4][4] = {};

#define QSTAGE(buf, k0_)                                                          \
  {                                                                               \
    _Pragma("unroll")                                                             \
    for (int p = 0; p < 4; ++p) {                                                 \
      int row = p * 32 + wave * 8 + srow;                                         \
      gload16(xb + (size_t)(m0 + row) * 512 + (k0_) + schunk * 8,                 \
              &sA[buf][p * 2048 + wave * 512 + lane * 8]);                        \
      gload16(wtq + (size_t)(n0 + row) * 512 + (k0_) + schunk * 8,                \
              &sB[buf][p * 2048 + wave * 512 + lane * 8]);                        \
    }                                                                             \
  }

#define QCOMPUTE(buf)                                                             \
  {                                                                               \
    _Pragma("unroll")                                                             \
    for (int kk = 0; kk < 2; ++kk) {                                              \
      bf16x8 af[4], bff[4];                                                       \
      const int pc = (kk * 4 + lg) ^ (lq & 7);                                    \
      _Pragma("unroll")                                                           \
      for (int f = 0; f < 4; ++f) {                                               \
        af[f]  = *reinterpret_cast<const bf16x8*>(&sA[buf][(wm * 64 + f * 16 + lq) * 64 + pc * 8]); \
        bff[f] = *reinterpret_cast<const bf16x8*>(&sB[buf][(wn * 64 + f * 16 + lq) * 64 + pc * 8]); \
      }                                                                           \
      _Pragma("unroll")                                                           \
      for (int i = 0; i < 4; ++i)                                                 \
        _Pragma("unroll")                                                         \
        for (int j = 0; j < 4; ++j)                                               \
          acc[i][j] = __builtin_amdgcn_mfma_f32_16x16x32_bf16(af[i], bff[j], acc[i][j], 0, 0, 0); \
    }                                                                             \
  }

  QSTAGE(0, 0);
  int cur = 0;
  for (int k0 = 0; k0 < 448; k0 += 64) {
    QSTAGE(cur ^ 1, k0 + 64);
    asm volatile("s_waitcnt vmcnt(8)" ::: "memory");   // tile-k0's 8 loads done; next 8 in flight
    __builtin_amdgcn_s_barrier();
    QCOMPUTE(cur);
    __builtin_amdgcn_s_barrier();
    cur ^= 1;
  }
  asm volatile("s_waitcnt vmcnt(0)" ::: "memory");
  __builtin_amdgcn_s_barrier();
  QCOMPUTE(cur);
#undef QSTAGE
#undef QCOMPUTE

  if (n0 >= 1024) {
    // ---- V block: transpose 128(m) x 128(c) through XOR-swizzled LDS, write Vt coalesced ----
    __syncthreads();                    // all waves done reading sA before scratch reuse
    u16* T = (u16*)&sA[0][0];
#pragma unroll
    for (int j = 0; j < 4; ++j) {
      int c = wn * 64 + j * 16 + lq;
#pragma unroll
      for (int i = 0; i < 4; ++i) {
        int mb = wm * 64 + i * 16 + lg * 4;
        u16x4 pw;
#pragma unroll
        for (int r = 0; r < 4; ++r) pw[r] = f2bf(acc[i][j][r]);
        *reinterpret_cast<u16x4*>(&T[c * 128 + ((((mb >> 3) ^ lq) << 3) | (mb & 7))]) = pw;
      }
    }
    __syncthreads();
    int c = t & 127;
    int ch0 = (t >> 7) << 3;
    int cg = n0 + c - 1024;
    int h = cg >> 6, d = cg & 63;
    int bb = m0 / NP;
    int nb = m0 - bb * NP;
    u16* dst = Vt + (((size_t)(bb * H_ + h) * HD + d) * NP + nb);
#pragma unroll
    for (int rep = 0; rep < 8; ++rep) {
      int chunk = ch0 + rep;
      u16x8 vv = *reinterpret_cast<const u16x8*>(&T[c * 128 + ((chunk ^ (c & 15)) << 3)]);
      *reinterpret_cast<u16x8*>(&dst[chunk * 8]) = vv;
    }
  } else {
#pragma unroll
    for (int j = 0; j < 4; ++j) {
      int c = n0 + wn * 64 + j * 16 + lq;
      int which = c >> 9, h = (c >> 6) & 7, d = c & 63;
#pragma unroll
      for (int i = 0; i < 4; ++i) {
        int mbase = m0 + wm * 64 + i * 16 + lg * 4;
#pragma unroll
        for (int r = 0; r < 4; ++r) {
          int m = mbase + r;
          int b = m / NP, n = m - b * NP;
          int bh = b * H_ + h;
          float v = acc[i][j][r];
          if (which == 0) Q[((size_t)bh * NP + n) * HD + d] = f2bf(v * 0.18033688f); // 0.125*log2(e)
          else            K[((size_t)bh * NP + n) * HD + d] = f2bf(v);
        }
      }
    }
  }
}

// ---------------- K4: flash attention (round-6 verified config) ----------------
// 8 waves, QBLK=128, KVBLK=64, counted-vmcnt, f32 amask C-init
__global__ __launch_bounds__(512) void k_attn(const u16* __restrict__ Q, const u16* __restrict__ K,
                                              const u16* __restrict__ Vt, const float* __restrict__ am,
                                              u16* __restrict__ O) {
  __shared__ u16 sK[2][64 * 64];
  __shared__ u16 sV[2][64 * 64];
  __shared__ u16 sP[8][16 * 64];

  int bid = blockIdx.x;
  int wg = (bid & 7) * (9 * 128 / 8) + (bid >> 3);   // XCD swizzle (1152 % 8 == 0)
  int bh = wg / 9, qt = wg - bh * 9;
  int b = bh >> 3, h = bh & 7;
  int t = threadIdx.x;
  int w = t >> 6, lane = t & 63;
  int lq = lane & 15, lg = lane >> 4;
  int qbase = qt * 128 + w * 16;
  int qg = qt * 8 + w;
  const u16* Qp = Q + ((size_t)bh * NP + qbase) * HD;
  const u16* Kp = K + (size_t)bh * NP * HD;
  const u16* Vp = Vt + (size_t)bh * HD * NP;
  const float* amp = am + ((size_t)qg * NTKV * 64 + lane) * 16;

  bf16x8 qf0 = *reinterpret_cast<const bf16x8*>(Qp + lq * HD + lg * 8);
  bf16x8 qf1 = *reinterpret_cast<const bf16x8*>(Qp + lq * HD + 32 + lg * 8);

  const int srow = t >> 3, sch = (t & 7) ^ (srow & 7);

  f32x4 oacc[4] = {};
  float lpart = 0.f;

#define STAGE(buf, kv0_)                                                        \
  {                                                                             \
    gload16(Kp + (size_t)((kv0_) + srow) * HD + sch * 8, &sK[buf][t * 8]);      \
    gload16(Vp + (size_t)srow * NP + (kv0_) + sch * 8,   &sV[buf][t * 8]);      \
  }

#define AML(an, ti_)                                                            \
  {                                                                             \
    const f32x4* ap = reinterpret_cast<const f32x4*>(amp + (size_t)(ti_) * 64 * 16); \
    an[0] = ap[0]; an[1] = ap[1]; an[2] = ap[2]; an[3] = ap[3];                 \
  }

#define COMPUTE(buf, ac)                                                         \
  {                                                                              \
    f32x4 s[4] = {ac[0], ac[1], ac[2], ac[3]};   /* C-init = additive mask */    \
    __builtin_amdgcn_s_setprio(1);                                               \
    _Pragma("unroll")                                                            \
    for (int kk = 0; kk < 2; ++kk) {                                             \
      bf16x8 qf = kk ? qf1 : qf0;                                                \
      int pc = (kk * 4 + lg) ^ (lq & 7);                                         \
      _Pragma("unroll")                                                          \
      for (int f = 0; f < 4; ++f) {                                              \
        bf16x8 kf = *reinterpret_cast<const bf16x8*>(&sK[buf][(f * 16 + lq) * 64 + pc * 8]); \
        s[f] = __builtin_amdgcn_mfma_f32_16x16x32_bf16(kf, qf, s[f], 0, 0, 0);   \
      }                                                                          \
    }                                                                            \
    __builtin_amdgcn_s_setprio(0);                                               \
    _Pragma("unroll")                                                            \
    for (int f = 0; f < 4; ++f) {                                                \
      _Pragma("unroll")                                                          \
      for (int r = 0; r < 4; ++r) {                                              \
        float pv = exp2a(s[f][r]);                                               \
        s[f][r] = pv;                                                            \
        lpart += pv;                                                             \
      }                                                                          \
    }                                                                            \
    _Pragma("unroll")                                                            \
    for (int f = 0; f < 4; ++f) {                                                \
      uint2 pw;                                                                  \
      pw.x = cvtpk(s[f][0], s[f][1]);                                            \
      pw.y = cvtpk(s[f][2], s[f][3]);                                            \
      int pch = (2 * f + (lg >> 1)) ^ (lq & 7);                                  \
      *reinterpret_cast<uint2*>(&sP[w][lq * 64 + pch * 8 + (lg & 1) * 4]) = pw;  \
    }                                                                            \
    __builtin_amdgcn_s_setprio(1);                                               \
    _Pragma("unroll")                                                            \
    for (int kk = 0; kk < 2; ++kk) {                                             \
      int pc = (kk * 4 + lg) ^ (lq & 7);                                         \
      bf16x8 pf = *reinterpret_cast<const bf16x8*>(&sP[w][lq * 64 + pc * 8]);    \
      _Pragma("unroll")                                                          \
      for (int j = 0; j < 4; ++j) {                                              \
        bf16x8 vf = *reinterpret_cast<const bf16x8*>(&sV[buf][(j * 16 + lq) * 64 + pc * 8]); \
        oacc[j] = __builtin_amdgcn_mfma_f32_16x16x32_bf16(pf, vf, oacc[j], 0, 0, 0); \
      }                                                                          \
    }                                                                            \
    __builtin_amdgcn_s_setprio(0);                                               \
  }

// pipelined step: stage tile ti+1 (2 loads) + amask ti+1 (4 loads); wait for tile-ti's 6
#define STEP(bufb, ac, an, ti_)                                                  \
  {                                                                              \
    STAGE((bufb) ^ 1, ((ti_) + 1) * 64);                                         \
    AML(an, (ti_) + 1);                                                          \
    asm volatile("s_waitcnt vmcnt(6)" ::: "memory");                             \
    __builtin_amdgcn_s_barrier();                                                \
    COMPUTE(bufb, ac);                                                           \
    __builtin_amdgcn_s_barrier();                                                \
  }

  f32x4 a0[4], a1[4];
  STAGE(0, 0);
  AML(a0, 0);
  for (int tp = 0; tp < 8; ++tp) {       // tiles 0..15
    STEP(0, a0, a1, 2 * tp);
    STEP(1, a1, a0, 2 * tp + 1);
  }
  // tile 16 (last): everything already staged into buf0, amask in a0
  asm volatile("s_waitcnt vmcnt(0)" ::: "memory");
  __builtin_amdgcn_s_barrier();
  COMPUTE(0, a0);
#undef STAGE
#undef AML
#undef COMPUTE
#undef STEP

  // deferred l reduction: combine the 4 lanes holding row lq
  lpart += __shfl_xor(lpart, 16);
  lpart += __shfl_xor(lpart, 32);

#pragma unroll
  for (int r = 0; r < 4; ++r) {
    int n = qbase + 4 * lg + r;
    float lr = __shfl(lpart, 4 * lg + r);
    float linv = (lr > 0.f) ? 1.f / lr : 0.f;
    size_t mrow = (size_t)b * NP + n;
#pragma unroll
    for (int j = 0; j < 4; ++j)
      O[mrow * D_ + h * HD + j * 16 + lq] = f2bf(oacc[j][r] * linv);
  }
}

// ---------------- K5: proj GEMM + bias -> fp32, counted-vmcnt, XCD-swizzled grid ----------------
// flat grid 4*144 = 576 blocks; each XCD gets 18 contiguous m-tiles (n fastest)
__global__ __launch_bounds__(256) void k_proj(const u16* __restrict__ ob, const u16* __restrict__ wtp,
                                              const float* __restrict__ bias, float* __restrict__ oproj) {
  __shared__ u16 sA[2][128 * 64];
  __shared__ u16 sB[2][128 * 64];
  const int bid = blockIdx.x;
  const int wg = (bid & 7) * 72 + (bid >> 3);    // 576/8 = 72, bijective
  const int m0 = (wg >> 2) * 128;
  const int n0 = (wg & 3) * 128;
  const int t = threadIdx.x;
  const int wave = t >> 6, lane = t & 63;
  const int wm = wave >> 1, wn = wave & 1;
  const int lq = lane & 15, lg = lane >> 4;

  const int srow = lane >> 3;
  const int schunk = (lane & 7) ^ srow;

  f32x4 acc[4][4] = {};

#define PSTAGE(buf, k0_)                                                          \
  {                                                                               \
    _Pragma("unroll")                                                             \
    for (int p = 0; p < 4; ++p) {                                                 \
      int row = p * 32 + wave * 8 + srow;                                         \
      gload16(ob + (size_t)(m0 + row) * 512 + (k0_) + schunk * 8,                 \
              &sA[buf][p * 2048 + wave * 512 + lane * 8]);                        \
      gload16(wtp + (size_t)(n0 + row) * 512 + (k0_) + schunk * 8,                \
              &sB[buf][p * 2048 + wave * 512 + lane * 8]);                        \
    }                                                                             \
  }

#define PCOMPUTE(buf)                                                             \
  {                                                                               \
    _Pragma("unroll")                                                             \
    for (int kk = 0; kk < 2; ++kk) {                                              \
      bf16x8 af[4], bff[4];                                                       \
      const int pc = (kk * 4 + lg) ^ (lq & 7);                                    \
      _Pragma("unroll")                                                           \
      for (int f = 0; f < 4; ++f) {                                               \
        af[f]  = *reinterpret_cast<const bf16x8*>(&sA[buf][(wm * 64 + f * 16 + lq) * 64 + pc * 8]); \
        bff[f] = *reinterpret_cast<const bf16x8*>(&sB[buf][(wn * 64 + f * 16 + lq) * 64 + pc * 8]); \
      }                                                                           \
      _Pragma("unroll")                                                           \
      for (int i = 0; i < 4; ++i)                                                 \
        _Pragma("unroll")                                                         \
        for (int j = 0; j < 4; ++j)                                               \
          acc[i][j] = __builtin_amdgcn_mfma_f32_16x16x32_bf16(af[i], bff[j], acc[i][j], 0, 0, 0); \
    }                                                                             \
  }

  PSTAGE(0, 0);
  int cur = 0;
  for (int k0 = 0; k0 < 448; k0 += 64) {
    PSTAGE(cur ^ 1, k0 + 64);
    asm volatile("s_waitcnt vmcnt(8)" ::: "memory");
    __builtin_amdgcn_s_barrier();
    PCOMPUTE(cur);
    __builtin_amdgcn_s_barrier();
    cur ^= 1;
  }
  asm volatile("s_waitcnt vmcnt(0)" ::: "memory");
  __builtin_amdgcn_s_barrier();
  PCOMPUTE(cur);
#undef PSTAGE
#undef PCOMPUTE

#pragma unroll
  for (int j = 0; j < 4; ++j) {
    int c = n0 + wn * 64 + j * 16 + lq;
    float bv = bias[c];
#pragma unroll
    for (int i = 0; i < 4; ++i) {
      int mbase = m0 + wm * 64 + i * 16 + lg * 4;
#pragma unroll
      for (int r = 0; r < 4; ++r) {
        int m = mbase + r;
        oproj[(size_t)m * D_ + c] = acc[i][j][r] + bv;
      }
    }
  }
}

// ---------------- K6: LN + residual (reads padded, writes real) ----------------
__global__ __launch_bounds__(256) void k_ln(const float* __restrict__ op, const float* __restrict__ gamma,
                                            const float* __restrict__ beta, float* __restrict__ out) {
  int row = blockIdx.x;
  int b = row / N_, n = row - b * N_;
  int t = threadIdx.x;
  const float* r = op + ((size_t)b * NP + n) * D_;
  float v0 = r[t], v1 = r[t + 256];
  float s = v0 + v1, sq = v0 * v0 + v1 * v1;
#pragma unroll
  for (int off = 1; off < 64; off <<= 1) { s += __shfl_xor(s, off); sq += __shfl_xor(sq, off); }
  __shared__ float ls[4], lsq[4];
  int wave = t >> 6, lane = t & 63;
  if (lane == 0) { ls[wave] = s; lsq[wave] = sq; }
  __syncthreads();
  float S = ls[0] + ls[1] + ls[2] + ls[3];
  float SQ = lsq[0] + lsq[1] + lsq[2] + lsq[3];
  float mu = S * (1.f / 512.f);
  float var = SQ * (1.f / 512.f) - mu * mu;
  float rinv = rsqrtf(var + 1e-5f);
  float g0 = gamma[t], g1 = gamma[t + 256], b0 = beta[t], b1 = beta[t + 256];
  out[(size_t)row * D_ + t]       = v0 + (v0 - mu) * rinv * g0 + b0;
  out[(size_t)row * D_ + t + 256] = v1 + (v1 - mu) * rinv * g1 + b1;
}

extern "C" void kernel_launch(void* const* d_in, const int* in_sizes, int n_in,
                              void* d_out, int out_size, void* d_ws, size_t ws_size,
                              hipStream_t stream) {
  const float* x     = (const float*)d_in[0];
  const float* wqkv  = (const float*)d_in[1];
  const float* wproj = (const float*)d_in[2];
  const float* bproj = (const float*)d_in[3];
  const float* gamma = (const float*)d_in[4];
  const float* beta  = (const float*)d_in[5];
  const float* mask  = (const float*)d_in[6];
  float* out = (float*)d_out;

  char* ws = (char*)d_ws;
  size_t off = 0;
  auto alloc = [&](size_t bytes) {
    void* p = ws + off;
    off = (off + bytes + 255) & ~(size_t)255;
    return p;
  };
  uint32_t* bmask = (uint32_t*)alloc((size_t)NP * WM * 4);
  float* am  = (float*)alloc((size_t)NQG * NTKV * 64 * 16 * 4);
  u16* wtq  = (u16*)alloc((size_t)3 * D_ * D_ * 2);
  u16* wtp  = (u16*)alloc((size_t)D_ * D_ * 2);
  u16* xb   = (u16*)alloc((size_t)MP * D_ * 2);
  u16* Qb   = (u16*)alloc((size_t)128 * NP * HD * 2);
  u16* Kb   = (u16*)alloc((size_t)128 * NP * HD * 2);
  u16* Vtb  = (u16*)alloc((size_t)128 * HD * NP * 2);
  u16* Ob   = (u16*)alloc((size_t)MP * D_ * 2);
  float* oproj = (float*)alloc((size_t)MP * D_ * 4);

  k_bitmask<<<dim3(NP), dim3(256), 0, stream>>>(mask, bmask);
  k_amask<<<dim3(NQG, NTKV), dim3(64), 0, stream>>>(bmask, am);
  k_wconv<<<dim3(3072), dim3(256), 0, stream>>>(wqkv, wproj, wtq, wtp);
  k_xconv<<<dim3(MP * D_ / (256 * 8)), dim3(256), 0, stream>>>(x, xb);
  k_qkv<<<dim3(12 * (MP / 128)), dim3(256), 0, stream>>>(xb, wtq, Qb, Kb, Vtb);
  k_attn<<<dim3(9 * 128), dim3(512), 0, stream>>>(Qb, Kb, Vtb, am, Ob);
  k_proj<<<dim3(4 * (MP / 128)), dim3(256), 0, stream>>>(Ob, wtp, bproj, oproj);
  k_ln<<<dim3(M_), dim3(256), 0, stream>>>(oproj, gamma, beta, out);
}

// Round 12
// 175.023 us; speedup vs baseline: 1.1550x; 1.0273x over previous
//
#include <hip/hip_runtime.h>
#include <stdint.h>

#define B_ 16
#define N_ 1025
#define D_ 512
#define H_ 8
#define HD 64
#define NP 1152           // padded N: 9*128 (q side)
#define WM 36             // bitmask u32 words per row
#define M_ (B_*N_)        // 16400 (real rows)
#define MP (B_*NP)        // 18432 = 144*128 padded rows
#define NTKV 17           // KV tiles of 64 (17*64=1088 >= 1025)
#define NQG 72            // q-groups of 16 (NP/16)

typedef unsigned short u16;
typedef __attribute__((ext_vector_type(8))) short bf16x8;
typedef __attribute__((ext_vector_type(4))) u16 u16x4;
typedef __attribute__((ext_vector_type(8))) u16 u16x8;
typedef __attribute__((ext_vector_type(4))) float f32x4;

typedef __attribute__((address_space(1))) const uint32_t gld_t;
typedef __attribute__((address_space(3))) uint32_t lds_t;

__device__ __forceinline__ u16 f2bf(float f) {
  uint32_t u = __float_as_uint(f);
  u += 0x7FFFu + ((u >> 16) & 1u);   // RNE
  return (u16)(u >> 16);
}

__device__ __forceinline__ float bf2f(u16 v) {
  return __uint_as_float(((uint32_t)v) << 16);
}

__device__ __forceinline__ uint32_t cvtpk(float a, float b) {
  uint32_t r;
  asm("v_cvt_pk_bf16_f32 %0, %1, %2" : "=v"(r) : "v"(a), "v"(b));
  return r;
}

__device__ __forceinline__ float exp2a(float x) {   // bare v_exp_f32 (no OCML fixup)
  float r;
  asm("v_exp_f32 %0, %1\n\ts_nop 0" : "=v"(r) : "v"(x));
  return r;
}

__device__ __forceinline__ void gload16(const void* g, void* l) {
  __builtin_amdgcn_global_load_lds((gld_t*)g, (lds_t*)l, 16, 0, 0);
}

// ---------------- K0: pack attn_mask into bitmask [NP][WM] u32 ----------------
__global__ void k_bitmask(const float* __restrict__ mask, uint32_t* __restrict__ bm) {
  int r = blockIdx.x;
  int wave = threadIdx.x >> 6, lane = threadIdx.x & 63;
  for (int chunk = wave; chunk < 18; chunk += 4) {
    int kv = chunk * 64 + lane;
    bool pred = (r < N_) && (kv < N_) && (mask[(size_t)r * N_ + kv] != 0.0f);
    unsigned long long bal = __ballot(pred);
    if (lane == 0) {
      bm[r * WM + chunk * 2]     = (uint32_t)bal;
      bm[r * WM + chunk * 2 + 1] = (uint32_t)(bal >> 32);
    }
  }
}

// ---------------- K0b: additive mask in MFMA C-fragment layout (f32, KVBLK=64) ----------------
__global__ __launch_bounds__(64) void k_amask(const uint32_t* __restrict__ bm, float* __restrict__ am) {
  int qg = blockIdx.x, ti = blockIdx.y;
  int lane = threadIdx.x;
  int lq = lane & 15, lg = lane >> 4;
  int q = qg * 16 + lq;
  size_t base = ((size_t)(qg * NTKV + ti) * 64 + lane) * 16;
#pragma unroll
  for (int f = 0; f < 4; ++f) {
    f32x4 o;
#pragma unroll
    for (int r = 0; r < 4; ++r) {
      int kv = ti * 64 + f * 16 + 4 * lg + r;
      uint32_t bit = (bm[q * WM + (kv >> 5)] >> (kv & 31)) & 1u;
      o[r] = bit ? 0.f : -30000.f;
    }
    *reinterpret_cast<f32x4*>(am + base + f * 4) = o;
  }
}

// ---------------- K1: convert+transpose weights to bf16 ----------------
__global__ void k_wconv(const float* __restrict__ wqkv, const float* __restrict__ wproj,
                        u16* __restrict__ wtq, u16* __restrict__ wtp) {
  int idx = blockIdx.x * 256 + threadIdx.x;
  if (idx < 3 * D_ * D_) {
    int k = idx / (3 * D_), c = idx % (3 * D_);
    wtq[c * D_ + k] = f2bf(wqkv[idx]);
  }
  if (idx < D_ * D_) {
    int k = idx >> 9, c = idx & 511;
    wtp[c * D_ + k] = f2bf(wproj[idx]);
  }
}

// ---------------- K2: x -> bf16, padded [B][NP][D], padded rows zeroed ----------------
__global__ void k_xconv(const float* __restrict__ x, u16* __restrict__ xb) {
  int i = blockIdx.x * 256 + threadIdx.x;
  int idx = i * 8;
  int pr = idx >> 9;
  int col = idx & 511;
  int b = pr / NP, n = pr - b * NP;
  u16x8 o;
  if (n < N_) {
    const float* src = x + ((size_t)b * N_ + n) * D_ + col;
    float4 v0 = *reinterpret_cast<const float4*>(src);
    float4 v1 = *reinterpret_cast<const float4*>(src + 4);
    o[0] = f2bf(v0.x); o[1] = f2bf(v0.y); o[2] = f2bf(v0.z); o[3] = f2bf(v0.w);
    o[4] = f2bf(v1.x); o[5] = f2bf(v1.y); o[6] = f2bf(v1.z); o[7] = f2bf(v1.w);
  } else {
    o = (u16x8){0,0,0,0,0,0,0,0};
  }
  *reinterpret_cast<u16x8*>(xb + idx) = o;
}

// ---------------- K3: QKV GEMM, counted-vmcnt pipeline, XCD-swizzled grid ----------------
__global__ __launch_bounds__(256) void k_qkv(const u16* __restrict__ xb, const u16* __restrict__ wtq,
                                             u16* __restrict__ Q, u16* __restrict__ K,
                                             u16* __restrict__ Vt) {
  __shared__ u16 sA[2][128 * 64];
  __shared__ u16 sB[2][128 * 64];
  const int bid = blockIdx.x;
  const int wg = (bid & 7) * 216 + (bid >> 3);   // 1728/8 = 216, bijective
  const int m0 = (wg / 12) * 128;
  const int n0 = (wg % 12) * 128;
  const int t = threadIdx.x;
  const int wave = t >> 6, lane = t & 63;
  const int wm = wave >> 1, wn = wave & 1;
  const int lq = lane & 15, lg = lane >> 4;

  const int srow = lane >> 3;
  const int schunk = (lane & 7) ^ srow;

  f32x4 acc[4][4] = {};

#define QSTAGE(buf, k0_)                                                          \
  {                                                                               \
    _Pragma("unroll")                                                             \
    for (int p = 0; p < 4; ++p) {                                                 \
      int row = p * 32 + wave * 8 + srow;                                         \
      gload16(xb + (size_t)(m0 + row) * 512 + (k0_) + schunk * 8,                 \
              &sA[buf][p * 2048 + wave * 512 + lane * 8]);                        \
      gload16(wtq + (size_t)(n0 + row) * 512 + (k0_) + schunk * 8,                \
              &sB[buf][p * 2048 + wave * 512 + lane * 8]);                        \
    }                                                                             \
  }

#define QCOMPUTE(buf)                                                             \
  {                                                                               \
    _Pragma("unroll")                                                             \
    for (int kk = 0; kk < 2; ++kk) {                                              \
      bf16x8 af[4], bff[4];                                                       \
      const int pc = (kk * 4 + lg) ^ (lq & 7);                                    \
      _Pragma("unroll")                                                           \
      for (int f = 0; f < 4; ++f) {                                               \
        af[f]  = *reinterpret_cast<const bf16x8*>(&sA[buf][(wm * 64 + f * 16 + lq) * 64 + pc * 8]); \
        bff[f] = *reinterpret_cast<const bf16x8*>(&sB[buf][(wn * 64 + f * 16 + lq) * 64 + pc * 8]); \
      }                                                                           \
      _Pragma("unroll")                                                           \
      for (int i = 0; i < 4; ++i)                                                 \
        _Pragma("unroll")                                                         \
        for (int j = 0; j < 4; ++j)                                               \
          acc[i][j] = __builtin_amdgcn_mfma_f32_16x16x32_bf16(af[i], bff[j], acc[i][j], 0, 0, 0); \
    }                                                                             \
  }

  QSTAGE(0, 0);
  int cur = 0;
  for (int k0 = 0; k0 < 448; k0 += 64) {
    QSTAGE(cur ^ 1, k0 + 64);
    asm volatile("s_waitcnt vmcnt(8)" ::: "memory");
    __builtin_amdgcn_s_barrier();
    QCOMPUTE(cur);
    __builtin_amdgcn_s_barrier();
    cur ^= 1;
  }
  asm volatile("s_waitcnt vmcnt(0)" ::: "memory");
  __builtin_amdgcn_s_barrier();
  QCOMPUTE(cur);
#undef QSTAGE
#undef QCOMPUTE

  if (n0 >= 1024) {
    // ---- V block: transpose 128(m) x 128(c) through XOR-swizzled LDS, write Vt coalesced ----
    __syncthreads();
    u16* T = (u16*)&sA[0][0];
#pragma unroll
    for (int j = 0; j < 4; ++j) {
      int c = wn * 64 + j * 16 + lq;
#pragma unroll
      for (int i = 0; i < 4; ++i) {
        int mb = wm * 64 + i * 16 + lg * 4;
        u16x4 pw;
#pragma unroll
        for (int r = 0; r < 4; ++r) pw[r] = f2bf(acc[i][j][r]);
        *reinterpret_cast<u16x4*>(&T[c * 128 + ((((mb >> 3) ^ lq) << 3) | (mb & 7))]) = pw;
      }
    }
    __syncthreads();
    int c = t & 127;
    int ch0 = (t >> 7) << 3;
    int cg = n0 + c - 1024;
    int h = cg >> 6, d = cg & 63;
    int bb = m0 / NP;
    int nb = m0 - bb * NP;
    u16* dst = Vt + (((size_t)(bb * H_ + h) * HD + d) * NP + nb);
#pragma unroll
    for (int rep = 0; rep < 8; ++rep) {
      int chunk = ch0 + rep;
      u16x8 vv = *reinterpret_cast<const u16x8*>(&T[c * 128 + ((chunk ^ (c & 15)) << 3)]);
      *reinterpret_cast<u16x8*>(&dst[chunk * 8]) = vv;
    }
  } else {
#pragma unroll
    for (int j = 0; j < 4; ++j) {
      int c = n0 + wn * 64 + j * 16 + lq;
      int which = c >> 9, h = (c >> 6) & 7, d = c & 63;
#pragma unroll
      for (int i = 0; i < 4; ++i) {
        int mbase = m0 + wm * 64 + i * 16 + lg * 4;
#pragma unroll
        for (int r = 0; r < 4; ++r) {
          int m = mbase + r;
          int b = m / NP, n = m - b * NP;
          int bh = b * H_ + h;
          float v = acc[i][j][r];
          if (which == 0) Q[((size_t)bh * NP + n) * HD + d] = f2bf(v * 0.18033688f); // 0.125*log2(e)
          else            K[((size_t)bh * NP + n) * HD + d] = f2bf(v);
        }
      }
    }
  }
}

// ---------------- K4: flash attention (round-6/9/10 verified config, f32 amask) ----------------
__global__ __launch_bounds__(512) void k_attn(const u16* __restrict__ Q, const u16* __restrict__ K,
                                              const u16* __restrict__ Vt, const float* __restrict__ am,
                                              u16* __restrict__ O) {
  __shared__ u16 sK[2][64 * 64];
  __shared__ u16 sV[2][64 * 64];
  __shared__ u16 sP[8][16 * 64];

  int bid = blockIdx.x;
  int wg = (bid & 7) * (9 * 128 / 8) + (bid >> 3);   // XCD swizzle (1152 % 8 == 0)
  int bh = wg / 9, qt = wg - bh * 9;
  int b = bh >> 3, h = bh & 7;
  int t = threadIdx.x;
  int w = t >> 6, lane = t & 63;
  int lq = lane & 15, lg = lane >> 4;
  int qbase = qt * 128 + w * 16;
  int qg = qt * 8 + w;
  const u16* Qp = Q + ((size_t)bh * NP + qbase) * HD;
  const u16* Kp = K + (size_t)bh * NP * HD;
  const u16* Vp = Vt + (size_t)bh * HD * NP;
  const float* amp = am + ((size_t)qg * NTKV * 64 + lane) * 16;

  bf16x8 qf0 = *reinterpret_cast<const bf16x8*>(Qp + lq * HD + lg * 8);
  bf16x8 qf1 = *reinterpret_cast<const bf16x8*>(Qp + lq * HD + 32 + lg * 8);

  const int srow = t >> 3, sch = (t & 7) ^ (srow & 7);

  f32x4 oacc[4] = {};
  float lpart = 0.f;

#define STAGE(buf, kv0_)                                                        \
  {                                                                             \
    gload16(Kp + (size_t)((kv0_) + srow) * HD + sch * 8, &sK[buf][t * 8]);      \
    gload16(Vp + (size_t)srow * NP + (kv0_) + sch * 8,   &sV[buf][t * 8]);      \
  }

#define AML(an, ti_)                                                            \
  {                                                                             \
    const f32x4* ap = reinterpret_cast<const f32x4*>(amp + (size_t)(ti_) * 64 * 16); \
    an[0] = ap[0]; an[1] = ap[1]; an[2] = ap[2]; an[3] = ap[3];                 \
  }

#define COMPUTE(buf, ac)                                                         \
  {                                                                              \
    f32x4 s[4] = {ac[0], ac[1], ac[2], ac[3]};   /* C-init = additive mask */    \
    __builtin_amdgcn_s_setprio(1);                                               \
    _Pragma("unroll")                                                            \
    for (int kk = 0; kk < 2; ++kk) {                                             \
      bf16x8 qf = kk ? qf1 : qf0;                                                \
      int pc = (kk * 4 + lg) ^ (lq & 7);                                         \
      _Pragma("unroll")                                                          \
      for (int f = 0; f < 4; ++f) {                                              \
        bf16x8 kf = *reinterpret_cast<const bf16x8*>(&sK[buf][(f * 16 + lq) * 64 + pc * 8]); \
        s[f] = __builtin_amdgcn_mfma_f32_16x16x32_bf16(kf, qf, s[f], 0, 0, 0);   \
      }                                                                          \
    }                                                                            \
    __builtin_amdgcn_s_setprio(0);                                               \
    _Pragma("unroll")                                                            \
    for (int f = 0; f < 4; ++f) {                                                \
      _Pragma("unroll")                                                          \
      for (int r = 0; r < 4; ++r) {                                              \
        float pv = exp2a(s[f][r]);                                               \
        s[f][r] = pv;                                                            \
        lpart += pv;                                                             \
      }                                                                          \
    }                                                                            \
    _Pragma("unroll")                                                            \
    for (int f = 0; f < 4; ++f) {                                                \
      uint2 pw;                                                                  \
      pw.x = cvtpk(s[f][0], s[f][1]);                                            \
      pw.y = cvtpk(s[f][2], s[f][3]);                                            \
      int pch = (2 * f + (lg >> 1)) ^ (lq & 7);                                  \
      *reinterpret_cast<uint2*>(&sP[w][lq * 64 + pch * 8 + (lg & 1) * 4]) = pw;  \
    }                                                                            \
    __builtin_amdgcn_s_setprio(1);                                               \
    _Pragma("unroll")                                                            \
    for (int kk = 0; kk < 2; ++kk) {                                             \
      int pc = (kk * 4 + lg) ^ (lq & 7);                                         \
      bf16x8 pf = *reinterpret_cast<const bf16x8*>(&sP[w][lq * 64 + pc * 8]);    \
      _Pragma("unroll")                                                          \
      for (int j = 0; j < 4; ++j) {                                              \
        bf16x8 vf = *reinterpret_cast<const bf16x8*>(&sV[buf][(j * 16 + lq) * 64 + pc * 8]); \
        oacc[j] = __builtin_amdgcn_mfma_f32_16x16x32_bf16(pf, vf, oacc[j], 0, 0, 0); \
      }                                                                          \
    }                                                                            \
    __builtin_amdgcn_s_setprio(0);                                               \
  }

// pipelined step: stage tile ti+1 (2 loads) + amask ti+1 (4 loads); wait for tile-ti's 6
#define STEP(bufb, ac, an, ti_)                                                  \
  {                                                                              \
    STAGE((bufb) ^ 1, ((ti_) + 1) * 64);                                         \
    AML(an, (ti_) + 1);                                                          \
    asm volatile("s_waitcnt vmcnt(6)" ::: "memory");                             \
    __builtin_amdgcn_s_barrier();                                                \
    COMPUTE(bufb, ac);                                                           \
    __builtin_amdgcn_s_barrier();                                                \
  }

  f32x4 a0[4], a1[4];
  STAGE(0, 0);
  AML(a0, 0);
  for (int tp = 0; tp < 8; ++tp) {       // tiles 0..15
    STEP(0, a0, a1, 2 * tp);
    STEP(1, a1, a0, 2 * tp + 1);
  }
  // tile 16 (last): everything already staged into buf0, amask in a0
  asm volatile("s_waitcnt vmcnt(0)" ::: "memory");
  __builtin_amdgcn_s_barrier();
  COMPUTE(0, a0);
#undef STAGE
#undef AML
#undef COMPUTE
#undef STEP

  // deferred l reduction: combine the 4 lanes holding row lq
  lpart += __shfl_xor(lpart, 16);
  lpart += __shfl_xor(lpart, 32);

#pragma unroll
  for (int r = 0; r < 4; ++r) {
    int n = qbase + 4 * lg + r;
    float lr = __shfl(lpart, 4 * lg + r);
    float linv = (lr > 0.f) ? 1.f / lr : 0.f;
    size_t mrow = (size_t)b * NP + n;
#pragma unroll
    for (int j = 0; j < 4; ++j)
      O[mrow * D_ + h * HD + j * 16 + lq] = f2bf(oacc[j][r] * linv);
  }
}

// ---------------- K5: proj GEMM + bias -> bf16 (padded M), counted-vmcnt, XCD-swizzled ----------------
__global__ __launch_bounds__(256) void k_proj(const u16* __restrict__ ob, const u16* __restrict__ wtp,
                                              const float* __restrict__ bias, u16* __restrict__ opb) {
  __shared__ u16 sA[2][128 * 64];
  __shared__ u16 sB[2][128 * 64];
  const int bid = blockIdx.x;
  const int wg = (bid & 7) * 72 + (bid >> 3);    // 576/8 = 72, bijective
  const int m0 = (wg >> 2) * 128;
  const int n0 = (wg & 3) * 128;
  const int t = threadIdx.x;
  const int wave = t >> 6, lane = t & 63;
  const int wm = wave >> 1, wn = wave & 1;
  const int lq = lane & 15, lg = lane >> 4;

  const int srow = lane >> 3;
  const int schunk = (lane & 7) ^ srow;

  f32x4 acc[4][4] = {};

#define PSTAGE(buf, k0_)                                                          \
  {                                                                               \
    _Pragma("unroll")                                                             \
    for (int p = 0; p < 4; ++p) {                                                 \
      int row = p * 32 + wave * 8 + srow;                                         \
      gload16(ob + (size_t)(m0 + row) * 512 + (k0_) + schunk * 8,                 \
              &sA[buf][p * 2048 + wave * 512 + lane * 8]);                        \
      gload16(wtp + (size_t)(n0 + row) * 512 + (k0_) + schunk * 8,                \
              &sB[buf][p * 2048 + wave * 512 + lane * 8]);                        \
    }                                                                             \
  }

#define PCOMPUTE(buf)                                                             \
  {                                                                               \
    _Pragma("unroll")                                                             \
    for (int kk = 0; kk < 2; ++kk) {                                              \
      bf16x8 af[4], bff[4];                                                       \
      const int pc = (kk * 4 + lg) ^ (lq & 7);                                    \
      _Pragma("unroll")                                                           \
      for (int f = 0; f < 4; ++f) {                                               \
        af[f]  = *reinterpret_cast<const bf16x8*>(&sA[buf][(wm * 64 + f * 16 + lq) * 64 + pc * 8]); \
        bff[f] = *reinterpret_cast<const bf16x8*>(&sB[buf][(wn * 64 + f * 16 + lq) * 64 + pc * 8]); \
      }                                                                           \
      _Pragma("unroll")                                                           \
      for (int i = 0; i < 4; ++i)                                                 \
        _Pragma("unroll")                                                         \
        for (int j = 0; j < 4; ++j)                                               \
          acc[i][j] = __builtin_amdgcn_mfma_f32_16x16x32_bf16(af[i], bff[j], acc[i][j], 0, 0, 0); \
    }                                                                             \
  }

  PSTAGE(0, 0);
  int cur = 0;
  for (int k0 = 0; k0 < 448; k0 += 64) {
    PSTAGE(cur ^ 1, k0 + 64);
    asm volatile("s_waitcnt vmcnt(8)" ::: "memory");
    __builtin_amdgcn_s_barrier();
    PCOMPUTE(cur);
    __builtin_amdgcn_s_barrier();
    cur ^= 1;
  }
  asm volatile("s_waitcnt vmcnt(0)" ::: "memory");
  __builtin_amdgcn_s_barrier();
  PCOMPUTE(cur);
#undef PSTAGE
#undef PCOMPUTE

#pragma unroll
  for (int j = 0; j < 4; ++j) {
    int c = n0 + wn * 64 + j * 16 + lq;
    float bv = bias[c];
#pragma unroll
    for (int i = 0; i < 4; ++i) {
      int mbase = m0 + wm * 64 + i * 16 + lg * 4;
#pragma unroll
      for (int r = 0; r < 4; ++r) {
        int m = mbase + r;
        opb[(size_t)m * D_ + c] = f2bf(acc[i][j][r] + bv);
      }
    }
  }
}

// ---------------- K6: LN + residual — wave per row, bf16 input, vectorized ----------------
__global__ __launch_bounds__(256) void k_ln(const u16* __restrict__ opb, const float* __restrict__ gamma,
                                            const float* __restrict__ beta, float* __restrict__ out) {
  int wave = threadIdx.x >> 6, lane = threadIdx.x & 63;
  int row = blockIdx.x * 4 + wave;            // 0..M_-1
  int b = row / N_, n = row - b * N_;
  const u16* src = opb + ((size_t)b * NP + n) * D_ + lane * 8;
  u16x8 ov = *reinterpret_cast<const u16x8*>(src);
  float v[8];
  float s = 0.f, sq = 0.f;
#pragma unroll
  for (int j = 0; j < 8; ++j) {
    v[j] = bf2f((u16)ov[j]);
    s += v[j];
    sq += v[j] * v[j];
  }
#pragma unroll
  for (int off = 1; off < 64; off <<= 1) { s += __shfl_xor(s, off); sq += __shfl_xor(sq, off); }
  float mu = s * (1.f / 512.f);
  float var = sq * (1.f / 512.f) - mu * mu;
  float rinv = rsqrtf(var + 1e-5f);
  float4 g0 = *reinterpret_cast<const float4*>(gamma + lane * 8);
  float4 g1 = *reinterpret_cast<const float4*>(gamma + lane * 8 + 4);
  float4 b0 = *reinterpret_cast<const float4*>(beta + lane * 8);
  float4 b1 = *reinterpret_cast<const float4*>(beta + lane * 8 + 4);
  float g[8] = {g0.x, g0.y, g0.z, g0.w, g1.x, g1.y, g1.z, g1.w};
  float bb[8] = {b0.x, b0.y, b0.z, b0.w, b1.x, b1.y, b1.z, b1.w};
  float* dst = out + (size_t)row * D_ + lane * 8;
  float4 o0, o1;
  o0.x = v[0] + (v[0] - mu) * rinv * g[0] + bb[0];
  o0.y = v[1] + (v[1] - mu) * rinv * g[1] + bb[1];
  o0.z = v[2] + (v[2] - mu) * rinv * g[2] + bb[2];
  o0.w = v[3] + (v[3] - mu) * rinv * g[3] + bb[3];
  o1.x = v[4] + (v[4] - mu) * rinv * g[4] + bb[4];
  o1.y = v[5] + (v[5] - mu) * rinv * g[5] + bb[5];
  o1.z = v[6] + (v[6] - mu) * rinv * g[6] + bb[6];
  o1.w = v[7] + (v[7] - mu) * rinv * g[7] + bb[7];
  *reinterpret_cast<float4*>(dst)     = o0;
  *reinterpret_cast<float4*>(dst + 4) = o1;
}

extern "C" void kernel_launch(void* const* d_in, const int* in_sizes, int n_in,
                              void* d_out, int out_size, void* d_ws, size_t ws_size,
                              hipStream_t stream) {
  const float* x     = (const float*)d_in[0];
  const float* wqkv  = (const float*)d_in[1];
  const float* wproj = (const float*)d_in[2];
  const float* bproj = (const float*)d_in[3];
  const float* gamma = (const float*)d_in[4];
  const float* beta  = (const float*)d_in[5];
  const float* mask  = (const float*)d_in[6];
  float* out = (float*)d_out;

  char* ws = (char*)d_ws;
  size_t off = 0;
  auto alloc = [&](size_t bytes) {
    void* p = ws + off;
    off = (off + bytes + 255) & ~(size_t)255;
    return p;
  };
  uint32_t* bmask = (uint32_t*)alloc((size_t)NP * WM * 4);
  float* am  = (float*)alloc((size_t)NQG * NTKV * 64 * 16 * 4);
  u16* wtq  = (u16*)alloc((size_t)3 * D_ * D_ * 2);
  u16* wtp  = (u16*)alloc((size_t)D_ * D_ * 2);
  u16* xb   = (u16*)alloc((size_t)MP * D_ * 2);
  u16* Qb   = (u16*)alloc((size_t)128 * NP * HD * 2);
  u16* Kb   = (u16*)alloc((size_t)128 * NP * HD * 2);
  u16* Vtb  = (u16*)alloc((size_t)128 * HD * NP * 2);
  u16* Ob   = (u16*)alloc((size_t)MP * D_ * 2);
  u16* opb  = (u16*)alloc((size_t)MP * D_ * 2);

  k_bitmask<<<dim3(NP), dim3(256), 0, stream>>>(mask, bmask);
  k_amask<<<dim3(NQG, NTKV), dim3(64), 0, stream>>>(bmask, am);
  k_wconv<<<dim3(3072), dim3(256), 0, stream>>>(wqkv, wproj, wtq, wtp);
  k_xconv<<<dim3(MP * D_ / (256 * 8)), dim3(256), 0, stream>>>(x, xb);
  k_qkv<<<dim3(12 * (MP / 128)), dim3(256), 0, stream>>>(xb, wtq, Qb, Kb, Vtb);
  k_attn<<<dim3(9 * 128), dim3(512), 0, stream>>>(Qb, Kb, Vtb, am, Ob);
  k_proj<<<dim3(4 * (MP / 128)), dim3(256), 0, stream>>>(Ob, wtp, bproj, opb);
  k_ln<<<dim3(M_ / 4), dim3(256), 0, stream>>>(opb, gamma, beta, out);
}

// Round 13
// 169.854 us; speedup vs baseline: 1.1902x; 1.0304x over previous
//
#include <hip/hip_runtime.h>
#include <stdint.h>

#define B_ 16
#define N_ 1025
#define D_ 512
#define H_ 8
#define HD 64
#define NP 1152           // padded N: 9*128 (q side)
#define M_ (B_*N_)        // 16400 (real rows)
#define MP (B_*NP)        // 18432 = 144*128 padded rows
#define NTKV 17           // KV tiles of 64 (17*64=1088 >= 1025)
#define NQG 72            // q-groups of 16 (NP/16)

typedef unsigned short u16;
typedef __attribute__((ext_vector_type(8))) short bf16x8;
typedef __attribute__((ext_vector_type(4))) u16 u16x4;
typedef __attribute__((ext_vector_type(8))) u16 u16x8;
typedef __attribute__((ext_vector_type(4))) float f32x4;

typedef __attribute__((address_space(1))) const uint32_t gld_t;
typedef __attribute__((address_space(3))) uint32_t lds_t;

__device__ __forceinline__ u16 f2bf(float f) {
  uint32_t u = __float_as_uint(f);
  u += 0x7FFFu + ((u >> 16) & 1u);   // RNE
  return (u16)(u >> 16);
}

__device__ __forceinline__ float bf2f(u16 v) {
  return __uint_as_float(((uint32_t)v) << 16);
}

__device__ __forceinline__ uint32_t cvtpk(float a, float b) {
  uint32_t r;
  asm("v_cvt_pk_bf16_f32 %0, %1, %2" : "=v"(r) : "v"(a), "v"(b));
  return r;
}

__device__ __forceinline__ float exp2a(float x) {   // bare v_exp_f32 (no OCML fixup)
  float r;
  asm("v_exp_f32 %0, %1\n\ts_nop 0" : "=v"(r) : "v"(x));
  return r;
}

__device__ __forceinline__ void gload16(const void* g, void* l) {
  __builtin_amdgcn_global_load_lds((gld_t*)g, (lds_t*)l, 16, 0, 0);
}

// ---------------- K0: additive mask in MFMA C-fragment layout, directly from mask ----------------
__global__ __launch_bounds__(64) void k_amask(const float* __restrict__ mask, float* __restrict__ am) {
  int qg = blockIdx.x, ti = blockIdx.y;
  int lane = threadIdx.x;
  int lq = lane & 15, lg = lane >> 4;
  int q = qg * 16 + lq;
  size_t base = ((size_t)(qg * NTKV + ti) * 64 + lane) * 16;
  const float* mrow = mask + (size_t)q * N_;
  bool qok = (q < N_);
#pragma unroll
  for (int f = 0; f < 4; ++f) {
    f32x4 o;
    int kvb = ti * 64 + f * 16 + 4 * lg;
#pragma unroll
    for (int r = 0; r < 4; ++r) {
      int kv = kvb + r;
      bool ok = qok && (kv < N_) && (mrow[kv] != 0.0f);
      o[r] = ok ? 0.f : -30000.f;
    }
    *reinterpret_cast<f32x4*>(am + base + f * 4) = o;
  }
}

// ---------------- K1: weight convert+transpose via LDS (coalesced both sides) ----------------
// blocks 0..191: wqkv [512][1536] -> wtq [1536][512]; blocks 192..255: wproj -> wtp
__global__ __launch_bounds__(256) void k_wconv(const float* __restrict__ wqkv, const float* __restrict__ wproj,
                                               u16* __restrict__ wtq, u16* __restrict__ wtp) {
  __shared__ float T[64][65];
  int bid = blockIdx.x;
  const float* src;
  u16* dst;
  int sstride;
  if (bid < 192) {
    int kt = bid / 24, ct = bid - kt * 24;
    src = wqkv + (size_t)(kt * 64) * 1536 + ct * 64;
    dst = wtq + (size_t)(ct * 64) * 512 + kt * 64;
    sstride = 1536;
  } else {
    int b2 = bid - 192;
    int kt = b2 >> 3, ct = b2 & 7;
    src = wproj + (size_t)(kt * 64) * 512 + ct * 64;
    dst = wtp + (size_t)(ct * 64) * 512 + kt * 64;
    sstride = 512;
  }
  int t = threadIdx.x;
  int r = t >> 2, cc = (t & 3) * 16;
#pragma unroll
  for (int i = 0; i < 4; ++i) {
    float4 v = *reinterpret_cast<const float4*>(src + (size_t)r * sstride + cc + i * 4);
    T[cc + i * 4 + 0][r] = v.x;
    T[cc + i * 4 + 1][r] = v.y;
    T[cc + i * 4 + 2][r] = v.z;
    T[cc + i * 4 + 3][r] = v.w;
  }
  __syncthreads();
  int c = t >> 2, k0 = (t & 3) * 16;
#pragma unroll
  for (int rep = 0; rep < 2; ++rep) {
    u16x8 o;
#pragma unroll
    for (int j = 0; j < 8; ++j) o[j] = f2bf(T[c][k0 + rep * 8 + j]);
    *reinterpret_cast<u16x8*>(dst + (size_t)c * 512 + k0 + rep * 8) = o;
  }
}

// ---------------- K2: x -> bf16, padded [B][NP][D], padded rows zeroed ----------------
__global__ void k_xconv(const float* __restrict__ x, u16* __restrict__ xb) {
  int i = blockIdx.x * 256 + threadIdx.x;
  int idx = i * 8;
  int pr = idx >> 9;
  int col = idx & 511;
  int b = pr / NP, n = pr - b * NP;
  u16x8 o;
  if (n < N_) {
    const float* src = x + ((size_t)b * N_ + n) * D_ + col;
    float4 v0 = *reinterpret_cast<const float4*>(src);
    float4 v1 = *reinterpret_cast<const float4*>(src + 4);
    o[0] = f2bf(v0.x); o[1] = f2bf(v0.y); o[2] = f2bf(v0.z); o[3] = f2bf(v0.w);
    o[4] = f2bf(v1.x); o[5] = f2bf(v1.y); o[6] = f2bf(v1.z); o[7] = f2bf(v1.w);
  } else {
    o = (u16x8){0,0,0,0,0,0,0,0};
  }
  *reinterpret_cast<u16x8*>(xb + idx) = o;
}

// ---------------- K3: QKV GEMM, counted-vmcnt pipeline, XCD-swizzled grid ----------------
__global__ __launch_bounds__(256) void k_qkv(const u16* __restrict__ xb, const u16* __restrict__ wtq,
                                             u16* __restrict__ Q, u16* __restrict__ K,
                                             u16* __restrict__ Vt) {
  __shared__ u16 sA[2][128 * 64];
  __shared__ u16 sB[2][128 * 64];
  const int bid = blockIdx.x;
  const int wg = (bid & 7) * 216 + (bid >> 3);   // 1728/8 = 216, bijective
  const int m0 = (wg / 12) * 128;
  const int n0 = (wg % 12) * 128;
  const int t = threadIdx.x;
  const int wave = t >> 6, lane = t & 63;
  const int wm = wave >> 1, wn = wave & 1;
  const int lq = lane & 15, lg = lane >> 4;

  const int srow = lane >> 3;
  const int schunk = (lane & 7) ^ srow;

  f32x4 acc[4][4] = {};

#define QSTAGE(buf, k0_)                                                          \
  {                                                                               \
    _Pragma("unroll")                                                             \
    for (int p = 0; p < 4; ++p) {                                                 \
      int row = p * 32 + wave * 8 + srow;                                         \
      gload16(xb + (size_t)(m0 + row) * 512 + (k0_) + schunk * 8,                 \
              &sA[buf][p * 2048 + wave * 512 + lane * 8]);                        \
      gload16(wtq + (size_t)(n0 + row) * 512 + (k0_) + schunk * 8,                \
              &sB[buf][p * 2048 + wave * 512 + lane * 8]);                        \
    }                                                                             \
  }

#define QCOMPUTE(buf)                                                             \
  {                                                                               \
    _Pragma("unroll")                                                             \
    for (int kk = 0; kk < 2; ++kk) {                                              \
      bf16x8 af[4], bff[4];                                                       \
      const int pc = (kk * 4 + lg) ^ (lq & 7);                                    \
      _Pragma("unroll")                                                           \
      for (int f = 0; f < 4; ++f) {                                               \
        af[f]  = *reinterpret_cast<const bf16x8*>(&sA[buf][(wm * 64 + f * 16 + lq) * 64 + pc * 8]); \
        bff[f] = *reinterpret_cast<const bf16x8*>(&sB[buf][(wn * 64 + f * 16 + lq) * 64 + pc * 8]); \
      }                                                                           \
      _Pragma("unroll")                                                           \
      for (int i = 0; i < 4; ++i)                                                 \
        _Pragma("unroll")                                                         \
        for (int j = 0; j < 4; ++j)                                               \
          acc[i][j] = __builtin_amdgcn_mfma_f32_16x16x32_bf16(af[i], bff[j], acc[i][j], 0, 0, 0); \
    }                                                                             \
  }

  QSTAGE(0, 0);
  int cur = 0;
  for (int k0 = 0; k0 < 448; k0 += 64) {
    QSTAGE(cur ^ 1, k0 + 64);
    asm volatile("s_waitcnt vmcnt(8)" ::: "memory");
    __builtin_amdgcn_s_barrier();
    QCOMPUTE(cur);
    __builtin_amdgcn_s_barrier();
    cur ^= 1;
  }
  asm volatile("s_waitcnt vmcnt(0)" ::: "memory");
  __builtin_amdgcn_s_barrier();
  QCOMPUTE(cur);
#undef QSTAGE
#undef QCOMPUTE

  if (n0 >= 1024) {
    // ---- V block: transpose 128(m) x 128(c) through XOR-swizzled LDS, write Vt coalesced ----
    __syncthreads();
    u16* T = (u16*)&sA[0][0];
#pragma unroll
    for (int j = 0; j < 4; ++j) {
      int c = wn * 64 + j * 16 + lq;
#pragma unroll
      for (int i = 0; i < 4; ++i) {
        int mb = wm * 64 + i * 16 + lg * 4;
        u16x4 pw;
#pragma unroll
        for (int r = 0; r < 4; ++r) pw[r] = f2bf(acc[i][j][r]);
        *reinterpret_cast<u16x4*>(&T[c * 128 + ((((mb >> 3) ^ lq) << 3) | (mb & 7))]) = pw;
      }
    }
    __syncthreads();
    int c = t & 127;
    int ch0 = (t >> 7) << 3;
    int cg = n0 + c - 1024;
    int h = cg >> 6, d = cg & 63;
    int bb = m0 / NP;
    int nb = m0 - bb * NP;
    u16* dst = Vt + (((size_t)(bb * H_ + h) * HD + d) * NP + nb);
#pragma unroll
    for (int rep = 0; rep < 8; ++rep) {
      int chunk = ch0 + rep;
      u16x8 vv = *reinterpret_cast<const u16x8*>(&T[c * 128 + ((chunk ^ (c & 15)) << 3)]);
      *reinterpret_cast<u16x8*>(&dst[chunk * 8]) = vv;
    }
  } else {
#pragma unroll
    for (int j = 0; j < 4; ++j) {
      int c = n0 + wn * 64 + j * 16 + lq;
      int which = c >> 9, h = (c >> 6) & 7, d = c & 63;
#pragma unroll
      for (int i = 0; i < 4; ++i) {
        int mbase = m0 + wm * 64 + i * 16 + lg * 4;
#pragma unroll
        for (int r = 0; r < 4; ++r) {
          int m = mbase + r;
          int b = m / NP, n = m - b * NP;
          int bh = b * H_ + h;
          float v = acc[i][j][r];
          if (which == 0) Q[((size_t)bh * NP + n) * HD + d] = f2bf(v * 0.18033688f); // 0.125*log2(e)
          else            K[((size_t)bh * NP + n) * HD + d] = f2bf(v);
        }
      }
    }
  }
}

// ---------------- K4: flash attention (r6 structure, sP halved -> 40KB LDS, 4 blocks/CU) ----------------
__global__ __launch_bounds__(512) void k_attn(const u16* __restrict__ Q, const u16* __restrict__ K,
                                              const u16* __restrict__ Vt, const float* __restrict__ am,
                                              u16* __restrict__ O) {
  __shared__ u16 sK[2][64 * 64];
  __shared__ u16 sV[2][64 * 64];
  __shared__ u16 sP[8][16 * 32];   // per-wave, per-kk half (16q x 32kv)

  int bid = blockIdx.x;
  int wg = (bid & 7) * (9 * 128 / 8) + (bid >> 3);   // XCD swizzle (1152 % 8 == 0)
  int bh = wg / 9, qt = wg - bh * 9;
  int b = bh >> 3, h = bh & 7;
  int t = threadIdx.x;
  int w = t >> 6, lane = t & 63;
  int lq = lane & 15, lg = lane >> 4;
  int qbase = qt * 128 + w * 16;
  int qg = qt * 8 + w;
  const u16* Qp = Q + ((size_t)bh * NP + qbase) * HD;
  const u16* Kp = K + (size_t)bh * NP * HD;
  const u16* Vp = Vt + (size_t)bh * HD * NP;
  const float* amp = am + ((size_t)qg * NTKV * 64 + lane) * 16;

  bf16x8 qf0 = *reinterpret_cast<const bf16x8*>(Qp + lq * HD + lg * 8);
  bf16x8 qf1 = *reinterpret_cast<const bf16x8*>(Qp + lq * HD + 32 + lg * 8);

  const int srow = t >> 3, sch = (t & 7) ^ (srow & 7);

  f32x4 oacc[4] = {};
  float lpart = 0.f;

#define STAGE(buf, kv0_)                                                        \
  {                                                                             \
    gload16(Kp + (size_t)((kv0_) + srow) * HD + sch * 8, &sK[buf][t * 8]);      \
    gload16(Vp + (size_t)srow * NP + (kv0_) + sch * 8,   &sV[buf][t * 8]);      \
  }

#define AML(an, ti_)                                                            \
  {                                                                             \
    const f32x4* ap = reinterpret_cast<const f32x4*>(amp + (size_t)(ti_) * 64 * 16); \
    an[0] = ap[0]; an[1] = ap[1]; an[2] = ap[2]; an[3] = ap[3];                 \
  }

#define COMPUTE(buf, ac)                                                         \
  {                                                                              \
    f32x4 s[4] = {ac[0], ac[1], ac[2], ac[3]};   /* C-init = additive mask */    \
    __builtin_amdgcn_s_setprio(1);                                               \
    _Pragma("unroll")                                                            \
    for (int kk = 0; kk < 2; ++kk) {                                             \
      bf16x8 qf = kk ? qf1 : qf0;                                                \
      int pc = (kk * 4 + lg) ^ (lq & 7);                                         \
      _Pragma("unroll")                                                          \
      for (int f = 0; f < 4; ++f) {                                              \
        bf16x8 kf = *reinterpret_cast<const bf16x8*>(&sK[buf][(f * 16 + lq) * 64 + pc * 8]); \
        s[f] = __builtin_amdgcn_mfma_f32_16x16x32_bf16(kf, qf, s[f], 0, 0, 0);   \
      }                                                                          \
    }                                                                            \
    __builtin_amdgcn_s_setprio(0);                                               \
    _Pragma("unroll")                                                            \
    for (int f = 0; f < 4; ++f) {                                                \
      _Pragma("unroll")                                                          \
      for (int r = 0; r < 4; ++r) {                                              \
        float pv = exp2a(s[f][r]);                                               \
        s[f][r] = pv;                                                            \
        lpart += pv;                                                             \
      }                                                                          \
    }                                                                            \
    _Pragma("unroll")                                                            \
    for (int kk = 0; kk < 2; ++kk) {                                             \
      _Pragma("unroll")                                                          \
      for (int fi = 0; fi < 2; ++fi) {                                           \
        int f = kk * 2 + fi;                                                     \
        uint2 pw;                                                                \
        pw.x = cvtpk(s[f][0], s[f][1]);                                          \
        pw.y = cvtpk(s[f][2], s[f][3]);                                          \
        int pch2 = (2 * fi + (lg >> 1)) ^ (lq & 3);                              \
        *reinterpret_cast<uint2*>(&sP[w][lq * 32 + pch2 * 8 + (lg & 1) * 4]) = pw; \
      }                                                                          \
      int pc2 = lg ^ (lq & 3);                                                   \
      int pcv = (kk * 4 + lg) ^ (lq & 7);                                        \
      bf16x8 pf = *reinterpret_cast<const bf16x8*>(&sP[w][lq * 32 + pc2 * 8]);   \
      __builtin_amdgcn_s_setprio(1);                                             \
      _Pragma("unroll")                                                          \
      for (int j = 0; j < 4; ++j) {                                              \
        bf16x8 vf = *reinterpret_cast<const bf16x8*>(&sV[buf][(j * 16 + lq) * 64 + pcv * 8]); \
        oacc[j] = __builtin_amdgcn_mfma_f32_16x16x32_bf16(pf, vf, oacc[j], 0, 0, 0); \
      }                                                                          \
      __builtin_amdgcn_s_setprio(0);                                             \
    }                                                                            \
  }

// pipelined step: stage tile ti+1 (2 loads) + amask ti+1 (4 loads); wait for tile-ti's 6
#define STEP(bufb, ac, an, ti_)                                                  \
  {                                                                              \
    STAGE((bufb) ^ 1, ((ti_) + 1) * 64);                                         \
    AML(an, (ti_) + 1);                                                          \
    asm volatile("s_waitcnt vmcnt(6)" ::: "memory");                             \
    __builtin_amdgcn_s_barrier();                                                \
    COMPUTE(bufb, ac);                                                           \
    __builtin_amdgcn_s_barrier();                                                \
  }

  f32x4 a0[4], a1[4];
  STAGE(0, 0);
  AML(a0, 0);
  for (int tp = 0; tp < 8; ++tp) {       // tiles 0..15
    STEP(0, a0, a1, 2 * tp);
    STEP(1, a1, a0, 2 * tp + 1);
  }
  // tile 16 (last): everything already staged into buf0, amask in a0
  asm volatile("s_waitcnt vmcnt(0)" ::: "memory");
  __builtin_amdgcn_s_barrier();
  COMPUTE(0, a0);
#undef STAGE
#undef AML
#undef COMPUTE
#undef STEP

  // deferred l reduction: combine the 4 lanes holding row lq
  lpart += __shfl_xor(lpart, 16);
  lpart += __shfl_xor(lpart, 32);

#pragma unroll
  for (int r = 0; r < 4; ++r) {
    int n = qbase + 4 * lg + r;
    float lr = __shfl(lpart, 4 * lg + r);
    float linv = (lr > 0.f) ? 1.f / lr : 0.f;
    size_t mrow = (size_t)b * NP + n;
#pragma unroll
    for (int j = 0; j < 4; ++j)
      O[mrow * D_ + h * HD + j * 16 + lq] = f2bf(oacc[j][r] * linv);
  }
}

// ---------------- K5: proj GEMM + bias -> bf16 (padded M), counted-vmcnt, XCD-swizzled ----------------
__global__ __launch_bounds__(256) void k_proj(const u16* __restrict__ ob, const u16* __restrict__ wtp,
                                              const float* __restrict__ bias, u16* __restrict__ opb) {
  __shared__ u16 sA[2][128 * 64];
  __shared__ u16 sB[2][128 * 64];
  const int bid = blockIdx.x;
  const int wg = (bid & 7) * 72 + (bid >> 3);    // 576/8 = 72, bijective
  const int m0 = (wg >> 2) * 128;
  const int n0 = (wg & 3) * 128;
  const int t = threadIdx.x;
  const int wave = t >> 6, lane = t & 63;
  const int wm = wave >> 1, wn = wave & 1;
  const int lq = lane & 15, lg = lane >> 4;

  const int srow = lane >> 3;
  const int schunk = (lane & 7) ^ srow;

  f32x4 acc[4][4] = {};

#define PSTAGE(buf, k0_)                                                          \
  {                                                                               \
    _Pragma("unroll")                                                             \
    for (int p = 0; p < 4; ++p) {                                                 \
      int row = p * 32 + wave * 8 + srow;                                         \
      gload16(ob + (size_t)(m0 + row) * 512 + (k0_) + schunk * 8,                 \
              &sA[buf][p * 2048 + wave * 512 + lane * 8]);                        \
      gload16(wtp + (size_t)(n0 + row) * 512 + (k0_) + schunk * 8,                \
              &sB[buf][p * 2048 + wave * 512 + lane * 8]);                        \
    }                                                                             \
  }

#define PCOMPUTE(buf)                                                             \
  {                                                                               \
    _Pragma("unroll")                                                             \
    for (int kk = 0; kk < 2; ++kk) {                                              \
      bf16x8 af[4], bff[4];                                                       \
      const int pc = (kk * 4 + lg) ^ (lq & 7);                                    \
      _Pragma("unroll")                                                           \
      for (int f = 0; f < 4; ++f) {                                               \
        af[f]  = *reinterpret_cast<const bf16x8*>(&sA[buf][(wm * 64 + f * 16 + lq) * 64 + pc * 8]); \
        bff[f] = *reinterpret_cast<const bf16x8*>(&sB[buf][(wn * 64 + f * 16 + lq) * 64 + pc * 8]); \
      }                                                                           \
      _Pragma("unroll")                                                           \
      for (int i = 0; i < 4; ++i)                                                 \
        _Pragma("unroll")                                                         \
        for (int j = 0; j < 4; ++j)                                               \
          acc[i][j] = __builtin_amdgcn_mfma_f32_16x16x32_bf16(af[i], bff[j], acc[i][j], 0, 0, 0); \
    }                                                                             \
  }

  PSTAGE(0, 0);
  int cur = 0;
  for (int k0 = 0; k0 < 448; k0 += 64) {
    PSTAGE(cur ^ 1, k0 + 64);
    asm volatile("s_waitcnt vmcnt(8)" ::: "memory");
    __builtin_amdgcn_s_barrier();
    PCOMPUTE(cur);
    __builtin_amdgcn_s_barrier();
    cur ^= 1;
  }
  asm volatile("s_waitcnt vmcnt(0)" ::: "memory");
  __builtin_amdgcn_s_barrier();
  PCOMPUTE(cur);
#undef PSTAGE
#undef PCOMPUTE

#pragma unroll
  for (int j = 0; j < 4; ++j) {
    int c = n0 + wn * 64 + j * 16 + lq;
    float bv = bias[c];
#pragma unroll
    for (int i = 0; i < 4; ++i) {
      int mbase = m0 + wm * 64 + i * 16 + lg * 4;
#pragma unroll
      for (int r = 0; r < 4; ++r) {
        int m = mbase + r;
        opb[(size_t)m * D_ + c] = f2bf(acc[i][j][r] + bv);
      }
    }
  }
}

// ---------------- K6: LN + residual — wave per row, bf16 input, vectorized ----------------
__global__ __launch_bounds__(256) void k_ln(const u16* __restrict__ opb, const float* __restrict__ gamma,
                                            const float* __restrict__ beta, float* __restrict__ out) {
  int wave = threadIdx.x >> 6, lane = threadIdx.x & 63;
  int row = blockIdx.x * 4 + wave;            // 0..M_-1
  int b = row / N_, n = row - b * N_;
  const u16* src = opb + ((size_t)b * NP + n) * D_ + lane * 8;
  u16x8 ov = *reinterpret_cast<const u16x8*>(src);
  float v[8];
  float s = 0.f, sq = 0.f;
#pragma unroll
  for (int j = 0; j < 8; ++j) {
    v[j] = bf2f((u16)ov[j]);
    s += v[j];
    sq += v[j] * v[j];
  }
#pragma unroll
  for (int off = 1; off < 64; off <<= 1) { s += __shfl_xor(s, off); sq += __shfl_xor(sq, off); }
  float mu = s * (1.f / 512.f);
  float var = sq * (1.f / 512.f) - mu * mu;
  float rinv = rsqrtf(var + 1e-5f);
  float4 g0 = *reinterpret_cast<const float4*>(gamma + lane * 8);
  float4 g1 = *reinterpret_cast<const float4*>(gamma + lane * 8 + 4);
  float4 b0 = *reinterpret_cast<const float4*>(beta + lane * 8);
  float4 b1 = *reinterpret_cast<const float4*>(beta + lane * 8 + 4);
  float g[8] = {g0.x, g0.y, g0.z, g0.w, g1.x, g1.y, g1.z, g1.w};
  float bb[8] = {b0.x, b0.y, b0.z, b0.w, b1.x, b1.y, b1.z, b1.w};
  float* dst = out + (size_t)row * D_ + lane * 8;
  float4 o0, o1;
  o0.x = v[0] + (v[0] - mu) * rinv * g[0] + bb[0];
  o0.y = v[1] + (v[1] - mu) * rinv * g[1] + bb[1];
  o0.z = v[2] + (v[2] - mu) * rinv * g[2] + bb[2];
  o0.w = v[3] + (v[3] - mu) * rinv * g[3] + bb[3];
  o1.x = v[4] + (v[4] - mu) * rinv * g[4] + bb[4];
  o1.y = v[5] + (v[5] - mu) * rinv * g[5] + bb[5];
  o1.z = v[6] + (v[6] - mu) * rinv * g[6] + bb[6];
  o1.w = v[7] + (v[7] - mu) * rinv * g[7] + bb[7];
  *reinterpret_cast<float4*>(dst)     = o0;
  *reinterpret_cast<float4*>(dst + 4) = o1;
}

extern "C" void kernel_launch(void* const* d_in, const int* in_sizes, int n_in,
                              void* d_out, int out_size, void* d_ws, size_t ws_size,
                              hipStream_t stream) {
  const float* x     = (const float*)d_in[0];
  const float* wqkv  = (const float*)d_in[1];
  const float* wproj = (const float*)d_in[2];
  const float* bproj = (const float*)d_in[3];
  const float* gamma = (const float*)d_in[4];
  const float* beta  = (const float*)d_in[5];
  const float* mask  = (const float*)d_in[6];
  float* out = (float*)d_out;

  char* ws = (char*)d_ws;
  size_t off = 0;
  auto alloc = [&](size_t bytes) {
    void* p = ws + off;
    off = (off + bytes + 255) & ~(size_t)255;
    return p;
  };
  float* am = (float*)alloc((size_t)NQG * NTKV * 64 * 16 * 4);
  u16* wtq  = (u16*)alloc((size_t)3 * D_ * D_ * 2);
  u16* wtp  = (u16*)alloc((size_t)D_ * D_ * 2);
  u16* xb   = (u16*)alloc((size_t)MP * D_ * 2);
  u16* Qb   = (u16*)alloc((size_t)128 * NP * HD * 2);
  u16* Kb   = (u16*)alloc((size_t)128 * NP * HD * 2);
  u16* Vtb  = (u16*)alloc((size_t)128 * HD * NP * 2);
  u16* Ob   = (u16*)alloc((size_t)MP * D_ * 2);
  u16* opb  = (u16*)alloc((size_t)MP * D_ * 2);

  k_amask<<<dim3(NQG, NTKV), dim3(64), 0, stream>>>(mask, am);
  k_wconv<<<dim3(256), dim3(256), 0, stream>>>(wqkv, wproj, wtq, wtp);
  k_xconv<<<dim3(MP * D_ / (256 * 8)), dim3(256), 0, stream>>>(x, xb);
  k_qkv<<<dim3(12 * (MP / 128)), dim3(256), 0, stream>>>(xb, wtq, Qb, Kb, Vtb);
  k_attn<<<dim3(9 * 128), dim3(512), 0, stream>>>(Qb, Kb, Vtb, am, Ob);
  k_proj<<<dim3(4 * (MP / 128)), dim3(256), 0, stream>>>(Ob, wtp, bproj, opb);
  k_ln<<<dim3(M_ / 4), dim3(256), 0, stream>>>(opb, gamma, beta, out);
}

// Round 14
// 166.876 us; speedup vs baseline: 1.2114x; 1.0178x over previous
//
#include <hip/hip_runtime.h>
#include <stdint.h>

#define B_ 16
#define N_ 1025
#define D_ 512
#define H_ 8
#define HD 64
#define NP 1152           // padded N: 9*128 (q side)
#define M_ (B_*N_)        // 16400 (real rows)
#define MP (B_*NP)        // 18432 = 144*128 padded rows
#define NTKV 17           // KV tiles of 64 (17*64=1088 >= 1025)
#define NQG 72            // q-groups of 16 (NP/16)

typedef unsigned short u16;
typedef __attribute__((ext_vector_type(8))) short bf16x8;
typedef __attribute__((ext_vector_type(4))) u16 u16x4;
typedef __attribute__((ext_vector_type(8))) u16 u16x8;
typedef __attribute__((ext_vector_type(4))) float f32x4;

typedef __attribute__((address_space(1))) const uint32_t gld_t;
typedef __attribute__((address_space(3))) uint32_t lds_t;

__device__ __forceinline__ u16 f2bf(float f) {
  uint32_t u = __float_as_uint(f);
  u += 0x7FFFu + ((u >> 16) & 1u);   // RNE
  return (u16)(u >> 16);
}

__device__ __forceinline__ float bf2f(u16 v) {
  return __uint_as_float(((uint32_t)v) << 16);
}

__device__ __forceinline__ uint32_t cvtpk(float a, float b) {
  uint32_t r;
  asm("v_cvt_pk_bf16_f32 %0, %1, %2" : "=v"(r) : "v"(a), "v"(b));
  return r;
}

__device__ __forceinline__ float exp2a(float x) {   // bare v_exp_f32 (no OCML fixup)
  float r;
  asm("v_exp_f32 %0, %1\n\ts_nop 0" : "=v"(r) : "v"(x));
  return r;
}

__device__ __forceinline__ void gload16(const void* g, void* l) {
  __builtin_amdgcn_global_load_lds((gld_t*)g, (lds_t*)l, 16, 0, 0);
}

// ---------------- K0: additive mask in MFMA C-fragment layout, directly from mask ----------------
__global__ __launch_bounds__(64) void k_amask(const float* __restrict__ mask, float* __restrict__ am) {
  int qg = blockIdx.x, ti = blockIdx.y;
  int lane = threadIdx.x;
  int lq = lane & 15, lg = lane >> 4;
  int q = qg * 16 + lq;
  size_t base = ((size_t)(qg * NTKV + ti) * 64 + lane) * 16;
  const float* mrow = mask + (size_t)q * N_;
  bool qok = (q < N_);
#pragma unroll
  for (int f = 0; f < 4; ++f) {
    f32x4 o;
    int kvb = ti * 64 + f * 16 + 4 * lg;
#pragma unroll
    for (int r = 0; r < 4; ++r) {
      int kv = kvb + r;
      bool ok = qok && (kv < N_) && (mrow[kv] != 0.0f);
      o[r] = ok ? 0.f : -30000.f;
    }
    *reinterpret_cast<f32x4*>(am + base + f * 4) = o;
  }
}

// ---------------- K1: weight convert+transpose via LDS (coalesced both sides) ----------------
__global__ __launch_bounds__(256) void k_wconv(const float* __restrict__ wqkv, const float* __restrict__ wproj,
                                               u16* __restrict__ wtq, u16* __restrict__ wtp) {
  __shared__ float T[64][65];
  int bid = blockIdx.x;
  const float* src;
  u16* dst;
  int sstride;
  if (bid < 192) {
    int kt = bid / 24, ct = bid - kt * 24;
    src = wqkv + (size_t)(kt * 64) * 1536 + ct * 64;
    dst = wtq + (size_t)(ct * 64) * 512 + kt * 64;
    sstride = 1536;
  } else {
    int b2 = bid - 192;
    int kt = b2 >> 3, ct = b2 & 7;
    src = wproj + (size_t)(kt * 64) * 512 + ct * 64;
    dst = wtp + (size_t)(ct * 64) * 512 + kt * 64;
    sstride = 512;
  }
  int t = threadIdx.x;
  int r = t >> 2, cc = (t & 3) * 16;
#pragma unroll
  for (int i = 0; i < 4; ++i) {
    float4 v = *reinterpret_cast<const float4*>(src + (size_t)r * sstride + cc + i * 4);
    T[cc + i * 4 + 0][r] = v.x;
    T[cc + i * 4 + 1][r] = v.y;
    T[cc + i * 4 + 2][r] = v.z;
    T[cc + i * 4 + 3][r] = v.w;
  }
  __syncthreads();
  int c = t >> 2, k0 = (t & 3) * 16;
#pragma unroll
  for (int rep = 0; rep < 2; ++rep) {
    u16x8 o;
#pragma unroll
    for (int j = 0; j < 8; ++j) o[j] = f2bf(T[c][k0 + rep * 8 + j]);
    *reinterpret_cast<u16x8*>(dst + (size_t)c * 512 + k0 + rep * 8) = o;
  }
}

// ---------------- K2: x -> bf16, padded [B][NP][D], padded rows zeroed ----------------
__global__ void k_xconv(const float* __restrict__ x, u16* __restrict__ xb) {
  int i = blockIdx.x * 256 + threadIdx.x;
  int idx = i * 8;
  int pr = idx >> 9;
  int col = idx & 511;
  int b = pr / NP, n = pr - b * NP;
  u16x8 o;
  if (n < N_) {
    const float* src = x + ((size_t)b * N_ + n) * D_ + col;
    float4 v0 = *reinterpret_cast<const float4*>(src);
    float4 v1 = *reinterpret_cast<const float4*>(src + 4);
    o[0] = f2bf(v0.x); o[1] = f2bf(v0.y); o[2] = f2bf(v0.z); o[3] = f2bf(v0.w);
    o[4] = f2bf(v1.x); o[5] = f2bf(v1.y); o[6] = f2bf(v1.z); o[7] = f2bf(v1.w);
  } else {
    o = (u16x8){0,0,0,0,0,0,0,0};
  }
  *reinterpret_cast<u16x8*>(xb + idx) = o;
}

// ---------------- K3: QKV GEMM, counted-vmcnt pipeline, XCD-swizzled grid ----------------
__global__ __launch_bounds__(256) void k_qkv(const u16* __restrict__ xb, const u16* __restrict__ wtq,
                                             u16* __restrict__ Q, u16* __restrict__ K,
                                             u16* __restrict__ Vt) {
  __shared__ u16 sA[2][128 * 64];
  __shared__ u16 sB[2][128 * 64];
  const int bid = blockIdx.x;
  const int wg = (bid & 7) * 216 + (bid >> 3);   // 1728/8 = 216, bijective
  const int m0 = (wg / 12) * 128;
  const int n0 = (wg % 12) * 128;
  const int t = threadIdx.x;
  const int wave = t >> 6, lane = t & 63;
  const int wm = wave >> 1, wn = wave & 1;
  const int lq = lane & 15, lg = lane >> 4;

  const int srow = lane >> 3;
  const int schunk = (lane & 7) ^ srow;

  f32x4 acc[4][4] = {};

#define QSTAGE(buf, k0_)                                                          \
  {                                                                               \
    _Pragma("unroll")                                                             \
    for (int p = 0; p < 4; ++p) {                                                 \
      int row = p * 32 + wave * 8 + srow;                                         \
      gload16(xb + (size_t)(m0 + row) * 512 + (k0_) + schunk * 8,                 \
              &sA[buf][p * 2048 + wave * 512 + lane * 8]);                        \
      gload16(wtq + (size_t)(n0 + row) * 512 + (k0_) + schunk * 8,                \
              &sB[buf][p * 2048 + wave * 512 + lane * 8]);                        \
    }                                                                             \
  }

#define QCOMPUTE(buf)                                                             \
  {                                                                               \
    _Pragma("unroll")                                                             \
    for (int kk = 0; kk < 2; ++kk) {                                              \
      bf16x8 af[4], bff[4];                                                       \
      const int pc = (kk * 4 + lg) ^ (lq & 7);                                    \
      _Pragma("unroll")                                                           \
      for (int f = 0; f < 4; ++f) {                                               \
        af[f]  = *reinterpret_cast<const bf16x8*>(&sA[buf][(wm * 64 + f * 16 + lq) * 64 + pc * 8]); \
        bff[f] = *reinterpret_cast<const bf16x8*>(&sB[buf][(wn * 64 + f * 16 + lq) * 64 + pc * 8]); \
      }                                                                           \
      _Pragma("unroll")                                                           \
      for (int i = 0; i < 4; ++i)                                                 \
        _Pragma("unroll")                                                         \
        for (int j = 0; j < 4; ++j)                                               \
          acc[i][j] = __builtin_amdgcn_mfma_f32_16x16x32_bf16(af[i], bff[j], acc[i][j], 0, 0, 0); \
    }                                                                             \
  }

  QSTAGE(0, 0);
  int cur = 0;
  for (int k0 = 0; k0 < 448; k0 += 64) {
    QSTAGE(cur ^ 1, k0 + 64);
    asm volatile("s_waitcnt vmcnt(8)" ::: "memory");
    __builtin_amdgcn_s_barrier();
    QCOMPUTE(cur);
    __builtin_amdgcn_s_barrier();
    cur ^= 1;
  }
  asm volatile("s_waitcnt vmcnt(0)" ::: "memory");
  __builtin_amdgcn_s_barrier();
  QCOMPUTE(cur);
#undef QSTAGE
#undef QCOMPUTE

  if (n0 >= 1024) {
    // ---- V block: transpose 128(m) x 128(c) through XOR-swizzled LDS, write Vt coalesced ----
    __syncthreads();
    u16* T = (u16*)&sA[0][0];
#pragma unroll
    for (int j = 0; j < 4; ++j) {
      int c = wn * 64 + j * 16 + lq;
#pragma unroll
      for (int i = 0; i < 4; ++i) {
        int mb = wm * 64 + i * 16 + lg * 4;
        u16x4 pw;
#pragma unroll
        for (int r = 0; r < 4; ++r) pw[r] = f2bf(acc[i][j][r]);
        *reinterpret_cast<u16x4*>(&T[c * 128 + ((((mb >> 3) ^ lq) << 3) | (mb & 7))]) = pw;
      }
    }
    __syncthreads();
    int c = t & 127;
    int ch0 = (t >> 7) << 3;
    int cg = n0 + c - 1024;
    int h = cg >> 6, d = cg & 63;
    int bb = m0 / NP;
    int nb = m0 - bb * NP;
    u16* dst = Vt + (((size_t)(bb * H_ + h) * HD + d) * NP + nb);
#pragma unroll
    for (int rep = 0; rep < 8; ++rep) {
      int chunk = ch0 + rep;
      u16x8 vv = *reinterpret_cast<const u16x8*>(&T[c * 128 + ((chunk ^ (c & 15)) << 3)]);
      *reinterpret_cast<u16x8*>(&dst[chunk * 8]) = vv;
    }
  } else {
#pragma unroll
    for (int j = 0; j < 4; ++j) {
      int c = n0 + wn * 64 + j * 16 + lq;
      int which = c >> 9, h = (c >> 6) & 7, d = c & 63;
#pragma unroll
      for (int i = 0; i < 4; ++i) {
        int mbase = m0 + wm * 64 + i * 16 + lg * 4;
#pragma unroll
        for (int r = 0; r < 4; ++r) {
          int m = mbase + r;
          int b = m / NP, n = m - b * NP;
          int bh = b * H_ + h;
          float v = acc[i][j][r];
          if (which == 0) Q[((size_t)bh * NP + n) * HD + d] = f2bf(v * 0.18033688f); // 0.125*log2(e)
          else            K[((size_t)bh * NP + n) * HD + d] = f2bf(v);
        }
      }
    }
  }
}

// ---------------- K4: flash attention (r12-exact verified config, f32 amask, 48KB LDS) ----------------
__global__ __launch_bounds__(512) void k_attn(const u16* __restrict__ Q, const u16* __restrict__ K,
                                              const u16* __restrict__ Vt, const float* __restrict__ am,
                                              u16* __restrict__ O) {
  __shared__ u16 sK[2][64 * 64];
  __shared__ u16 sV[2][64 * 64];
  __shared__ u16 sP[8][16 * 64];

  int bid = blockIdx.x;
  int wg = (bid & 7) * (9 * 128 / 8) + (bid >> 3);   // XCD swizzle (1152 % 8 == 0)
  int bh = wg / 9, qt = wg - bh * 9;
  int b = bh >> 3, h = bh & 7;
  int t = threadIdx.x;
  int w = t >> 6, lane = t & 63;
  int lq = lane & 15, lg = lane >> 4;
  int qbase = qt * 128 + w * 16;
  int qg = qt * 8 + w;
  const u16* Qp = Q + ((size_t)bh * NP + qbase) * HD;
  const u16* Kp = K + (size_t)bh * NP * HD;
  const u16* Vp = Vt + (size_t)bh * HD * NP;
  const float* amp = am + ((size_t)qg * NTKV * 64 + lane) * 16;

  bf16x8 qf0 = *reinterpret_cast<const bf16x8*>(Qp + lq * HD + lg * 8);
  bf16x8 qf1 = *reinterpret_cast<const bf16x8*>(Qp + lq * HD + 32 + lg * 8);

  const int srow = t >> 3, sch = (t & 7) ^ (srow & 7);

  f32x4 oacc[4] = {};
  float lpart = 0.f;

#define STAGE(buf, kv0_)                                                        \
  {                                                                             \
    gload16(Kp + (size_t)((kv0_) + srow) * HD + sch * 8, &sK[buf][t * 8]);      \
    gload16(Vp + (size_t)srow * NP + (kv0_) + sch * 8,   &sV[buf][t * 8]);      \
  }

#define AML(an, ti_)                                                            \
  {                                                                             \
    const f32x4* ap = reinterpret_cast<const f32x4*>(amp + (size_t)(ti_) * 64 * 16); \
    an[0] = ap[0]; an[1] = ap[1]; an[2] = ap[2]; an[3] = ap[3];                 \
  }

#define COMPUTE(buf, ac)                                                         \
  {                                                                              \
    f32x4 s[4] = {ac[0], ac[1], ac[2], ac[3]};   /* C-init = additive mask */    \
    __builtin_amdgcn_s_setprio(1);                                               \
    _Pragma("unroll")                                                            \
    for (int kk = 0; kk < 2; ++kk) {                                             \
      bf16x8 qf = kk ? qf1 : qf0;                                                \
      int pc = (kk * 4 + lg) ^ (lq & 7);                                         \
      _Pragma("unroll")                                                          \
      for (int f = 0; f < 4; ++f) {                                              \
        bf16x8 kf = *reinterpret_cast<const bf16x8*>(&sK[buf][(f * 16 + lq) * 64 + pc * 8]); \
        s[f] = __builtin_amdgcn_mfma_f32_16x16x32_bf16(kf, qf, s[f], 0, 0, 0);   \
      }                                                                          \
    }                                                                            \
    __builtin_amdgcn_s_setprio(0);                                               \
    _Pragma("unroll")                                                            \
    for (int f = 0; f < 4; ++f) {                                                \
      _Pragma("unroll")                                                          \
      for (int r = 0; r < 4; ++r) {                                              \
        float pv = exp2a(s[f][r]);                                               \
        s[f][r] = pv;                                                            \
        lpart += pv;                                                             \
      }                                                                          \
    }                                                                            \
    _Pragma("unroll")                                                            \
    for (int f = 0; f < 4; ++f) {                                                \
      uint2 pw;                                                                  \
      pw.x = cvtpk(s[f][0], s[f][1]);                                            \
      pw.y = cvtpk(s[f][2], s[f][3]);                                            \
      int pch = (2 * f + (lg >> 1)) ^ (lq & 7);                                  \
      *reinterpret_cast<uint2*>(&sP[w][lq * 64 + pch * 8 + (lg & 1) * 4]) = pw;  \
    }                                                                            \
    __builtin_amdgcn_s_setprio(1);                                               \
    _Pragma("unroll")                                                            \
    for (int kk = 0; kk < 2; ++kk) {                                             \
      int pc = (kk * 4 + lg) ^ (lq & 7);                                         \
      bf16x8 pf = *reinterpret_cast<const bf16x8*>(&sP[w][lq * 64 + pc * 8]);    \
      _Pragma("unroll")                                                          \
      for (int j = 0; j < 4; ++j) {                                              \
        bf16x8 vf = *reinterpret_cast<const bf16x8*>(&sV[buf][(j * 16 + lq) * 64 + pc * 8]); \
        oacc[j] = __builtin_amdgcn_mfma_f32_16x16x32_bf16(pf, vf, oacc[j], 0, 0, 0); \
      }                                                                          \
    }                                                                            \
    __builtin_amdgcn_s_setprio(0);                                               \
  }

// pipelined step: stage tile ti+1 (2 loads) + amask ti+1 (4 loads); wait for tile-ti's 6
#define STEP(bufb, ac, an, ti_)                                                  \
  {                                                                              \
    STAGE((bufb) ^ 1, ((ti_) + 1) * 64);                                         \
    AML(an, (ti_) + 1);                                                          \
    asm volatile("s_waitcnt vmcnt(6)" ::: "memory");                             \
    __builtin_amdgcn_s_barrier();                                                \
    COMPUTE(bufb, ac);                                                           \
    __builtin_amdgcn_s_barrier();                                                \
  }

  f32x4 a0[4], a1[4];
  STAGE(0, 0);
  AML(a0, 0);
  for (int tp = 0; tp < 8; ++tp) {       // tiles 0..15
    STEP(0, a0, a1, 2 * tp);
    STEP(1, a1, a0, 2 * tp + 1);
  }
  // tile 16 (last): everything already staged into buf0, amask in a0
  asm volatile("s_waitcnt vmcnt(0)" ::: "memory");
  __builtin_amdgcn_s_barrier();
  COMPUTE(0, a0);
#undef STAGE
#undef AML
#undef COMPUTE
#undef STEP

  // deferred l reduction: combine the 4 lanes holding row lq
  lpart += __shfl_xor(lpart, 16);
  lpart += __shfl_xor(lpart, 32);

#pragma unroll
  for (int r = 0; r < 4; ++r) {
    int n = qbase + 4 * lg + r;
    float lr = __shfl(lpart, 4 * lg + r);
    float linv = (lr > 0.f) ? 1.f / lr : 0.f;
    size_t mrow = (size_t)b * NP + n;
#pragma unroll
    for (int j = 0; j < 4; ++j)
      O[mrow * D_ + h * HD + j * 16 + lq] = f2bf(oacc[j][r] * linv);
  }
}

// ---------------- K5: proj GEMM + bias -> bf16 (padded M), counted-vmcnt, XCD-swizzled ----------------
__global__ __launch_bounds__(256) void k_proj(const u16* __restrict__ ob, const u16* __restrict__ wtp,
                                              const float* __restrict__ bias, u16* __restrict__ opb) {
  __shared__ u16 sA[2][128 * 64];
  __shared__ u16 sB[2][128 * 64];
  const int bid = blockIdx.x;
  const int wg = (bid & 7) * 72 + (bid >> 3);    // 576/8 = 72, bijective
  const int m0 = (wg >> 2) * 128;
  const int n0 = (wg & 3) * 128;
  const int t = threadIdx.x;
  const int wave = t >> 6, lane = t & 63;
  const int wm = wave >> 1, wn = wave & 1;
  const int lq = lane & 15, lg = lane >> 4;

  const int srow = lane >> 3;
  const int schunk = (lane & 7) ^ srow;

  f32x4 acc[4][4] = {};

#define PSTAGE(buf, k0_)                                                          \
  {                                                                               \
    _Pragma("unroll")                                                             \
    for (int p = 0; p < 4; ++p) {                                                 \
      int row = p * 32 + wave * 8 + srow;                                         \
      gload16(ob + (size_t)(m0 + row) * 512 + (k0_) + schunk * 8,                 \
              &sA[buf][p * 2048 + wave * 512 + lane * 8]);                        \
      gload16(wtp + (size_t)(n0 + row) * 512 + (k0_) + schunk * 8,                \
              &sB[buf][p * 2048 + wave * 512 + lane * 8]);                        \
    }                                                                             \
  }

#define PCOMPUTE(buf)                                                             \
  {                                                                               \
    _Pragma("unroll")                                                             \
    for (int kk = 0; kk < 2; ++kk) {                                              \
      bf16x8 af[4], bff[4];                                                       \
      const int pc = (kk * 4 + lg) ^ (lq & 7);                                    \
      _Pragma("unroll")                                                           \
      for (int f = 0; f < 4; ++f) {                                               \
        af[f]  = *reinterpret_cast<const bf16x8*>(&sA[buf][(wm * 64 + f * 16 + lq) * 64 + pc * 8]); \
        bff[f] = *reinterpret_cast<const bf16x8*>(&sB[buf][(wn * 64 + f * 16 + lq) * 64 + pc * 8]); \
      }                                                                           \
      _Pragma("unroll")                                                           \
      for (int i = 0; i < 4; ++i)                                                 \
        _Pragma("unroll")                                                         \
        for (int j = 0; j < 4; ++j)                                               \
          acc[i][j] = __builtin_amdgcn_mfma_f32_16x16x32_bf16(af[i], bff[j], acc[i][j], 0, 0, 0); \
    }                                                                             \
  }

  PSTAGE(0, 0);
  int cur = 0;
  for (int k0 = 0; k0 < 448; k0 += 64) {
    PSTAGE(cur ^ 1, k0 + 64);
    asm volatile("s_waitcnt vmcnt(8)" ::: "memory");
    __builtin_amdgcn_s_barrier();
    PCOMPUTE(cur);
    __builtin_amdgcn_s_barrier();
    cur ^= 1;
  }
  asm volatile("s_waitcnt vmcnt(0)" ::: "memory");
  __builtin_amdgcn_s_barrier();
  PCOMPUTE(cur);
#undef PSTAGE
#undef PCOMPUTE

#pragma unroll
  for (int j = 0; j < 4; ++j) {
    int c = n0 + wn * 64 + j * 16 + lq;
    float bv = bias[c];
#pragma unroll
    for (int i = 0; i < 4; ++i) {
      int mbase = m0 + wm * 64 + i * 16 + lg * 4;
#pragma unroll
      for (int r = 0; r < 4; ++r) {
        int m = mbase + r;
        opb[(size_t)m * D_ + c] = f2bf(acc[i][j][r] + bv);
      }
    }
  }
}

// ---------------- K6: LN + residual — wave per row, bf16 input, vectorized ----------------
__global__ __launch_bounds__(256) void k_ln(const u16* __restrict__ opb, const float* __restrict__ gamma,
                                            const float* __restrict__ beta, float* __restrict__ out) {
  int wave = threadIdx.x >> 6, lane = threadIdx.x & 63;
  int row = blockIdx.x * 4 + wave;            // 0..M_-1
  int b = row / N_, n = row - b * N_;
  const u16* src = opb + ((size_t)b * NP + n) * D_ + lane * 8;
  u16x8 ov = *reinterpret_cast<const u16x8*>(src);
  float v[8];
  float s = 0.f, sq = 0.f;
#pragma unroll
  for (int j = 0; j < 8; ++j) {
    v[j] = bf2f((u16)ov[j]);
    s += v[j];
    sq += v[j] * v[j];
  }
#pragma unroll
  for (int off = 1; off < 64; off <<= 1) { s += __shfl_xor(s, off); sq += __shfl_xor(sq, off); }
  float mu = s * (1.f / 512.f);
  float var = sq * (1.f / 512.f) - mu * mu;
  float rinv = rsqrtf(var + 1e-5f);
  float4 g0 = *reinterpret_cast<const float4*>(gamma + lane * 8);
  float4 g1 = *reinterpret_cast<const float4*>(gamma + lane * 8 + 4);
  float4 b0 = *reinterpret_cast<const float4*>(beta + lane * 8);
  float4 b1 = *reinterpret_cast<const float4*>(beta + lane * 8 + 4);
  float g[8] = {g0.x, g0.y, g0.z, g0.w, g1.x, g1.y, g1.z, g1.w};
  float bb[8] = {b0.x, b0.y, b0.z, b0.w, b1.x, b1.y, b1.z, b1.w};
  float* dst = out + (size_t)row * D_ + lane * 8;
  float4 o0, o1;
  o0.x = v[0] + (v[0] - mu) * rinv * g[0] + bb[0];
  o0.y = v[1] + (v[1] - mu) * rinv * g[1] + bb[1];
  o0.z = v[2] + (v[2] - mu) * rinv * g[2] + bb[2];
  o0.w = v[3] + (v[3] - mu) * rinv * g[3] + bb[3];
  o1.x = v[4] + (v[4] - mu) * rinv * g[4] + bb[4];
  o1.y = v[5] + (v[5] - mu) * rinv * g[5] + bb[5];
  o1.z = v[6] + (v[6] - mu) * rinv * g[6] + bb[6];
  o1.w = v[7] + (v[7] - mu) * rinv * g[7] + bb[7];
  *reinterpret_cast<float4*>(dst)     = o0;
  *reinterpret_cast<float4*>(dst + 4) = o1;
}

extern "C" void kernel_launch(void* const* d_in, const int* in_sizes, int n_in,
                              void* d_out, int out_size, void* d_ws, size_t ws_size,
                              hipStream_t stream) {
  const float* x     = (const float*)d_in[0];
  const float* wqkv  = (const float*)d_in[1];
  const float* wproj = (const float*)d_in[2];
  const float* bproj = (const float*)d_in[3];
  const float* gamma = (const float*)d_in[4];
  const float* beta  = (const float*)d_in[5];
  const float* mask  = (const float*)d_in[6];
  float* out = (float*)d_out;

  char* ws = (char*)d_ws;
  size_t off = 0;
  auto alloc = [&](size_t bytes) {
    void* p = ws + off;
    off = (off + bytes + 255) & ~(size_t)255;
    return p;
  };
  float* am = (float*)alloc((size_t)NQG * NTKV * 64 * 16 * 4);
  u16* wtq  = (u16*)alloc((size_t)3 * D_ * D_ * 2);
  u16* wtp  = (u16*)alloc((size_t)D_ * D_ * 2);
  u16* xb   = (u16*)alloc((size_t)MP * D_ * 2);
  u16* Qb   = (u16*)alloc((size_t)128 * NP * HD * 2);
  u16* Kb   = (u16*)alloc((size_t)128 * NP * HD * 2);
  u16* Vtb  = (u16*)alloc((size_t)128 * HD * NP * 2);
  u16* Ob   = (u16*)alloc((size_t)MP * D_ * 2);
  u16* opb  = (u16*)alloc((size_t)MP * D_ * 2);

  k_amask<<<dim3(NQG, NTKV), dim3(64), 0, stream>>>(mask, am);
  k_wconv<<<dim3(256), dim3(256), 0, stream>>>(wqkv, wproj, wtq, wtp);
  k_xconv<<<dim3(MP * D_ / (256 * 8)), dim3(256), 0, stream>>>(x, xb);
  k_qkv<<<dim3(12 * (MP / 128)), dim3(256), 0, stream>>>(xb, wtq, Qb, Kb, Vtb);
  k_attn<<<dim3(9 * 128), dim3(512), 0, stream>>>(Qb, Kb, Vtb, am, Ob);
  k_proj<<<dim3(4 * (MP / 128)), dim3(256), 0, stream>>>(Ob, wtp, bproj, opb);
  k_ln<<<dim3(M_ / 4), dim3(256), 0, stream>>>(opb, gamma, beta, out);
}

// Round 15
// 154.876 us; speedup vs baseline: 1.3053x; 1.0775x over previous
//
#include <hip/hip_runtime.h>
#include <stdint.h>

#define B_ 16
#define N_ 1025
#define D_ 512
#define H_ 8
#define HD 64
#define NP 1152           // padded N: 9*128 (q side)
#define WM 34             // bitmask u32 words per row (34*32 = 1088 = 17*64)
#define M_ (B_*N_)        // 16400 (real rows)
#define MP (B_*NP)        // 18432 = 144*128 padded rows
#define NTKV 17           // KV tiles of 64 (17*64=1088 >= 1025)

typedef unsigned short u16;
typedef __attribute__((ext_vector_type(8))) short bf16x8;
typedef __attribute__((ext_vector_type(4))) u16 u16x4;
typedef __attribute__((ext_vector_type(8))) u16 u16x8;
typedef __attribute__((ext_vector_type(4))) float f32x4;

typedef __attribute__((address_space(1))) const uint32_t gld_t;
typedef __attribute__((address_space(3))) uint32_t lds_t;

__device__ __forceinline__ u16 f2bf(float f) {
  uint32_t u = __float_as_uint(f);
  u += 0x7FFFu + ((u >> 16) & 1u);   // RNE
  return (u16)(u >> 16);
}

__device__ __forceinline__ float bf2f(u16 v) {
  return __uint_as_float(((uint32_t)v) << 16);
}

__device__ __forceinline__ uint32_t cvtpk(float a, float b) {
  uint32_t r;
  asm("v_cvt_pk_bf16_f32 %0, %1, %2" : "=v"(r) : "v"(a), "v"(b));
  return r;
}

__device__ __forceinline__ float exp2a(float x) {   // bare v_exp_f32 (no OCML fixup)
  float r;
  asm("v_exp_f32 %0, %1\n\ts_nop 0" : "=v"(r) : "v"(x));
  return r;
}

__device__ __forceinline__ void gload16(const void* g, void* l) {
  __builtin_amdgcn_global_load_lds((gld_t*)g, (lds_t*)l, 16, 0, 0);
}

// ---------------- K0: pack attn_mask into bitmask [NP][WM] u32 (r5-proven) ----------------
__global__ void k_bitmask(const float* __restrict__ mask, uint32_t* __restrict__ bm) {
  int r = blockIdx.x;                       // 0..NP-1
  int wave = threadIdx.x >> 6, lane = threadIdx.x & 63;
  for (int chunk = wave; chunk < 17; chunk += 4) {
    int kv = chunk * 64 + lane;
    bool pred = (r < N_) && (kv < N_) && (mask[(size_t)r * N_ + kv] != 0.0f);
    unsigned long long bal = __ballot(pred);
    if (lane == 0) {
      bm[r * WM + chunk * 2]     = (uint32_t)bal;
      bm[r * WM + chunk * 2 + 1] = (uint32_t)(bal >> 32);
    }
  }
}

// ---------------- K1: weight convert+transpose via LDS (coalesced both sides) ----------------
__global__ __launch_bounds__(256) void k_wconv(const float* __restrict__ wqkv, const float* __restrict__ wproj,
                                               u16* __restrict__ wtq, u16* __restrict__ wtp) {
  __shared__ float T[64][65];
  int bid = blockIdx.x;
  const float* src;
  u16* dst;
  int sstride;
  if (bid < 192) {
    int kt = bid / 24, ct = bid - kt * 24;
    src = wqkv + (size_t)(kt * 64) * 1536 + ct * 64;
    dst = wtq + (size_t)(ct * 64) * 512 + kt * 64;
    sstride = 1536;
  } else {
    int b2 = bid - 192;
    int kt = b2 >> 3, ct = b2 & 7;
    src = wproj + (size_t)(kt * 64) * 512 + ct * 64;
    dst = wtp + (size_t)(ct * 64) * 512 + kt * 64;
    sstride = 512;
  }
  int t = threadIdx.x;
  int r = t >> 2, cc = (t & 3) * 16;
#pragma unroll
  for (int i = 0; i < 4; ++i) {
    float4 v = *reinterpret_cast<const float4*>(src + (size_t)r * sstride + cc + i * 4);
    T[cc + i * 4 + 0][r] = v.x;
    T[cc + i * 4 + 1][r] = v.y;
    T[cc + i * 4 + 2][r] = v.z;
    T[cc + i * 4 + 3][r] = v.w;
  }
  __syncthreads();
  int c = t >> 2, k0 = (t & 3) * 16;
#pragma unroll
  for (int rep = 0; rep < 2; ++rep) {
    u16x8 o;
#pragma unroll
    for (int j = 0; j < 8; ++j) o[j] = f2bf(T[c][k0 + rep * 8 + j]);
    *reinterpret_cast<u16x8*>(dst + (size_t)c * 512 + k0 + rep * 8) = o;
  }
}

// ---------------- K2: x -> bf16, padded [B][NP][D], padded rows zeroed ----------------
__global__ void k_xconv(const float* __restrict__ x, u16* __restrict__ xb) {
  int i = blockIdx.x * 256 + threadIdx.x;
  int idx = i * 8;
  int pr = idx >> 9;
  int col = idx & 511;
  int b = pr / NP, n = pr - b * NP;
  u16x8 o;
  if (n < N_) {
    const float* src = x + ((size_t)b * N_ + n) * D_ + col;
    float4 v0 = *reinterpret_cast<const float4*>(src);
    float4 v1 = *reinterpret_cast<const float4*>(src + 4);
    o[0] = f2bf(v0.x); o[1] = f2bf(v0.y); o[2] = f2bf(v0.z); o[3] = f2bf(v0.w);
    o[4] = f2bf(v1.x); o[5] = f2bf(v1.y); o[6] = f2bf(v1.z); o[7] = f2bf(v1.w);
  } else {
    o = (u16x8){0,0,0,0,0,0,0,0};
  }
  *reinterpret_cast<u16x8*>(xb + idx) = o;
}

// ---------------- K3: QKV GEMM, counted-vmcnt pipeline, XCD-swizzled grid ----------------
__global__ __launch_bounds__(256) void k_qkv(const u16* __restrict__ xb, const u16* __restrict__ wtq,
                                             u16* __restrict__ Q, u16* __restrict__ K,
                                             u16* __restrict__ Vt) {
  __shared__ u16 sA[2][128 * 64];
  __shared__ u16 sB[2][128 * 64];
  const int bid = blockIdx.x;
  const int wg = (bid & 7) * 216 + (bid >> 3);   // 1728/8 = 216, bijective
  const int m0 = (wg / 12) * 128;
  const int n0 = (wg % 12) * 128;
  const int t = threadIdx.x;
  const int wave = t >> 6, lane = t & 63;
  const int wm = wave >> 1, wn = wave & 1;
  const int lq = lane & 15, lg = lane >> 4;

  const int srow = lane >> 3;
  const int schunk = (lane & 7) ^ srow;

  f32x4 acc[4][4] = {};

#define QSTAGE(buf, k0_)                                                          \
  {                                                                               \
    _Pragma("unroll")                                                             \
    for (int p = 0; p < 4; ++p) {                                                 \
      int row = p * 32 + wave * 8 + srow;                                         \
      gload16(xb + (size_t)(m0 + row) * 512 + (k0_) + schunk * 8,                 \
              &sA[buf][p * 2048 + wave * 512 + lane * 8]);                        \
      gload16(wtq + (size_t)(n0 + row) * 512 + (k0_) + schunk * 8,                \
              &sB[buf][p * 2048 + wave * 512 + lane * 8]);                        \
    }                                                                             \
  }

#define QCOMPUTE(buf)                                                             \
  {                                                                               \
    _Pragma("unroll")                                                             \
    for (int kk = 0; kk < 2; ++kk) {                                              \
      bf16x8 af[4], bff[4];                                                       \
      const int pc = (kk * 4 + lg) ^ (lq & 7);                                    \
      _Pragma("unroll")                                                           \
      for (int f = 0; f < 4; ++f) {                                               \
        af[f]  = *reinterpret_cast<const bf16x8*>(&sA[buf][(wm * 64 + f * 16 + lq) * 64 + pc * 8]); \
        bff[f] = *reinterpret_cast<const bf16x8*>(&sB[buf][(wn * 64 + f * 16 + lq) * 64 + pc * 8]); \
      }                                                                           \
      _Pragma("unroll")                                                           \
      for (int i = 0; i < 4; ++i)                                                 \
        _Pragma("unroll")                                                         \
        for (int j = 0; j < 4; ++j)                                               \
          acc[i][j] = __builtin_amdgcn_mfma_f32_16x16x32_bf16(af[i], bff[j], acc[i][j], 0, 0, 0); \
    }                                                                             \
  }

  QSTAGE(0, 0);
  int cur = 0;
  for (int k0 = 0; k0 < 448; k0 += 64) {
    QSTAGE(cur ^ 1, k0 + 64);
    asm volatile("s_waitcnt vmcnt(8)" ::: "memory");
    __builtin_amdgcn_s_barrier();
    QCOMPUTE(cur);
    __builtin_amdgcn_s_barrier();
    cur ^= 1;
  }
  asm volatile("s_waitcnt vmcnt(0)" ::: "memory");
  __builtin_amdgcn_s_barrier();
  QCOMPUTE(cur);
#undef QSTAGE
#undef QCOMPUTE

  if (n0 >= 1024) {
    // ---- V block: transpose 128(m) x 128(c) through XOR-swizzled LDS, write Vt coalesced ----
    __syncthreads();
    u16* T = (u16*)&sA[0][0];
#pragma unroll
    for (int j = 0; j < 4; ++j) {
      int c = wn * 64 + j * 16 + lq;
#pragma unroll
      for (int i = 0; i < 4; ++i) {
        int mb = wm * 64 + i * 16 + lg * 4;
        u16x4 pw;
#pragma unroll
        for (int r = 0; r < 4; ++r) pw[r] = f2bf(acc[i][j][r]);
        *reinterpret_cast<u16x4*>(&T[c * 128 + ((((mb >> 3) ^ lq) << 3) | (mb & 7))]) = pw;
      }
    }
    __syncthreads();
    int c = t & 127;
    int ch0 = (t >> 7) << 3;
    int cg = n0 + c - 1024;
    int h = cg >> 6, d = cg & 63;
    int bb = m0 / NP;
    int nb = m0 - bb * NP;
    u16* dst = Vt + (((size_t)(bb * H_ + h) * HD + d) * NP + nb);
#pragma unroll
    for (int rep = 0; rep < 8; ++rep) {
      int chunk = ch0 + rep;
      u16x8 vv = *reinterpret_cast<const u16x8*>(&T[c * 128 + ((chunk ^ (c & 15)) << 3)]);
      *reinterpret_cast<u16x8*>(&dst[chunk * 8]) = vv;
    }
  } else {
#pragma unroll
    for (int j = 0; j < 4; ++j) {
      int c = n0 + wn * 64 + j * 16 + lq;
      int which = c >> 9, h = (c >> 6) & 7, d = c & 63;
#pragma unroll
      for (int i = 0; i < 4; ++i) {
        int mbase = m0 + wm * 64 + i * 16 + lg * 4;
#pragma unroll
        for (int r = 0; r < 4; ++r) {
          int m = mbase + r;
          int b = m / NP, n = m - b * NP;
          int bh = b * H_ + h;
          float v = acc[i][j][r];
          if (which == 0) Q[((size_t)bh * NP + n) * HD + d] = f2bf(v * 0.18033688f); // 0.125*log2(e)
          else            K[((size_t)bh * NP + n) * HD + d] = f2bf(v);
        }
      }
    }
  }
}

// ---------------- K4: flash attention (r6 pipeline, bitmask C-init expansion in VALU) ----------------
__global__ __launch_bounds__(512) void k_attn(const u16* __restrict__ Q, const u16* __restrict__ K,
                                              const u16* __restrict__ Vt, const uint32_t* __restrict__ bm,
                                              u16* __restrict__ O) {
  __shared__ u16 sK[2][64 * 64];
  __shared__ u16 sV[2][64 * 64];
  __shared__ u16 sP[8][16 * 64];

  int bid = blockIdx.x;
  int wg = (bid & 7) * (9 * 128 / 8) + (bid >> 3);   // XCD swizzle (1152 % 8 == 0)
  int bh = wg / 9, qt = wg - bh * 9;
  int b = bh >> 3, h = bh & 7;
  int t = threadIdx.x;
  int w = t >> 6, lane = t & 63;
  int lq = lane & 15, lg = lane >> 4;
  int qbase = qt * 128 + w * 16;
  const u16* Qp = Q + ((size_t)bh * NP + qbase) * HD;
  const u16* Kp = K + (size_t)bh * NP * HD;
  const u16* Vp = Vt + (size_t)bh * HD * NP;
  const uint2* bmrow2 = reinterpret_cast<const uint2*>(bm + (size_t)(qbase + lq) * WM);

  bf16x8 qf0 = *reinterpret_cast<const bf16x8*>(Qp + lq * HD + lg * 8);
  bf16x8 qf1 = *reinterpret_cast<const bf16x8*>(Qp + lq * HD + 32 + lg * 8);

  const int srow = t >> 3, sch = (t & 7) ^ (srow & 7);

  f32x4 oacc[4] = {};
  float lpart = 0.f;

#define STAGE(buf, kv0_)                                                        \
  {                                                                             \
    gload16(Kp + (size_t)((kv0_) + srow) * HD + sch * 8, &sK[buf][t * 8]);      \
    gload16(Vp + (size_t)srow * NP + (kv0_) + sch * 8,   &sV[buf][t * 8]);      \
  }

#define COMPUTE(buf, mx, my)                                                     \
  {                                                                              \
    uint32_t u0 = (mx) >> (4 * lg);                                              \
    uint32_t u1 = (my) >> (4 * lg);                                              \
    f32x4 s[4];                                                                  \
    _Pragma("unroll")                                                            \
    for (int f = 0; f < 4; ++f) {                                                \
      uint32_t uu = (f & 2) ? u1 : u0;                                           \
      int sh = (f & 1) * 16;                                                     \
      _Pragma("unroll")                                                          \
      for (int r = 0; r < 4; ++r)                                                \
        s[f][r] = ((uu >> (sh + r)) & 1u) ? 0.f : -30000.f;                      \
    }                                                                            \
    __builtin_amdgcn_s_setprio(1);                                               \
    _Pragma("unroll")                                                            \
    for (int kk = 0; kk < 2; ++kk) {                                             \
      bf16x8 qf = kk ? qf1 : qf0;                                                \
      int pc = (kk * 4 + lg) ^ (lq & 7);                                         \
      _Pragma("unroll")                                                          \
      for (int f = 0; f < 4; ++f) {                                              \
        bf16x8 kf = *reinterpret_cast<const bf16x8*>(&sK[buf][(f * 16 + lq) * 64 + pc * 8]); \
        s[f] = __builtin_amdgcn_mfma_f32_16x16x32_bf16(kf, qf, s[f], 0, 0, 0);   \
      }                                                                          \
    }                                                                            \
    __builtin_amdgcn_s_setprio(0);                                               \
    _Pragma("unroll")                                                            \
    for (int f = 0; f < 4; ++f) {                                                \
      _Pragma("unroll")                                                          \
      for (int r = 0; r < 4; ++r) {                                              \
        float pv = exp2a(s[f][r]);                                               \
        s[f][r] = pv;                                                            \
        lpart += pv;                                                             \
      }                                                                          \
    }                                                                            \
    _Pragma("unroll")                                                            \
    for (int f = 0; f < 4; ++f) {                                                \
      uint2 pw;                                                                  \
      pw.x = cvtpk(s[f][0], s[f][1]);                                            \
      pw.y = cvtpk(s[f][2], s[f][3]);                                            \
      int pch = (2 * f + (lg >> 1)) ^ (lq & 7);                                  \
      *reinterpret_cast<uint2*>(&sP[w][lq * 64 + pch * 8 + (lg & 1) * 4]) = pw;  \
    }                                                                            \
    __builtin_amdgcn_s_setprio(1);                                               \
    _Pragma("unroll")                                                            \
    for (int kk = 0; kk < 2; ++kk) {                                             \
      int pc = (kk * 4 + lg) ^ (lq & 7);                                         \
      bf16x8 pf = *reinterpret_cast<const bf16x8*>(&sP[w][lq * 64 + pc * 8]);    \
      _Pragma("unroll")                                                          \
      for (int j = 0; j < 4; ++j) {                                              \
        bf16x8 vf = *reinterpret_cast<const bf16x8*>(&sV[buf][(j * 16 + lq) * 64 + pc * 8]); \
        oacc[j] = __builtin_amdgcn_mfma_f32_16x16x32_bf16(pf, vf, oacc[j], 0, 0, 0); \
      }                                                                          \
    }                                                                            \
    __builtin_amdgcn_s_setprio(0);                                               \
  }

// pipelined step: stage tile ti+1 (2 loads) + mask word ti+1 (1 load); keep 3 in flight (r5-proven)
#define STEP(bufb, ti_)                                                          \
  {                                                                              \
    STAGE((bufb) ^ 1, ((ti_) + 1) * 64);                                         \
    uint2 mw_nxt = bmrow2[(ti_) + 1];                                            \
    asm volatile("s_waitcnt vmcnt(3)" ::: "memory");                             \
    __builtin_amdgcn_s_barrier();                                                \
    COMPUTE(bufb, mw_cur.x, mw_cur.y);                                           \
    __builtin_amdgcn_s_barrier();                                                \
    mw_cur = mw_nxt;                                                             \
  }

  STAGE(0, 0);
  uint2 mw_cur = bmrow2[0];
  for (int tp = 0; tp < 8; ++tp) {       // tiles 0..15
    STEP(0, 2 * tp);
    STEP(1, 2 * tp + 1);
  }
  // tile 16 (last): staged into buf0, mask in mw_cur
  asm volatile("s_waitcnt vmcnt(0)" ::: "memory");
  __builtin_amdgcn_s_barrier();
  COMPUTE(0, mw_cur.x, mw_cur.y);
#undef STAGE
#undef COMPUTE
#undef STEP

  // deferred l reduction: combine the 4 lanes holding row lq
  lpart += __shfl_xor(lpart, 16);
  lpart += __shfl_xor(lpart, 32);

#pragma unroll
  for (int r = 0; r < 4; ++r) {
    int n = qbase + 4 * lg + r;
    float lr = __shfl(lpart, 4 * lg + r);
    float linv = (lr > 0.f) ? 1.f / lr : 0.f;
    size_t mrow = (size_t)b * NP + n;
#pragma unroll
    for (int j = 0; j < 4; ++j)
      O[mrow * D_ + h * HD + j * 16 + lq] = f2bf(oacc[j][r] * linv);
  }
}

// ---------------- K5: proj GEMM + bias -> bf16 (padded M), counted-vmcnt, XCD-swizzled ----------------
__global__ __launch_bounds__(256) void k_proj(const u16* __restrict__ ob, const u16* __restrict__ wtp,
                                              const float* __restrict__ bias, u16* __restrict__ opb) {
  __shared__ u16 sA[2][128 * 64];
  __shared__ u16 sB[2][128 * 64];
  const int bid = blockIdx.x;
  const int wg = (bid & 7) * 72 + (bid >> 3);    // 576/8 = 72, bijective
  const int m0 = (wg >> 2) * 128;
  const int n0 = (wg & 3) * 128;
  const int t = threadIdx.x;
  const int wave = t >> 6, lane = t & 63;
  const int wm = wave >> 1, wn = wave & 1;
  const int lq = lane & 15, lg = lane >> 4;

  const int srow = lane >> 3;
  const int schunk = (lane & 7) ^ srow;

  f32x4 acc[4][4] = {};

#define PSTAGE(buf, k0_)                                                          \
  {                                                                               \
    _Pragma("unroll")                                                             \
    for (int p = 0; p < 4; ++p) {                                                 \
      int row = p * 32 + wave * 8 + srow;                                         \
      gload16(ob + (size_t)(m0 + row) * 512 + (k0_) + schunk * 8,                 \
              &sA[buf][p * 2048 + wave * 512 + lane * 8]);                        \
      gload16(wtp + (size_t)(n0 + row) * 512 + (k0_) + schunk * 8,                \
              &sB[buf][p * 2048 + wave * 512 + lane * 8]);                        \
    }                                                                             \
  }

#define PCOMPUTE(buf)                                                             \
  {                                                                               \
    _Pragma("unroll")                                                             \
    for (int kk = 0; kk < 2; ++kk) {                                              \
      bf16x8 af[4], bff[4];                                                       \
      const int pc = (kk * 4 + lg) ^ (lq & 7);                                    \
      _Pragma("unroll")                                                           \
      for (int f = 0; f < 4; ++f) {                                               \
        af[f]  = *reinterpret_cast<const bf16x8*>(&sA[buf][(wm * 64 + f * 16 + lq) * 64 + pc * 8]); \
        bff[f] = *reinterpret_cast<const bf16x8*>(&sB[buf][(wn * 64 + f * 16 + lq) * 64 + pc * 8]); \
      }                                                                           \
      _Pragma("unroll")                                                           \
      for (int i = 0; i < 4; ++i)                                                 \
        _Pragma("unroll")                                                         \
        for (int j = 0; j < 4; ++j)                                               \
          acc[i][j] = __builtin_amdgcn_mfma_f32_16x16x32_bf16(af[i], bff[j], acc[i][j], 0, 0, 0); \
    }                                                                             \
  }

  PSTAGE(0, 0);
  int cur = 0;
  for (int k0 = 0; k0 < 448; k0 += 64) {
    PSTAGE(cur ^ 1, k0 + 64);
    asm volatile("s_waitcnt vmcnt(8)" ::: "memory");
    __builtin_amdgcn_s_barrier();
    PCOMPUTE(cur);
    __builtin_amdgcn_s_barrier();
    cur ^= 1;
  }
  asm volatile("s_waitcnt vmcnt(0)" ::: "memory");
  __builtin_amdgcn_s_barrier();
  PCOMPUTE(cur);
#undef PSTAGE
#undef PCOMPUTE

#pragma unroll
  for (int j = 0; j < 4; ++j) {
    int c = n0 + wn * 64 + j * 16 + lq;
    float bv = bias[c];
#pragma unroll
    for (int i = 0; i < 4; ++i) {
      int mbase = m0 + wm * 64 + i * 16 + lg * 4;
#pragma unroll
      for (int r = 0; r < 4; ++r) {
        int m = mbase + r;
        opb[(size_t)m * D_ + c] = f2bf(acc[i][j][r] + bv);
      }
    }
  }
}

// ---------------- K6: LN + residual — wave per row, bf16 input, vectorized ----------------
__global__ __launch_bounds__(256) void k_ln(const u16* __restrict__ opb, const float* __restrict__ gamma,
                                            const float* __restrict__ beta, float* __restrict__ out) {
  int wave = threadIdx.x >> 6, lane = threadIdx.x & 63;
  int row = blockIdx.x * 4 + wave;            // 0..M_-1
  int b = row / N_, n = row - b * N_;
  const u16* src = opb + ((size_t)b * NP + n) * D_ + lane * 8;
  u16x8 ov = *reinterpret_cast<const u16x8*>(src);
  float v[8];
  float s = 0.f, sq = 0.f;
#pragma unroll
  for (int j = 0; j < 8; ++j) {
    v[j] = bf2f((u16)ov[j]);
    s += v[j];
    sq += v[j] * v[j];
  }
#pragma unroll
  for (int off = 1; off < 64; off <<= 1) { s += __shfl_xor(s, off); sq += __shfl_xor(sq, off); }
  float mu = s * (1.f / 512.f);
  float var = sq * (1.f / 512.f) - mu * mu;
  float rinv = rsqrtf(var + 1e-5f);
  float4 g0 = *reinterpret_cast<const float4*>(gamma + lane * 8);
  float4 g1 = *reinterpret_cast<const float4*>(gamma + lane * 8 + 4);
  float4 b0 = *reinterpret_cast<const float4*>(beta + lane * 8);
  float4 b1 = *reinterpret_cast<const float4*>(beta + lane * 8 + 4);
  float g[8] = {g0.x, g0.y, g0.z, g0.w, g1.x, g1.y, g1.z, g1.w};
  float bb[8] = {b0.x, b0.y, b0.z, b0.w, b1.x, b1.y, b1.z, b1.w};
  float* dst = out + (size_t)row * D_ + lane * 8;
  float4 o0, o1;
  o0.x = v[0] + (v[0] - mu) * rinv * g[0] + bb[0];
  o0.y = v[1] + (v[1] - mu) * rinv * g[1] + bb[1];
  o0.z = v[2] + (v[2] - mu) * rinv * g[2] + bb[2];
  o0.w = v[3] + (v[3] - mu) * rinv * g[3] + bb[3];
  o1.x = v[4] + (v[4] - mu) * rinv * g[4] + bb[4];
  o1.y = v[5] + (v[5] - mu) * rinv * g[5] + bb[5];
  o1.z = v[6] + (v[6] - mu) * rinv * g[6] + bb[6];
  o1.w = v[7] + (v[7] - mu) * rinv * g[7] + bb[7];
  *reinterpret_cast<float4*>(dst)     = o0;
  *reinterpret_cast<float4*>(dst + 4) = o1;
}

extern "C" void kernel_launch(void* const* d_in, const int* in_sizes, int n_in,
                              void* d_out, int out_size, void* d_ws, size_t ws_size,
                              hipStream_t stream) {
  const float* x     = (const float*)d_in[0];
  const float* wqkv  = (const float*)d_in[1];
  const float* wproj = (const float*)d_in[2];
  const float* bproj = (const float*)d_in[3];
  const float* gamma = (const float*)d_in[4];
  const float* beta  = (const float*)d_in[5];
  const float* mask  = (const float*)d_in[6];
  float* out = (float*)d_out;

  char* ws = (char*)d_ws;
  size_t off = 0;
  auto alloc = [&](size_t bytes) {
    void* p = ws + off;
    off = (off + bytes + 255) & ~(size_t)255;
    return p;
  };
  uint32_t* bmask = (uint32_t*)alloc((size_t)NP * WM * 4);
  u16* wtq  = (u16*)alloc((size_t)3 * D_ * D_ * 2);
  u16* wtp  = (u16*)alloc((size_t)D_ * D_ * 2);
  u16* xb   = (u16*)alloc((size_t)MP * D_ * 2);
  u16* Qb   = (u16*)alloc((size_t)128 * NP * HD * 2);
  u16* Kb   = (u16*)alloc((size_t)128 * NP * HD * 2);
  u16* Vtb  = (u16*)alloc((size_t)128 * HD * NP * 2);
  u16* Ob   = (u16*)alloc((size_t)MP * D_ * 2);
  u16* opb  = (u16*)alloc((size_t)MP * D_ * 2);

  k_bitmask<<<dim3(NP), dim3(256), 0, stream>>>(mask, bmask);
  k_wconv<<<dim3(256), dim3(256), 0, stream>>>(wqkv, wproj, wtq, wtp);
  k_xconv<<<dim3(MP * D_ / (256 * 8)), dim3(256), 0, stream>>>(x, xb);
  k_qkv<<<dim3(12 * (MP / 128)), dim3(256), 0, stream>>>(xb, wtq, Qb, Kb, Vtb);
  k_attn<<<dim3(9 * 128), dim3(512), 0, stream>>>(Qb, Kb, Vtb, bmask, Ob);
  k_proj<<<dim3(4 * (MP / 128)), dim3(256), 0, stream>>>(Ob, wtp, bproj, opb);
  k_ln<<<dim3(M_ / 4), dim3(256), 0, stream>>>(opb, gamma, beta, out);
}

// Round 16
// 143.078 us; speedup vs baseline: 1.4129x; 1.0825x over previous
//
#include <hip/hip_runtime.h>
#include <stdint.h>

#define B_ 16
#define N_ 1025
#define D_ 512
#define H_ 8
#define HD 64
#define NP 1152           // padded N: 9*128 (q side)
#define WM 34             // bitmask u32 words per row (34*32 = 1088 = 17*64)
#define M_ (B_*N_)        // 16400 (real rows)
#define MP (B_*NP)        // 18432 = 144*128 padded rows
#define NTKV 17           // KV tiles of 64 (17*64=1088 >= 1025)

typedef unsigned short u16;
typedef __attribute__((ext_vector_type(8))) short bf16x8;
typedef __attribute__((ext_vector_type(4))) u16 u16x4;
typedef __attribute__((ext_vector_type(8))) u16 u16x8;
typedef __attribute__((ext_vector_type(4))) float f32x4;
typedef __attribute__((ext_vector_type(4))) uint32_t u32x4;

typedef __attribute__((address_space(1))) const uint32_t gld_t;
typedef __attribute__((address_space(3))) uint32_t lds_t;

__device__ __forceinline__ u16 f2bf(float f) {
  uint32_t u = __float_as_uint(f);
  u += 0x7FFFu + ((u >> 16) & 1u);   // RNE
  return (u16)(u >> 16);
}

__device__ __forceinline__ float bf2f(u16 v) {
  return __uint_as_float(((uint32_t)v) << 16);
}

__device__ __forceinline__ uint32_t cvtpk(float a, float b) {
  uint32_t r;
  asm("v_cvt_pk_bf16_f32 %0, %1, %2" : "=v"(r) : "v"(a), "v"(b));
  return r;
}

__device__ __forceinline__ float exp2a(float x) {   // bare v_exp_f32 (no OCML fixup)
  float r;
  asm("v_exp_f32 %0, %1\n\ts_nop 0" : "=v"(r) : "v"(x));
  return r;
}

__device__ __forceinline__ void gload16(const void* g, void* l) {
  __builtin_amdgcn_global_load_lds((gld_t*)g, (lds_t*)l, 16, 0, 0);
}

// ---------------- K0: pack attn_mask into bitmask [NP][WM] u32 ----------------
__global__ void k_bitmask(const float* __restrict__ mask, uint32_t* __restrict__ bm) {
  int r = blockIdx.x;
  int wave = threadIdx.x >> 6, lane = threadIdx.x & 63;
  for (int chunk = wave; chunk < 17; chunk += 4) {
    int kv = chunk * 64 + lane;
    bool pred = (r < N_) && (kv < N_) && (mask[(size_t)r * N_ + kv] != 0.0f);
    unsigned long long bal = __ballot(pred);
    if (lane == 0) {
      bm[r * WM + chunk * 2]     = (uint32_t)bal;
      bm[r * WM + chunk * 2 + 1] = (uint32_t)(bal >> 32);
    }
  }
}

// ---------------- K1: weight convert+transpose via LDS (coalesced both sides) ----------------
__global__ __launch_bounds__(256) void k_wconv(const float* __restrict__ wqkv, const float* __restrict__ wproj,
                                               u16* __restrict__ wtq, u16* __restrict__ wtp) {
  __shared__ float T[64][65];
  int bid = blockIdx.x;
  const float* src;
  u16* dst;
  int sstride;
  if (bid < 192) {
    int kt = bid / 24, ct = bid - kt * 24;
    src = wqkv + (size_t)(kt * 64) * 1536 + ct * 64;
    dst = wtq + (size_t)(ct * 64) * 512 + kt * 64;
    sstride = 1536;
  } else {
    int b2 = bid - 192;
    int kt = b2 >> 3, ct = b2 & 7;
    src = wproj + (size_t)(kt * 64) * 512 + ct * 64;
    dst = wtp + (size_t)(ct * 64) * 512 + kt * 64;
    sstride = 512;
  }
  int t = threadIdx.x;
  int r = t >> 2, cc = (t & 3) * 16;
#pragma unroll
  for (int i = 0; i < 4; ++i) {
    float4 v = *reinterpret_cast<const float4*>(src + (size_t)r * sstride + cc + i * 4);
    T[cc + i * 4 + 0][r] = v.x;
    T[cc + i * 4 + 1][r] = v.y;
    T[cc + i * 4 + 2][r] = v.z;
    T[cc + i * 4 + 3][r] = v.w;
  }
  __syncthreads();
  int c = t >> 2, k0 = (t & 3) * 16;
#pragma unroll
  for (int rep = 0; rep < 2; ++rep) {
    u16x8 o;
#pragma unroll
    for (int j = 0; j < 8; ++j) o[j] = f2bf(T[c][k0 + rep * 8 + j]);
    *reinterpret_cast<u16x8*>(dst + (size_t)c * 512 + k0 + rep * 8) = o;
  }
}

// ---------------- K2: x -> bf16, padded [B][NP][D], padded rows zeroed ----------------
__global__ void k_xconv(const float* __restrict__ x, u16* __restrict__ xb) {
  int i = blockIdx.x * 256 + threadIdx.x;
  int idx = i * 8;
  int pr = idx >> 9;
  int col = idx & 511;
  int b = pr / NP, n = pr - b * NP;
  u16x8 o;
  if (n < N_) {
    const float* src = x + ((size_t)b * N_ + n) * D_ + col;
    float4 v0 = *reinterpret_cast<const float4*>(src);
    float4 v1 = *reinterpret_cast<const float4*>(src + 4);
    o[0] = f2bf(v0.x); o[1] = f2bf(v0.y); o[2] = f2bf(v0.z); o[3] = f2bf(v0.w);
    o[4] = f2bf(v1.x); o[5] = f2bf(v1.y); o[6] = f2bf(v1.z); o[7] = f2bf(v1.w);
  } else {
    o = (u16x8){0,0,0,0,0,0,0,0};
  }
  *reinterpret_cast<u16x8*>(xb + idx) = o;
}

// ---------------- K3: QKV GEMM, counted-vmcnt pipeline, XCD-swizzled grid ----------------
// Vt written in sigma-permuted kv order: pos p (per 64-block) holds V[32kk+4lg+(j<4?j:16+j-4)],
// p = 32kk+8lg+j  -> PV A-operand needs NO cross-lane P movement in k_attn.
__global__ __launch_bounds__(256) void k_qkv(const u16* __restrict__ xb, const u16* __restrict__ wtq,
                                             u16* __restrict__ Q, u16* __restrict__ K,
                                             u16* __restrict__ Vt) {
  __shared__ u16 sA[2][128 * 64];
  __shared__ u16 sB[2][128 * 64];
  const int bid = blockIdx.x;
  const int wg = (bid & 7) * 216 + (bid >> 3);   // 1728/8 = 216, bijective
  const int m0 = (wg / 12) * 128;
  const int n0 = (wg % 12) * 128;
  const int t = threadIdx.x;
  const int wave = t >> 6, lane = t & 63;
  const int wm = wave >> 1, wn = wave & 1;
  const int lq = lane & 15, lg = lane >> 4;

  const int srow = lane >> 3;
  const int schunk = (lane & 7) ^ srow;

  f32x4 acc[4][4] = {};

#define QSTAGE(buf, k0_)                                                          \
  {                                                                               \
    _Pragma("unroll")                                                             \
    for (int p = 0; p < 4; ++p) {                                                 \
      int row = p * 32 + wave * 8 + srow;                                         \
      gload16(xb + (size_t)(m0 + row) * 512 + (k0_) + schunk * 8,                 \
              &sA[buf][p * 2048 + wave * 512 + lane * 8]);                        \
      gload16(wtq + (size_t)(n0 + row) * 512 + (k0_) + schunk * 8,                \
              &sB[buf][p * 2048 + wave * 512 + lane * 8]);                        \
    }                                                                             \
  }

#define QCOMPUTE(buf)                                                             \
  {                                                                               \
    _Pragma("unroll")                                                             \
    for (int kk = 0; kk < 2; ++kk) {                                              \
      bf16x8 af[4], bff[4];                                                       \
      const int pc = (kk * 4 + lg) ^ (lq & 7);                                    \
      _Pragma("unroll")                                                           \
      for (int f = 0; f < 4; ++f) {                                               \
        af[f]  = *reinterpret_cast<const bf16x8*>(&sA[buf][(wm * 64 + f * 16 + lq) * 64 + pc * 8]); \
        bff[f] = *reinterpret_cast<const bf16x8*>(&sB[buf][(wn * 64 + f * 16 + lq) * 64 + pc * 8]); \
      }                                                                           \
      _Pragma("unroll")                                                           \
      for (int i = 0; i < 4; ++i)                                                 \
        _Pragma("unroll")                                                         \
        for (int j = 0; j < 4; ++j)                                               \
          acc[i][j] = __builtin_amdgcn_mfma_f32_16x16x32_bf16(af[i], bff[j], acc[i][j], 0, 0, 0); \
    }                                                                             \
  }

  QSTAGE(0, 0);
  int cur = 0;
  for (int k0 = 0; k0 < 448; k0 += 64) {
    QSTAGE(cur ^ 1, k0 + 64);
    asm volatile("s_waitcnt vmcnt(8)" ::: "memory");
    __builtin_amdgcn_s_barrier();
    QCOMPUTE(cur);
    __builtin_amdgcn_s_barrier();
    cur ^= 1;
  }
  asm volatile("s_waitcnt vmcnt(0)" ::: "memory");
  __builtin_amdgcn_s_barrier();
  QCOMPUTE(cur);
#undef QSTAGE
#undef QCOMPUTE

  if (n0 >= 1024) {
    // ---- V block: transpose through XOR-swizzled LDS, write Vt in sigma-permuted kv order ----
    __syncthreads();
    u16* T = (u16*)&sA[0][0];
#pragma unroll
    for (int j = 0; j < 4; ++j) {
      int c = wn * 64 + j * 16 + lq;
#pragma unroll
      for (int i = 0; i < 4; ++i) {
        int mb = wm * 64 + i * 16 + lg * 4;
        u16x4 pw;
#pragma unroll
        for (int r = 0; r < 4; ++r) pw[r] = f2bf(acc[i][j][r]);
        *reinterpret_cast<u16x4*>(&T[c * 128 + ((((mb >> 3) ^ lq) << 3) | (mb & 7))]) = pw;
      }
    }
    __syncthreads();
    int c = t & 127;
    int ch0 = (t >> 7) << 3;
    int cg = n0 + c - 1024;
    int h = cg >> 6, d = cg & 63;
    int bb = m0 / NP;
    int nb = m0 - bb * NP;
    u16* dst = Vt + (((size_t)(bb * H_ + h) * HD + d) * NP + nb);
#pragma unroll
    for (int rep = 0; rep < 8; ++rep) {
      int chunk = ch0 + rep;              // storage chunk 0..15 (8 elems each)
      int blk = chunk >> 3;               // 64-block within the 128 rows
      int kkv = (chunk >> 2) & 1;
      int lgv = chunk & 3;
      int kvA = blk * 64 + kkv * 32 + lgv * 4;   // logical source col base (4 elems)
      int kvB = kvA + 16;
      u16x4 lo = *reinterpret_cast<const u16x4*>(&T[c * 128 + (((kvA >> 3) ^ (c & 15)) << 3) + (kvA & 7)]);
      u16x4 hi = *reinterpret_cast<const u16x4*>(&T[c * 128 + (((kvB >> 3) ^ (c & 15)) << 3) + (kvB & 7)]);
      u16x8 o = {lo[0], lo[1], lo[2], lo[3], hi[0], hi[1], hi[2], hi[3]};
      *reinterpret_cast<u16x8*>(&dst[chunk * 8]) = o;
    }
  } else {
#pragma unroll
    for (int j = 0; j < 4; ++j) {
      int c = n0 + wn * 64 + j * 16 + lq;
      int which = c >> 9, h = (c >> 6) & 7, d = c & 63;
#pragma unroll
      for (int i = 0; i < 4; ++i) {
        int mbase = m0 + wm * 64 + i * 16 + lg * 4;
#pragma unroll
        for (int r = 0; r < 4; ++r) {
          int m = mbase + r;
          int b = m / NP, n = m - b * NP;
          int bh = b * H_ + h;
          float v = acc[i][j][r];
          if (which == 0) Q[((size_t)bh * NP + n) * HD + d] = f2bf(v * 0.18033688f); // 0.125*log2(e)
          else            K[((size_t)bh * NP + n) * HD + d] = f2bf(v);
        }
      }
    }
  }
}

// ---------------- K4: flash attention — in-register P (no sP), 32KB LDS ----------------
__global__ __launch_bounds__(512) void k_attn(const u16* __restrict__ Q, const u16* __restrict__ K,
                                              const u16* __restrict__ Vt, const uint32_t* __restrict__ bm,
                                              u16* __restrict__ O) {
  __shared__ u16 sK[2][64 * 64];
  __shared__ u16 sV[2][64 * 64];

  int bid = blockIdx.x;
  int wg = (bid & 7) * (9 * 128 / 8) + (bid >> 3);   // XCD swizzle (1152 % 8 == 0)
  int bh = wg / 9, qt = wg - bh * 9;
  int b = bh >> 3, h = bh & 7;
  int t = threadIdx.x;
  int w = t >> 6, lane = t & 63;
  int lq = lane & 15, lg = lane >> 4;
  int qbase = qt * 128 + w * 16;
  const u16* Qp = Q + ((size_t)bh * NP + qbase) * HD;
  const u16* Kp = K + (size_t)bh * NP * HD;
  const u16* Vp = Vt + (size_t)bh * HD * NP;
  const uint2* bmrow2 = reinterpret_cast<const uint2*>(bm + (size_t)(qbase + lq) * WM);

  bf16x8 qf0 = *reinterpret_cast<const bf16x8*>(Qp + lq * HD + lg * 8);
  bf16x8 qf1 = *reinterpret_cast<const bf16x8*>(Qp + lq * HD + 32 + lg * 8);

  const int srow = t >> 3, sch = (t & 7) ^ (srow & 7);

  f32x4 oacc[4] = {};
  float lpart = 0.f;

#define STAGE(buf, kv0_)                                                        \
  {                                                                             \
    gload16(Kp + (size_t)((kv0_) + srow) * HD + sch * 8, &sK[buf][t * 8]);      \
    gload16(Vp + (size_t)srow * NP + (kv0_) + sch * 8,   &sV[buf][t * 8]);      \
  }

#define COMPUTE(buf, mx, my)                                                     \
  {                                                                              \
    uint32_t u0 = (mx) >> (4 * lg);                                              \
    uint32_t u1 = (my) >> (4 * lg);                                              \
    f32x4 s[4];                                                                  \
    _Pragma("unroll")                                                            \
    for (int f = 0; f < 4; ++f) {                                                \
      uint32_t uu = (f & 2) ? u1 : u0;                                           \
      int sh = (f & 1) * 16;                                                     \
      _Pragma("unroll")                                                          \
      for (int r = 0; r < 4; ++r)                                                \
        s[f][r] = ((uu >> (sh + r)) & 1u) ? 0.f : -30000.f;                      \
    }                                                                            \
    __builtin_amdgcn_s_setprio(1);                                               \
    _Pragma("unroll")                                                            \
    for (int kk = 0; kk < 2; ++kk) {                                             \
      bf16x8 qf = kk ? qf1 : qf0;                                                \
      int pc = (kk * 4 + lg) ^ (lq & 7);                                         \
      _Pragma("unroll")                                                          \
      for (int f = 0; f < 4; ++f) {                                              \
        bf16x8 kf = *reinterpret_cast<const bf16x8*>(&sK[buf][(f * 16 + lq) * 64 + pc * 8]); \
        s[f] = __builtin_amdgcn_mfma_f32_16x16x32_bf16(kf, qf, s[f], 0, 0, 0);   \
      }                                                                          \
    }                                                                            \
    __builtin_amdgcn_s_setprio(0);                                               \
    _Pragma("unroll")                                                            \
    for (int f = 0; f < 4; ++f) {                                                \
      _Pragma("unroll")                                                          \
      for (int r = 0; r < 4; ++r) {                                              \
        float pv = exp2a(s[f][r]);                                               \
        s[f][r] = pv;                                                            \
        lpart += pv;                                                             \
      }                                                                          \
    }                                                                            \
    uint32_t Af[4], Bf[4];                                                       \
    _Pragma("unroll")                                                            \
    for (int f = 0; f < 4; ++f) {                                                \
      Af[f] = cvtpk(s[f][0], s[f][1]);                                           \
      Bf[f] = cvtpk(s[f][2], s[f][3]);                                           \
    }                                                                            \
    __builtin_amdgcn_s_setprio(1);                                               \
    _Pragma("unroll")                                                            \
    for (int kk = 0; kk < 2; ++kk) {                                             \
      u32x4 pw = {Af[2 * kk], Bf[2 * kk], Af[2 * kk + 1], Bf[2 * kk + 1]};       \
      bf16x8 pf = *reinterpret_cast<bf16x8*>(&pw);                               \
      int pc = (kk * 4 + lg) ^ (lq & 7);                                         \
      _Pragma("unroll")                                                          \
      for (int j = 0; j < 4; ++j) {                                              \
        bf16x8 vf = *reinterpret_cast<const bf16x8*>(&sV[buf][(j * 16 + lq) * 64 + pc * 8]); \
        oacc[j] = __builtin_amdgcn_mfma_f32_16x16x32_bf16(pf, vf, oacc[j], 0, 0, 0); \
      }                                                                          \
    }                                                                            \
    __builtin_amdgcn_s_setprio(0);                                               \
  }

// pipelined step: stage tile ti+1 (2 loads) + mask word ti+1 (1 load); keep 3 in flight
#define STEP(bufb, ti_)                                                          \
  {                                                                              \
    STAGE((bufb) ^ 1, ((ti_) + 1) * 64);                                         \
    uint2 mw_nxt = bmrow2[(ti_) + 1];                                            \
    asm volatile("s_waitcnt vmcnt(3)" ::: "memory");                             \
    __builtin_amdgcn_s_barrier();                                                \
    COMPUTE(bufb, mw_cur.x, mw_cur.y);                                           \
    __builtin_amdgcn_s_barrier();                                                \
    mw_cur = mw_nxt;                                                             \
  }

  STAGE(0, 0);
  uint2 mw_cur = bmrow2[0];
  for (int tp = 0; tp < 8; ++tp) {       // tiles 0..15
    STEP(0, 2 * tp);
    STEP(1, 2 * tp + 1);
  }
  asm volatile("s_waitcnt vmcnt(0)" ::: "memory");
  __builtin_amdgcn_s_barrier();
  COMPUTE(0, mw_cur.x, mw_cur.y);        // tile 16
#undef STAGE
#undef COMPUTE
#undef STEP

  // deferred l reduction: combine the 4 lanes holding row lq
  lpart += __shfl_xor(lpart, 16);
  lpart += __shfl_xor(lpart, 32);

#pragma unroll
  for (int r = 0; r < 4; ++r) {
    int n = qbase + 4 * lg + r;
    float lr = __shfl(lpart, 4 * lg + r);
    float linv = (lr > 0.f) ? 1.f / lr : 0.f;
    size_t mrow = (size_t)b * NP + n;
#pragma unroll
    for (int j = 0; j < 4; ++j)
      O[mrow * D_ + h * HD + j * 16 + lq] = f2bf(oacc[j][r] * linv);
  }
}

// ---------------- K5: proj GEMM + bias -> bf16 (padded M), counted-vmcnt, XCD-swizzled ----------------
__global__ __launch_bounds__(256) void k_proj(const u16* __restrict__ ob, const u16* __restrict__ wtp,
                                              const float* __restrict__ bias, u16* __restrict__ opb) {
  __shared__ u16 sA[2][128 * 64];
  __shared__ u16 sB[2][128 * 64];
  const int bid = blockIdx.x;
  const int wg = (bid & 7) * 72 + (bid >> 3);    // 576/8 = 72, bijective
  const int m0 = (wg >> 2) * 128;
  const int n0 = (wg & 3) * 128;
  const int t = threadIdx.x;
  const int wave = t >> 6, lane = t & 63;
  const int wm = wave >> 1, wn = wave & 1;
  const int lq = lane & 15, lg = lane >> 4;

  const int srow = lane >> 3;
  const int schunk = (lane & 7) ^ srow;

  f32x4 acc[4][4] = {};

#define PSTAGE(buf, k0_)                                                          \
  {                                                                               \
    _Pragma("unroll")                                                             \
    for (int p = 0; p < 4; ++p) {                                                 \
      int row = p * 32 + wave * 8 + srow;                                         \
      gload16(ob + (size_t)(m0 + row) * 512 + (k0_) + schunk * 8,                 \
              &sA[buf][p * 2048 + wave * 512 + lane * 8]);                        \
      gload16(wtp + (size_t)(n0 + row) * 512 + (k0_) + schunk * 8,                \
              &sB[buf][p * 2048 + wave * 512 + lane * 8]);                        \
    }                                                                             \
  }

#define PCOMPUTE(buf)                                                             \
  {                                                                               \
    _Pragma("unroll")                                                             \
    for (int kk = 0; kk < 2; ++kk) {                                              \
      bf16x8 af[4], bff[4];                                                       \
      const int pc = (kk * 4 + lg) ^ (lq & 7);                                    \
      _Pragma("unroll")                                                           \
      for (int f = 0; f < 4; ++f) {                                               \
        af[f]  = *reinterpret_cast<const bf16x8*>(&sA[buf][(wm * 64 + f * 16 + lq) * 64 + pc * 8]); \
        bff[f] = *reinterpret_cast<const bf16x8*>(&sB[buf][(wn * 64 + f * 16 + lq) * 64 + pc * 8]); \
      }                                                                           \
      _Pragma("unroll")                                                           \
      for (int i = 0; i < 4; ++i)                                                 \
        _Pragma("unroll")                                                         \
        for (int j = 0; j < 4; ++j)                                               \
          acc[i][j] = __builtin_amdgcn_mfma_f32_16x16x32_bf16(af[i], bff[j], acc[i][j], 0, 0, 0); \
    }                                                                             \
  }

  PSTAGE(0, 0);
  int cur = 0;
  for (int k0 = 0; k0 < 448; k0 += 64) {
    PSTAGE(cur ^ 1, k0 + 64);
    asm volatile("s_waitcnt vmcnt(8)" ::: "memory");
    __builtin_amdgcn_s_barrier();
    PCOMPUTE(cur);
    __builtin_amdgcn_s_barrier();
    cur ^= 1;
  }
  asm volatile("s_waitcnt vmcnt(0)" ::: "memory");
  __builtin_amdgcn_s_barrier();
  PCOMPUTE(cur);
#undef PSTAGE
#undef PCOMPUTE

#pragma unroll
  for (int j = 0; j < 4; ++j) {
    int c = n0 + wn * 64 + j * 16 + lq;
    float bv = bias[c];
#pragma unroll
    for (int i = 0; i < 4; ++i) {
      int mbase = m0 + wm * 64 + i * 16 + lg * 4;
#pragma unroll
      for (int r = 0; r < 4; ++r) {
        int m = mbase + r;
        opb[(size_t)m * D_ + c] = f2bf(acc[i][j][r] + bv);
      }
    }
  }
}

// ---------------- K6: LN + residual — wave per row, bf16 input, vectorized ----------------
__global__ __launch_bounds__(256) void k_ln(const u16* __restrict__ opb, const float* __restrict__ gamma,
                                            const float* __restrict__ beta, float* __restrict__ out) {
  int wave = threadIdx.x >> 6, lane = threadIdx.x & 63;
  int row = blockIdx.x * 4 + wave;            // 0..M_-1
  int b = row / N_, n = row - b * N_;
  const u16* src = opb + ((size_t)b * NP + n) * D_ + lane * 8;
  u16x8 ov = *reinterpret_cast<const u16x8*>(src);
  float v[8];
  float s = 0.f, sq = 0.f;
#pragma unroll
  for (int j = 0; j < 8; ++j) {
    v[j] = bf2f((u16)ov[j]);
    s += v[j];
    sq += v[j] * v[j];
  }
#pragma unroll
  for (int off = 1; off < 64; off <<= 1) { s += __shfl_xor(s, off); sq += __shfl_xor(sq, off); }
  float mu = s * (1.f / 512.f);
  float var = sq * (1.f / 512.f) - mu * mu;
  float rinv = rsqrtf(var + 1e-5f);
  float4 g0 = *reinterpret_cast<const float4*>(gamma + lane * 8);
  float4 g1 = *reinterpret_cast<const float4*>(gamma + lane * 8 + 4);
  float4 b0 = *reinterpret_cast<const float4*>(beta + lane * 8);
  float4 b1 = *reinterpret_cast<const float4*>(beta + lane * 8 + 4);
  float g[8] = {g0.x, g0.y, g0.z, g0.w, g1.x, g1.y, g1.z, g1.w};
  float bb[8] = {b0.x, b0.y, b0.z, b0.w, b1.x, b1.y, b1.z, b1.w};
  float* dst = out + (size_t)row * D_ + lane * 8;
  float4 o0, o1;
  o0.x = v[0] + (v[0] - mu) * rinv * g[0] + bb[0];
  o0.y = v[1] + (v[1] - mu) * rinv * g[1] + bb[1];
  o0.z = v[2] + (v[2] - mu) * rinv * g[2] + bb[2];
  o0.w = v[3] + (v[3] - mu) * rinv * g[3] + bb[3];
  o1.x = v[4] + (v[4] - mu) * rinv * g[4] + bb[4];
  o1.y = v[5] + (v[5] - mu) * rinv * g[5] + bb[5];
  o1.z = v[6] + (v[6] - mu) * rinv * g[6] + bb[6];
  o1.w = v[7] + (v[7] - mu) * rinv * g[7] + bb[7];
  *reinterpret_cast<float4*>(dst)     = o0;
  *reinterpret_cast<float4*>(dst + 4) = o1;
}

extern "C" void kernel_launch(void* const* d_in, const int* in_sizes, int n_in,
                              void* d_out, int out_size, void* d_ws, size_t ws_size,
                              hipStream_t stream) {
  const float* x     = (const float*)d_in[0];
  const float* wqkv  = (const float*)d_in[1];
  const float* wproj = (const float*)d_in[2];
  const float* bproj = (const float*)d_in[3];
  const float* gamma = (const float*)d_in[4];
  const float* beta  = (const float*)d_in[5];
  const float* mask  = (const float*)d_in[6];
  float* out = (float*)d_out;

  char* ws = (char*)d_ws;
  size_t off = 0;
  auto alloc = [&](size_t bytes) {
    void* p = ws + off;
    off = (off + bytes + 255) & ~(size_t)255;
    return p;
  };
  uint32_t* bmask = (uint32_t*)alloc((size_t)NP * WM * 4);
  u16* wtq  = (u16*)alloc((size_t)3 * D_ * D_ * 2);
  u16* wtp  = (u16*)alloc((size_t)D_ * D_ * 2);
  u16* xb   = (u16*)alloc((size_t)MP * D_ * 2);
  u16* Qb   = (u16*)alloc((size_t)128 * NP * HD * 2);
  u16* Kb   = (u16*)alloc((size_t)128 * NP * HD * 2);
  u16* Vtb  = (u16*)alloc((size_t)128 * HD * NP * 2);
  u16* Ob   = (u16*)alloc((size_t)MP * D_ * 2);
  u16* opb  = (u16*)alloc((size_t)MP * D_ * 2);

  k_bitmask<<<dim3(NP), dim3(256), 0, stream>>>(mask, bmask);
  k_wconv<<<dim3(256), dim3(256), 0, stream>>>(wqkv, wproj, wtq, wtp);
  k_xconv<<<dim3(MP * D_ / (256 * 8)), dim3(256), 0, stream>>>(x, xb);
  k_qkv<<<dim3(12 * (MP / 128)), dim3(256), 0, stream>>>(xb, wtq, Qb, Kb, Vtb);
  k_attn<<<dim3(9 * 128), dim3(512), 0, stream>>>(Qb, Kb, Vtb, bmask, Ob);
  k_proj<<<dim3(4 * (MP / 128)), dim3(256), 0, stream>>>(Ob, wtp, bproj, opb);
  k_ln<<<dim3(M_ / 4), dim3(256), 0, stream>>>(opb, gamma, beta, out);
}